// Round 5
// baseline (786.318 us; speedup 1.0000x reference)
//
#include <hip/hip_runtime.h>
#include <stdint.h>

#define DI __device__ __forceinline__

typedef __attribute__((ext_vector_type(8))) short bfx8;
typedef __attribute__((ext_vector_type(4))) short bfx4;
typedef __attribute__((ext_vector_type(4))) float f4;

DI unsigned short f2bf(float x){
  unsigned u = __float_as_uint(x);
  u = (u + 0x7FFFu + ((u >> 16) & 1u)) >> 16;
  return (unsigned short)u;
}
DI float bf2f(unsigned short h){ return __uint_as_float(((unsigned)h) << 16); }

DI f4 mfma32(bfx8 a, bfx8 b, f4 c){
  return __builtin_amdgcn_mfma_f32_16x16x32_bf16(a, b, c, 0, 0, 0);
}
#if __has_builtin(__builtin_amdgcn_mfma_f32_16x16x16bf16_1k)
DI f4 mfma16(bfx4 a, bfx4 b, f4 c){
  return __builtin_amdgcn_mfma_f32_16x16x16bf16_1k(a, b, c, 0, 0, 0);
}
#else
DI f4 mfma16(bfx4 a, bfx4 b, f4 c){
  f4 d = c;
  asm volatile("v_mfma_f32_16x16x16_bf16 %0, %1, %2, %0" : "+v"(d) : "v"(a), "v"(b));
  return d;
}
#endif

// ---------------- cast f32 -> bf16 (4-wide) ----------------
__global__ void k_cast(const float* __restrict__ src, unsigned short* __restrict__ dst, int n4){
  int i = blockIdx.x*256 + threadIdx.x;
  if (i < n4){
    const float4 v = ((const float4*)src)[i];
    bfx4 o;
    o[0] = (short)f2bf(v.x); o[1] = (short)f2bf(v.y);
    o[2] = (short)f2bf(v.z); o[3] = (short)f2bf(v.w);
    *(bfx4*)(dst + (size_t)i*4) = o;
  }
}

// relk_bf: [272][64] zero-padded rows; relvT_bf: [64][288] = rel_v^T zero-padded cols
__global__ void k_relprep(const float* __restrict__ rlk, const float* __restrict__ rlv,
                          unsigned short* __restrict__ relk_bf, unsigned short* __restrict__ relvT_bf){
  int i = blockIdx.x*256 + threadIdx.x;
  if (i < 272*64){
    int r = i >> 6, d = i & 63;
    relk_bf[i] = (r < 257) ? f2bf(rlk[r*64 + d]) : (unsigned short)0;
  }
  if (i < 64*288){
    int d = i / 288, r = i % 288;
    relvT_bf[i] = (r < 257) ? f2bf(rlv[(size_t)r*64 + d]) : (unsigned short)0;
  }
}

// ---------------- QK projection: D[sb'][n] = x @ w^T ; Q scaled by 1/8 ----------------
__global__ __launch_bounds__(256) void k_qk(
    const unsigned short* __restrict__ xbf, const unsigned short* __restrict__ wq,
    const unsigned short* __restrict__ wk, unsigned short* __restrict__ Qb,
    unsigned short* __restrict__ Kb)
{
  const int w = threadIdx.x >> 6, lane = threadIdx.x & 63;
  const int p = lane & 15, g = lane >> 4;
  const int r0 = blockIdx.x*64 + w*16;
  const int b = r0 >> 10, s0 = r0 & 1023;
  const int n0 = blockIdx.y*64;
  const bool isQ = (n0 < 1024);
  const unsigned short* wsel = isQ ? wq : wk;
  const int nn0 = n0 & 1023;
  const f4 fz = {0.f,0.f,0.f,0.f};
  f4 acc[4] = {fz,fz,fz,fz};
  const unsigned short* arow = xbf + ((size_t)((s0 + p)*4 + b))*1024;
  for (int k0=0; k0<1024; k0+=32){
    bfx8 a = *(const bfx8*)(arow + k0 + 8*g);
#pragma unroll
    for (int f=0; f<4; ++f){
      bfx8 bb = *(const bfx8*)(wsel + (size_t)(nn0 + 16*f + p)*1024 + k0 + 8*g);
      acc[f] = mfma32(a, bb, acc[f]);
    }
  }
  unsigned short* dst = isQ ? Qb : Kb;
  const float scl = isQ ? 0.125f : 1.0f;
#pragma unroll
  for (int f=0; f<4; ++f){
    int col = nn0 + 16*f + p;
    int h = col >> 6, d = col & 63;
#pragma unroll
    for (int r=0; r<4; ++r){
      int srow = s0 + 4*g + r;
      dst[((size_t)(b*16 + h)*1024 + srow)*64 + d] = f2bf(acc[f][r] * scl);
    }
  }
}

// ---------------- V projection transposed: VT layout [b][h][d][s] ----------------
__global__ __launch_bounds__(256) void k_v(
    const unsigned short* __restrict__ xbf, const unsigned short* __restrict__ wv,
    unsigned short* __restrict__ VT)
{
  const int w = threadIdx.x >> 6, lane = threadIdx.x & 63;
  const int p = lane & 15, g = lane >> 4;
  const int n0 = blockIdx.x*64 + w*16;
  const int c0 = blockIdx.y*64;
  const int b = c0 >> 10, s0 = c0 & 1023;
  const f4 fz = {0.f,0.f,0.f,0.f};
  f4 acc[4] = {fz,fz,fz,fz};
  const unsigned short* arow = wv + (size_t)(n0 + p)*1024;
  for (int k0=0; k0<1024; k0+=32){
    bfx8 a = *(const bfx8*)(arow + k0 + 8*g);
#pragma unroll
    for (int f=0; f<4; ++f){
      bfx8 bb = *(const bfx8*)(xbf + ((size_t)((s0 + 16*f + p)*4 + b))*1024 + k0 + 8*g);
      acc[f] = mfma32(a, bb, acc[f]);
    }
  }
#pragma unroll
  for (int f=0; f<4; ++f){
#pragma unroll
    for (int r=0; r<4; ++r){
      int n = n0 + 4*g + r; int h = n >> 6, d = n & 63;
      int srow = s0 + 16*f + p;
      VT[((size_t)(b*16 + h)*64 + d)*1024 + srow] = f2bf(acc[f][r]);
    }
  }
}

// ---------------- Qr[bh][s][272] = Qscaled @ rel_k^T (bf16) ----------------
__global__ __launch_bounds__(256) void k_qr(
    const unsigned short* __restrict__ Qb, const unsigned short* __restrict__ relk,
    unsigned short* __restrict__ Qr)
{
  const int bh = blockIdx.x;
  const int w = threadIdx.x >> 6, lane = threadIdx.x & 63;
  const int p = lane & 15, g = lane >> 4;
  const int s0 = blockIdx.y*64 + w*16;
  const f4 fz = {0.f,0.f,0.f,0.f};
  bfx8 a0 = *(const bfx8*)(Qb + ((size_t)bh*1024 + s0 + p)*64 + 8*g);
  bfx8 a1 = *(const bfx8*)(Qb + ((size_t)bh*1024 + s0 + p)*64 + 32 + 8*g);
  for (int r0=0; r0<272; r0+=16){
    f4 acc = fz;
    bfx8 b0 = *(const bfx8*)(relk + (size_t)(r0 + p)*64 + 8*g);
    bfx8 b1 = *(const bfx8*)(relk + (size_t)(r0 + p)*64 + 32 + 8*g);
    acc = mfma32(a0, b0, acc);
    acc = mfma32(a1, b1, acc);
#pragma unroll
    for (int r=0; r<4; ++r)
      Qr[((size_t)bh*1024 + s0 + 4*g + r)*272 + r0 + p] = f2bf(acc[r]);
  }
}

// ---------------- softmax denominator: invS[b][s][t] = 1/sum_h exp(sc_h + rel) ----------------
// one short-lived block per (b, s-tile, t-tile); 8 waves x 2 heads; single reduce.
__global__ __launch_bounds__(512, 4) void k_s(
    const unsigned short* __restrict__ Qb, const unsigned short* __restrict__ Kb,
    const unsigned short* __restrict__ Qr, float* __restrict__ invS)
{
  __shared__ __align__(16) float red[8][256];
  const int pbid = blockIdx.x;           // (st<<8)|(tt<<2)|b
  const int b  = pbid & 3;
  const int tt = (pbid >> 2) & 63;
  const int st = pbid >> 8;
  const int s0 = st << 4, t0 = tt << 4;
  const int w = threadIdx.x >> 6, lane = threadIdx.x & 63;
  const int p = lane & 15, g = lane >> 4;
  const int s = s0 + p;
  const int h0 = w * 2;
  const f4 fz = {0.f,0.f,0.f,0.f};

  f4 ps = fz;
#pragma unroll
  for (int hh=0; hh<2; ++hh){
    size_t bh = (size_t)(b*16 + h0 + hh);
    const unsigned short* qb = Qb + (bh*1024 + s)*64;
    const unsigned short* kb = Kb + (bh*1024 + t0 + p)*64;
    bfx8 q0 = *(const bfx8*)(qb + 8*g);
    bfx8 q1 = *(const bfx8*)(qb + 32 + 8*g);
    bfx8 k0v = *(const bfx8*)(kb + 8*g);
    bfx8 k1v = *(const bfx8*)(kb + 32 + 8*g);
    f4 sc = mfma32(k1v, q1, mfma32(k0v, q0, fz));
    const unsigned short* qrow = Qr + (bh*1024 + s)*272;
#pragma unroll
    for (int r=0; r<4; ++r){
      int t = t0 + 4*g + r;
      int u = s - t + 128; u = u < 0 ? 0 : (u > 256 ? 256 : u);
      ps[r] += __expf(sc[r] + bf2f(qrow[u]));
    }
  }
  *(f4*)&red[w][lane*4] = ps;
  __syncthreads();
  if (w == 0){
    f4 S = *(const f4*)&red[0][lane*4];
#pragma unroll
    for (int ww=1; ww<8; ++ww){
      f4 t = *(const f4*)&red[ww][lane*4];
#pragma unroll
      for (int r=0; r<4; ++r) S[r] += t[r];
    }
    f4 inv;
#pragma unroll
    for (int r=0; r<4; ++r) inv[r] = 1.0f / S[r];
    *(f4*)(invS + ((size_t)b*1024 + s)*1024 + t0 + 4*g) = inv;
  }
}

// ---------------- far attention: barrier-free t-loop, invS preloaded ----------------
// grid 2048: pbid = (st<<5)|(hhalf<<4)|(part<<2)|b. 4 waves x 2 heads (wave-independent).
__global__ __launch_bounds__(256, 3) void k_far(
    const unsigned short* __restrict__ Qb, const unsigned short* __restrict__ Kb,
    const unsigned short* __restrict__ VT, const unsigned short* __restrict__ Qr,
    const float* __restrict__ invS, float* __restrict__ tails,
    unsigned short* __restrict__ op)
{
  __shared__ __align__(16) float slab[4][16][68];   // 17,408 B (epilogue only)
  const int pbid  = blockIdx.x;
  const int b     = pbid & 3;
  const int part  = (pbid >> 2) & 3;
  const int hhalf = (pbid >> 4) & 1;
  const int st    = pbid >> 5;
  const int s0 = st << 4;
  const int w = threadIdx.x >> 6, lane = threadIdx.x & 63;
  const int p = lane & 15, g = lane >> 4;
  const int s = s0 + p;
  const int h0 = hhalf*8 + w*2;
  const f4 fz = {0.f,0.f,0.f,0.f};

  bfx8 qf[2][2]; float qr0[2], qr1[2];
#pragma unroll
  for (int hh=0; hh<2; ++hh){
    size_t bh = (size_t)(b*16 + h0 + hh);
    size_t base = (bh*1024 + s)*64;
    qf[hh][0] = *(const bfx8*)(Qb + base + 8*g);
    qf[hh][1] = *(const bfx8*)(Qb + base + 32 + 8*g);
    qr0[hh] = bf2f(Qr[(bh*1024 + s)*272 + 0]);
    qr1[hh] = bf2f(Qr[(bh*1024 + s)*272 + 256]);
  }

  f4 o[2][4];
#pragma unroll
  for (int hh=0; hh<2; ++hh)
#pragma unroll
    for (int df=0; df<4; ++df) o[hh][df] = fz;
  float tl0[2] = {0.f,0.f};
  float tl1[2] = {0.f,0.f};

  const int lim = part*16 + 16;
  const int nlo = st - 8, nhi = st + 8;

  bfx8 kc[2][2]; bfx4 vc[2][4]; f4 is;
  bfx8 kn[2][2]; bfx4 vn[2][4]; f4 isn;

  int ti = part*16;
  if (ti >= nlo && ti <= nhi) ti = nhi + 1;
  if (ti < lim){
    const int t0 = ti << 4;
#pragma unroll
    for (int hh=0; hh<2; ++hh){
      size_t bh = (size_t)(b*16 + h0 + hh);
      kc[hh][0] = *(const bfx8*)(Kb + (bh*1024 + t0 + p)*64 + 8*g);
      kc[hh][1] = *(const bfx8*)(Kb + (bh*1024 + t0 + p)*64 + 32 + 8*g);
#pragma unroll
      for (int df=0; df<4; ++df)
        vc[hh][df] = *(const bfx4*)(VT + (bh*64 + df*16 + p)*1024 + t0 + 4*g);
    }
    is = *(const f4*)(invS + ((size_t)b*1024 + s)*1024 + t0 + 4*g);
  }

  while (ti < lim){
    int tn = ti + 1;
    if (tn >= nlo && tn <= nhi) tn = nhi + 1;
    if (tn < lim){
      const int t1 = tn << 4;
#pragma unroll
      for (int hh=0; hh<2; ++hh){
        size_t bh = (size_t)(b*16 + h0 + hh);
        kn[hh][0] = *(const bfx8*)(Kb + (bh*1024 + t1 + p)*64 + 8*g);
        kn[hh][1] = *(const bfx8*)(Kb + (bh*1024 + t1 + p)*64 + 32 + 8*g);
#pragma unroll
        for (int df=0; df<4; ++df)
          vn[hh][df] = *(const bfx4*)(VT + (bh*64 + df*16 + p)*1024 + t1 + 4*g);
      }
      isn = *(const f4*)(invS + ((size_t)b*1024 + s)*1024 + t1 + 4*g);
    }

    const bool hiSide = (ti < st);
#pragma unroll
    for (int hh=0; hh<2; ++hh){
      f4 sc = mfma32(kc[hh][1], qf[hh][1], mfma32(kc[hh][0], qf[hh][0], fz));
      const float qa = hiSide ? qr1[hh] : qr0[hh];
      f4 at;
#pragma unroll
      for (int r=0; r<4; ++r) at[r] = __expf(sc[r] + qa) * is[r];
      float tsum = at[0] + at[1] + at[2] + at[3];
      if (hiSide) tl1[hh] += tsum; else tl0[hh] += tsum;
      bfx4 pk;
#pragma unroll
      for (int r=0; r<4; ++r) pk[r] = (short)f2bf(at[r]);
#pragma unroll
      for (int df=0; df<4; ++df)
        o[hh][df] = mfma16(vc[hh][df], pk, o[hh][df]);
    }

    if (tn < lim){
#pragma unroll
      for (int hh=0; hh<2; ++hh){
        kc[hh][0] = kn[hh][0]; kc[hh][1] = kn[hh][1];
#pragma unroll
        for (int df=0; df<4; ++df) vc[hh][df] = vn[hh][df];
      }
      is = isn;
    }
    ti = tn;
  }

  // tail buckets for this part
#pragma unroll
  for (int hh=0; hh<2; ++hh){
    float v0 = tl0[hh];
    v0 += __shfl_xor(v0, 16, 64);
    v0 += __shfl_xor(v0, 32, 64);
    float v1 = tl1[hh];
    v1 += __shfl_xor(v1, 16, 64);
    v1 += __shfl_xor(v1, 32, 64);
    if (g == 0){
      size_t tix = ((size_t)(part*64 + b*16 + h0 + hh)*1024 + s)*2;
      tails[tix + 0] = v0;
      tails[tix + 1] = v1;
    }
  }

  // transpose epilogue -> bf16 partial output for this part
  unsigned short* dst = op + (size_t)part * 4194304;
#pragma unroll
  for (int hh=0; hh<2; ++hh){
    float (*tb)[68] = slab[w];
#pragma unroll
    for (int df=0; df<4; ++df)
      *(f4*)&tb[p][df*16 + 4*g] = o[hh][df];
    __syncthreads();
    const int srow = lane >> 2, quad = lane & 3;
    f4 r0 = *(const f4*)&tb[srow][quad*16 + 0];
    f4 r1 = *(const f4*)&tb[srow][quad*16 + 4];
    f4 r2 = *(const f4*)&tb[srow][quad*16 + 8];
    f4 r3 = *(const f4*)&tb[srow][quad*16 + 12];
    bfx8 pa, pb;
#pragma unroll
    for (int j=0; j<4; ++j){
      pa[j]   = (short)f2bf(r0[j]);
      pa[j+4] = (short)f2bf(r1[j]);
      pb[j]   = (short)f2bf(r2[j]);
      pb[j+4] = (short)f2bf(r3[j]);
    }
    size_t addr = ((size_t)b*1024 + s0 + srow)*1024 + (h0+hh)*64 + quad*16;
    *(bfx8*)(dst + addr) = pa;
    *(bfx8*)(dst + addr + 8) = pb;
    __syncthreads();
  }
}

// ---------------- near attention (17 tiles), barrier-free loop + fused rel_v GEMM ----------------
// 8 waves x 2 heads; skew rows wave-disjoint; invS preloaded.
__global__ __launch_bounds__(512, 2) void k_near(
    const unsigned short* __restrict__ Qb, const unsigned short* __restrict__ Kb,
    const unsigned short* __restrict__ VT, const unsigned short* __restrict__ Qr,
    const float* __restrict__ invS, const unsigned short* __restrict__ relvT,
    const float* __restrict__ relv, const float* __restrict__ tails,
    const unsigned short* __restrict__ op, unsigned short* __restrict__ out1)
{
  __shared__ __align__(16) unsigned short skew[256*264];  // 135,168 B; aliased as slabs at end
  const int pbid = blockIdx.x;
  const int xcd = pbid & 7;
  const int b = xcd >> 1;
  const int st = ((pbid >> 3) << 1) | (xcd & 1);
  const int s0 = st << 4;
  const int w = threadIdx.x >> 6;
  const int lane = threadIdx.x & 63;
  const int p = lane & 15, g = lane >> 4;
  const int s = s0 + p;
  const int h0 = w * 2;
  const f4 fz = {0.f,0.f,0.f,0.f};

  // zero own-wave skew rows (rows w*32 .. w*32+31) -- wave-local, no barrier needed
  {
    unsigned* zp = (unsigned*)skew + w*4224;
    for (int i = lane; i < 4224; i += 64) zp[i] = 0u;
  }

  bfx8 qf[2][2];
#pragma unroll
  for (int hh=0; hh<2; ++hh){
    size_t base = ((size_t)(b*16 + h0 + hh) * 1024 + s) * 64;
#pragma unroll
    for (int kf=0; kf<2; ++kf)
      qf[hh][kf] = *(const bfx8*)(Qb + base + kf*32 + 8*g);
  }

  f4 o[2][4];
#pragma unroll
  for (int hh=0; hh<2; ++hh)
#pragma unroll
    for (int df=0; df<4; ++df) o[hh][df] = fz;

  float tl0[2] = {0.f,0.f};
  float tl1[2] = {0.f,0.f};

  const int tlo = (st-8 < 0) ? 0 : st-8;
  const int thi = (st+8 > 63) ? 63 : st+8;
  const int tbase = tlo << 4;

  bfx8 kc[2][2]; bfx4 vc[2][4]; unsigned short qc[2][4]; f4 is;
  bfx8 kn[2][2]; bfx4 vn[2][4]; unsigned short qn[2][4]; f4 isn;

#pragma unroll
  for (int hh=0; hh<2; ++hh){
    size_t bh = (size_t)(b*16 + h0 + hh);
#pragma unroll
    for (int kf=0; kf<2; ++kf)
      kc[hh][kf] = *(const bfx8*)(Kb + (bh*1024 + tbase + p)*64 + kf*32 + 8*g);
#pragma unroll
    for (int df=0; df<4; ++df)
      vc[hh][df] = *(const bfx4*)(VT + (bh*64 + df*16 + p)*1024 + tbase + 4*g);
#pragma unroll
    for (int r=0; r<4; ++r){
      int t = tbase + 4*g + r;
      int u = s - t + 128; u = u < 0 ? 0 : (u > 256 ? 256 : u);
      qc[hh][r] = Qr[(bh*1024 + s)*272 + u];
    }
  }
  is = *(const f4*)(invS + ((size_t)b*1024 + s)*1024 + tbase + 4*g);

  for (int ti = tlo; ti <= thi; ++ti){
    const int t0 = ti << 4;

    if (ti < thi){
      const int t1 = t0 + 16;
#pragma unroll
      for (int hh=0; hh<2; ++hh){
        size_t bh = (size_t)(b*16 + h0 + hh);
#pragma unroll
        for (int kf=0; kf<2; ++kf)
          kn[hh][kf] = *(const bfx8*)(Kb + (bh*1024 + t1 + p)*64 + kf*32 + 8*g);
#pragma unroll
        for (int df=0; df<4; ++df)
          vn[hh][df] = *(const bfx4*)(VT + (bh*64 + df*16 + p)*1024 + t1 + 4*g);
#pragma unroll
        for (int r=0; r<4; ++r){
          int t = t1 + 4*g + r;
          int u = s - t + 128; u = u < 0 ? 0 : (u > 256 ? 256 : u);
          qn[hh][r] = Qr[(bh*1024 + s)*272 + u];
        }
      }
      isn = *(const f4*)(invS + ((size_t)b*1024 + s)*1024 + t1 + 4*g);
    }

#pragma unroll
    for (int hh=0; hh<2; ++hh){
      f4 sc = mfma32(kc[hh][1], qf[hh][1], mfma32(kc[hh][0], qf[hh][0], fz));
      f4 at;
#pragma unroll
      for (int r=0; r<4; ++r) at[r] = __expf(sc[r] + bf2f(qc[hh][r])) * is[r];
      const int row = (h0 + hh)*16 + p;
#pragma unroll
      for (int r=0; r<4; ++r){
        int t = t0 + 4*g + r;
        int u = s - t + 128;
        float a = at[r];
        if (u <= 0) tl0[hh] += a;
        else if (u >= 256) tl1[hh] += a;
        else skew[row*264 + u] = f2bf(a);
      }
      bfx4 pk;
#pragma unroll
      for (int r=0; r<4; ++r) pk[r] = (short)f2bf(at[r]);
#pragma unroll
      for (int df=0; df<4; ++df)
        o[hh][df] = mfma16(vc[hh][df], pk, o[hh][df]);
    }

    if (ti < thi){
#pragma unroll
      for (int hh=0; hh<2; ++hh){
#pragma unroll
        for (int kf=0; kf<2; ++kf) kc[hh][kf] = kn[hh][kf];
#pragma unroll
        for (int df=0; df<4; ++df) vc[hh][df] = vn[hh][df];
#pragma unroll
        for (int r=0; r<4; ++r) qc[hh][r] = qn[hh][r];
      }
      is = isn;
    }
  }

  __syncthreads();  // ensure all skew writes visible (safety; reads are wave-local)

  // ---- fused out2 = rel_v^T @ skew (own-wave rows only) ----
  f4 acc2[2][4];
#pragma unroll
  for (int hh=0; hh<2; ++hh)
#pragma unroll
    for (int df=0; df<4; ++df) acc2[hh][df] = fz;
#pragma unroll
  for (int k0=0; k0<256; k0+=32){
    bfx8 bb0 = *(const bfx8*)&skew[(h0*16 + p)*264 + k0 + 8*g];
    bfx8 bb1 = *(const bfx8*)&skew[((h0+1)*16 + p)*264 + k0 + 8*g];
#pragma unroll
    for (int df=0; df<4; ++df){
      bfx8 a = *(const bfx8*)(relvT + (size_t)(df*16 + p)*288 + k0 + 8*g);
      acc2[0][df] = mfma32(a, bb0, acc2[0][df]);
      acc2[1][df] = mfma32(a, bb1, acc2[1][df]);
    }
  }

  // ---- tails (near in-register + 4 far parts) x rel_v rows 0 / 256 ----
  f4 rv0[4], rv1[4];
#pragma unroll
  for (int df=0; df<4; ++df){
    rv0[df] = *(const f4*)(relv + df*16 + 4*g);
    rv1[df] = *(const f4*)(relv + 16384 + df*16 + 4*g);
  }
#pragma unroll
  for (int hh=0; hh<2; ++hh){
    float tv0 = tl0[hh];
    tv0 += __shfl_xor(tv0, 16, 64);
    tv0 += __shfl_xor(tv0, 32, 64);
    float tv1 = tl1[hh];
    tv1 += __shfl_xor(tv1, 16, 64);
    tv1 += __shfl_xor(tv1, 32, 64);
    size_t bh = (size_t)(b*16 + h0 + hh);
#pragma unroll
    for (int part=0; part<4; ++part){
      size_t tix = ((size_t)(part*64) + bh)*2048 + (size_t)s*2;
      tv0 += tails[tix + 0];
      tv1 += tails[tix + 1];
    }
#pragma unroll
    for (int df=0; df<4; ++df)
#pragma unroll
      for (int r=0; r<4; ++r)
        o[hh][df][r] += acc2[hh][df][r] + tv0*rv0[df][r] + tv1*rv1[df][r];
  }

  __syncthreads();  // skew GEMM reads complete; alias as transpose slabs

  float* slabBase = (float*)skew;
  float (*tb)[68] = (float(*)[68])(slabBase + w*(16*68));
#pragma unroll
  for (int hh=0; hh<2; ++hh){
#pragma unroll
    for (int df=0; df<4; ++df)
      *(f4*)&tb[p][df*16 + 4*g] = o[hh][df];
    __syncthreads();
    const int srow = lane >> 2, quad = lane & 3;
    f4 r0 = *(const f4*)&tb[srow][quad*16 + 0];
    f4 r1 = *(const f4*)&tb[srow][quad*16 + 4];
    f4 r2 = *(const f4*)&tb[srow][quad*16 + 8];
    f4 r3 = *(const f4*)&tb[srow][quad*16 + 12];
    size_t addr = ((size_t)b*1024 + s0 + srow)*1024 + (h0+hh)*64 + quad*16;
    bfx8 pa, pb;
#pragma unroll
    for (int j=0; j<4; ++j){
      float a0 = r0[j], a1 = r1[j], a2 = r2[j], a3 = r3[j];
#pragma unroll
      for (int part=0; part<4; ++part){
        const unsigned short* pp = op + (size_t)part*4194304 + addr;
        bfx8 q0 = *(const bfx8*)pp;
        bfx8 q1 = *(const bfx8*)(pp + 8);
        a0 += bf2f((unsigned short)q0[j]);
        a1 += bf2f((unsigned short)q0[j+4]);
        a2 += bf2f((unsigned short)q1[j]);
        a3 += bf2f((unsigned short)q1[j+4]);
      }
      pa[j]   = (short)f2bf(a0);
      pa[j+4] = (short)f2bf(a1);
      pb[j]   = (short)f2bf(a2);
      pb[j+4] = (short)f2bf(a3);
    }
    *(bfx8*)(out1 + addr) = pa;
    *(bfx8*)(out1 + addr + 8) = pb;
    __syncthreads();
  }
}

// ---------------- final projection: d_out[(s,b)][n] = out1 @ w_o^T + b_o ----------------
__global__ __launch_bounds__(256) void k_wo(
    const unsigned short* __restrict__ out1, const unsigned short* __restrict__ wo,
    const float* __restrict__ bo, float* __restrict__ dout)
{
  const int bm = blockIdx.x;
  const int b = bm >> 4;
  const int w = threadIdx.x >> 6, lane = threadIdx.x & 63;
  const int p = lane & 15, g = lane >> 4;
  const int s0 = (bm & 15)*64 + w*16;
  const int n0 = blockIdx.y*64;
  const f4 fz = {0.f,0.f,0.f,0.f};
  f4 acc[4] = {fz,fz,fz,fz};
  const unsigned short* arow = out1 + ((size_t)b*1024 + s0 + p)*1024;
  for (int k0=0; k0<1024; k0+=32){
    bfx8 a = *(const bfx8*)(arow + k0 + 8*g);
#pragma unroll
    for (int f=0; f<4; ++f){
      bfx8 bb = *(const bfx8*)(wo + (size_t)(n0 + 16*f + p)*1024 + k0 + 8*g);
      acc[f] = mfma32(a, bb, acc[f]);
    }
  }
#pragma unroll
  for (int f=0; f<4; ++f){
    int col = n0 + 16*f + p;
    float bias = bo[col];
#pragma unroll
    for (int r=0; r<4; ++r){
      int srow = s0 + 4*g + r;
      dout[((size_t)srow*4 + b)*1024 + col] = acc[f][r] + bias;
    }
  }
}

extern "C" void kernel_launch(void* const* d_in, const int* in_sizes, int n_in,
                              void* d_out, int out_size, void* d_ws, size_t ws_size,
                              hipStream_t stream){
  const float* x   = (const float*)d_in[0];
  const float* wq  = (const float*)d_in[1];
  const float* wk  = (const float*)d_in[2];
  const float* wv  = (const float*)d_in[3];
  const float* wo  = (const float*)d_in[4];
  const float* bo  = (const float*)d_in[5];
  const float* rlk = (const float*)d_in[6];
  const float* rlv = (const float*)d_in[7];
  char* ws = (char*)d_ws;

  unsigned short* x_bf    = (unsigned short*)(ws + 0);
  unsigned short* wq_bf   = (unsigned short*)(ws + 8388608);
  unsigned short* wk_bf   = (unsigned short*)(ws + 10485760);
  unsigned short* wv_bf   = (unsigned short*)(ws + 12582912);
  unsigned short* wo_bf   = (unsigned short*)(ws + 14680064);
  unsigned short* relk_bf = (unsigned short*)(ws + 16777216);
  unsigned short* relvT_bf= (unsigned short*)(ws + 16812032);
  unsigned short* Qb      = (unsigned short*)(ws + 16848896);
  unsigned short* Kb      = (unsigned short*)(ws + 25237504);
  unsigned short* VT      = (unsigned short*)(ws + 33626112);
  unsigned short* Qr      = (unsigned short*)(ws + 42014720);   // 35.65 MB -> 77666304
  float*          tails   = (float*)        (ws + 77666304);   // 2 MB -> 79763456
  unsigned short* op      = (unsigned short*)(ws + 79763456);   // 32 MB (4 parts) -> 113317888
  unsigned short* out1    = (unsigned short*)(ws + 113317888);  // 8 MB -> 121706496
  float*          invS    = (float*)        (ws + 121706496);  // 16 MB -> 138483712

  k_cast<<<4096, 256, 0, stream>>>(x,  x_bf,  1048576);
  k_cast<<<1024, 256, 0, stream>>>(wq, wq_bf, 262144);
  k_cast<<<1024, 256, 0, stream>>>(wk, wk_bf, 262144);
  k_cast<<<1024, 256, 0, stream>>>(wv, wv_bf, 262144);
  k_cast<<<1024, 256, 0, stream>>>(wo, wo_bf, 262144);
  k_relprep<<<72, 256, 0, stream>>>(rlk, rlv, relk_bf, relvT_bf);

  k_qk<<<dim3(64,32), 256, 0, stream>>>(x_bf, wq_bf, wk_bf, Qb, Kb);
  k_v <<<dim3(16,64), 256, 0, stream>>>(x_bf, wv_bf, VT);
  k_qr<<<dim3(64,16), 256, 0, stream>>>(Qb, relk_bf, Qr);

  k_s  <<<16384, 512, 0, stream>>>(Qb, Kb, Qr, invS);
  k_far<<<2048, 256, 0, stream>>>(Qb, Kb, VT, Qr, invS, tails, op);
  k_near<<<256, 512, 0, stream>>>(Qb, Kb, VT, Qr, invS, relvT_bf, rlv, tails, op, out1);
  k_wo<<<dim3(64,16), 256, 0, stream>>>(out1, wo_bf, bo, (float*)d_out);
}

// Round 6
// 758.276 us; speedup vs baseline: 1.0370x; 1.0370x over previous
//
#include <hip/hip_runtime.h>
#include <stdint.h>

#define DI __device__ __forceinline__

typedef __attribute__((ext_vector_type(8))) short bfx8;
typedef __attribute__((ext_vector_type(4))) short bfx4;
typedef __attribute__((ext_vector_type(4))) float f4;

DI unsigned short f2bf(float x){
  unsigned u = __float_as_uint(x);
  u = (u + 0x7FFFu + ((u >> 16) & 1u)) >> 16;
  return (unsigned short)u;
}
DI float bf2f(unsigned short h){ return __uint_as_float(((unsigned)h) << 16); }

DI f4 mfma32(bfx8 a, bfx8 b, f4 c){
  return __builtin_amdgcn_mfma_f32_16x16x32_bf16(a, b, c, 0, 0, 0);
}
#if __has_builtin(__builtin_amdgcn_mfma_f32_16x16x16bf16_1k)
DI f4 mfma16(bfx4 a, bfx4 b, f4 c){
  return __builtin_amdgcn_mfma_f32_16x16x16bf16_1k(a, b, c, 0, 0, 0);
}
#else
DI f4 mfma16(bfx4 a, bfx4 b, f4 c){
  f4 d = c;
  asm volatile("v_mfma_f32_16x16x16_bf16 %0, %1, %2, %0" : "+v"(d) : "v"(a), "v"(b));
  return d;
}
#endif

// ---------------- cast f32 -> bf16 (4-wide) ----------------
__global__ void k_cast(const float* __restrict__ src, unsigned short* __restrict__ dst, int n4){
  int i = blockIdx.x*256 + threadIdx.x;
  if (i < n4){
    const float4 v = ((const float4*)src)[i];
    bfx4 o;
    o[0] = (short)f2bf(v.x); o[1] = (short)f2bf(v.y);
    o[2] = (short)f2bf(v.z); o[3] = (short)f2bf(v.w);
    *(bfx4*)(dst + (size_t)i*4) = o;
  }
}

// relk_bf: [272][64] zero-padded rows; relvT_bf: [64][288] = rel_v^T zero-padded cols
__global__ void k_relprep(const float* __restrict__ rlk, const float* __restrict__ rlv,
                          unsigned short* __restrict__ relk_bf, unsigned short* __restrict__ relvT_bf){
  int i = blockIdx.x*256 + threadIdx.x;
  if (i < 272*64){
    int r = i >> 6, d = i & 63;
    relk_bf[i] = (r < 257) ? f2bf(rlk[r*64 + d]) : (unsigned short)0;
  }
  if (i < 64*288){
    int d = i / 288, r = i % 288;
    relvT_bf[i] = (r < 257) ? f2bf(rlv[(size_t)r*64 + d]) : (unsigned short)0;
  }
}

// ---------------- QK projection: D[sb'][n] = x @ w^T ; Q scaled by 1/8 ----------------
__global__ __launch_bounds__(256) void k_qk(
    const unsigned short* __restrict__ xbf, const unsigned short* __restrict__ wq,
    const unsigned short* __restrict__ wk, unsigned short* __restrict__ Qb,
    unsigned short* __restrict__ Kb)
{
  const int w = threadIdx.x >> 6, lane = threadIdx.x & 63;
  const int p = lane & 15, g = lane >> 4;
  const int r0 = blockIdx.x*64 + w*16;
  const int b = r0 >> 10, s0 = r0 & 1023;
  const int n0 = blockIdx.y*64;
  const bool isQ = (n0 < 1024);
  const unsigned short* wsel = isQ ? wq : wk;
  const int nn0 = n0 & 1023;
  const f4 fz = {0.f,0.f,0.f,0.f};
  f4 acc[4] = {fz,fz,fz,fz};
  const unsigned short* arow = xbf + ((size_t)((s0 + p)*4 + b))*1024;
  for (int k0=0; k0<1024; k0+=32){
    bfx8 a = *(const bfx8*)(arow + k0 + 8*g);
#pragma unroll
    for (int f=0; f<4; ++f){
      bfx8 bb = *(const bfx8*)(wsel + (size_t)(nn0 + 16*f + p)*1024 + k0 + 8*g);
      acc[f] = mfma32(a, bb, acc[f]);
    }
  }
  unsigned short* dst = isQ ? Qb : Kb;
  const float scl = isQ ? 0.125f : 1.0f;
#pragma unroll
  for (int f=0; f<4; ++f){
    int col = nn0 + 16*f + p;
    int h = col >> 6, d = col & 63;
#pragma unroll
    for (int r=0; r<4; ++r){
      int srow = s0 + 4*g + r;
      dst[((size_t)(b*16 + h)*1024 + srow)*64 + d] = f2bf(acc[f][r] * scl);
    }
  }
}

// ---------------- V projection transposed: VT layout [b][h][d][s] ----------------
__global__ __launch_bounds__(256) void k_v(
    const unsigned short* __restrict__ xbf, const unsigned short* __restrict__ wv,
    unsigned short* __restrict__ VT)
{
  const int w = threadIdx.x >> 6, lane = threadIdx.x & 63;
  const int p = lane & 15, g = lane >> 4;
  const int n0 = blockIdx.x*64 + w*16;
  const int c0 = blockIdx.y*64;
  const int b = c0 >> 10, s0 = c0 & 1023;
  const f4 fz = {0.f,0.f,0.f,0.f};
  f4 acc[4] = {fz,fz,fz,fz};
  const unsigned short* arow = wv + (size_t)(n0 + p)*1024;
  for (int k0=0; k0<1024; k0+=32){
    bfx8 a = *(const bfx8*)(arow + k0 + 8*g);
#pragma unroll
    for (int f=0; f<4; ++f){
      bfx8 bb = *(const bfx8*)(xbf + ((size_t)((s0 + 16*f + p)*4 + b))*1024 + k0 + 8*g);
      acc[f] = mfma32(a, bb, acc[f]);
    }
  }
#pragma unroll
  for (int f=0; f<4; ++f){
#pragma unroll
    for (int r=0; r<4; ++r){
      int n = n0 + 4*g + r; int h = n >> 6, d = n & 63;
      int srow = s0 + 16*f + p;
      VT[((size_t)(b*16 + h)*64 + d)*1024 + srow] = f2bf(acc[f][r]);
    }
  }
}

// ---------------- Qr2[b][s][u(272)][h(16)] = Qscaled @ rel_k^T (bf16, head-last layout) ----------------
__global__ __launch_bounds__(256) void k_qr(
    const unsigned short* __restrict__ Qb, const unsigned short* __restrict__ relk,
    unsigned short* __restrict__ Qr2)
{
  const int bh = blockIdx.x;
  const int b = bh >> 4, h = bh & 15;
  const int w = threadIdx.x >> 6, lane = threadIdx.x & 63;
  const int p = lane & 15, g = lane >> 4;
  const int s0 = blockIdx.y*64 + w*16;
  const f4 fz = {0.f,0.f,0.f,0.f};
  bfx8 a0 = *(const bfx8*)(Qb + ((size_t)bh*1024 + s0 + p)*64 + 8*g);
  bfx8 a1 = *(const bfx8*)(Qb + ((size_t)bh*1024 + s0 + p)*64 + 32 + 8*g);
  for (int r0=0; r0<272; r0+=16){
    f4 acc = fz;
    bfx8 b0 = *(const bfx8*)(relk + (size_t)(r0 + p)*64 + 8*g);
    bfx8 b1 = *(const bfx8*)(relk + (size_t)(r0 + p)*64 + 32 + 8*g);
    acc = mfma32(a0, b0, acc);
    acc = mfma32(a1, b1, acc);
#pragma unroll
    for (int r=0; r<4; ++r)
      Qr2[(((size_t)b*1024 + s0 + 4*g + r)*272 + r0 + p)*16 + h] = f2bf(acc[r]);
  }
}

// ---------------- softmax denominator: invS[b][s][t] = 1/sum_h exp(sc_h + rel_h) ----------------
// ONE WAVE per (b, s-tile, t-tile), all 16 heads in-lane. No LDS, no barriers, no cross-lane.
// Block = 4 waves sharing (b, st), 4 consecutive tt. Rel addends: 2 bfx8 loads per (lane,r).
__global__ __launch_bounds__(256, 3) void k_s(
    const unsigned short* __restrict__ Qb, const unsigned short* __restrict__ Kb,
    const unsigned short* __restrict__ Qr2, float* __restrict__ invS)
{
  const int pbid = blockIdx.x;            // (st<<6)|(ttg<<2)|b
  const int b   = pbid & 3;
  const int ttg = (pbid >> 2) & 15;
  const int st  = pbid >> 6;
  const int w = threadIdx.x >> 6, lane = threadIdx.x & 63;
  const int tt = ttg*4 + w;
  const int p = lane & 15, g = lane >> 4;
  const int s0 = st << 4, t0 = tt << 4;
  const int s = s0 + p;
  const f4 fz = {0.f,0.f,0.f,0.f};

  // rel addends for all 16 heads, per r (32B contiguous in head-last layout)
  bfx8 rv[4][2];
#pragma unroll
  for (int r=0; r<4; ++r){
    int t = t0 + 4*g + r;
    int u = s - t + 128; u = u < 0 ? 0 : (u > 256 ? 256 : u);
    const unsigned short* q = Qr2 + (((size_t)b*1024 + s)*272 + u)*16;
    rv[r][0] = *(const bfx8*)q;
    rv[r][1] = *(const bfx8*)(q + 8);
  }

  f4 ps = fz;
#pragma unroll
  for (int hg=0; hg<2; ++hg){
    f4 sc[8];
#pragma unroll
    for (int h8=0; h8<8; ++h8){
      size_t bh = (size_t)(b*16 + hg*8 + h8);
      const unsigned short* qb = Qb + (bh*1024 + s)*64;
      const unsigned short* kb = Kb + (bh*1024 + t0 + p)*64;
      bfx8 q0 = *(const bfx8*)(qb + 8*g);
      bfx8 q1 = *(const bfx8*)(qb + 32 + 8*g);
      bfx8 k0 = *(const bfx8*)(kb + 8*g);
      bfx8 k1 = *(const bfx8*)(kb + 32 + 8*g);
      sc[h8] = mfma32(k1, q1, mfma32(k0, q0, fz));
    }
#pragma unroll
    for (int h8=0; h8<8; ++h8)
#pragma unroll
      for (int r=0; r<4; ++r)
        ps[r] += __expf(sc[h8][r] + bf2f((unsigned short)rv[r][hg][h8]));
  }

  f4 inv;
#pragma unroll
  for (int r=0; r<4; ++r) inv[r] = 1.0f / ps[r];
  *(f4*)(invS + ((size_t)b*1024 + s)*1024 + t0 + 4*g) = inv;
}

// ---------------- far attention: barrier-free t-loop, invS preloaded ----------------
// grid 2048: pbid = (st<<5)|(hhalf<<4)|(part<<2)|b. 4 waves x 2 heads (wave-independent).
__global__ __launch_bounds__(256, 3) void k_far(
    const unsigned short* __restrict__ Qb, const unsigned short* __restrict__ Kb,
    const unsigned short* __restrict__ VT, const unsigned short* __restrict__ Qr2,
    const float* __restrict__ invS, float* __restrict__ tails,
    unsigned short* __restrict__ op)
{
  __shared__ __align__(16) float slab[4][16][68];   // 17,408 B (epilogue only)
  const int pbid  = blockIdx.x;
  const int b     = pbid & 3;
  const int part  = (pbid >> 2) & 3;
  const int hhalf = (pbid >> 4) & 1;
  const int st    = pbid >> 5;
  const int s0 = st << 4;
  const int w = threadIdx.x >> 6, lane = threadIdx.x & 63;
  const int p = lane & 15, g = lane >> 4;
  const int s = s0 + p;
  const int h0 = hhalf*8 + w*2;
  const f4 fz = {0.f,0.f,0.f,0.f};

  bfx8 qf[2][2]; float qr0[2], qr1[2];
#pragma unroll
  for (int hh=0; hh<2; ++hh){
    size_t bh = (size_t)(b*16 + h0 + hh);
    size_t base = (bh*1024 + s)*64;
    qf[hh][0] = *(const bfx8*)(Qb + base + 8*g);
    qf[hh][1] = *(const bfx8*)(Qb + base + 32 + 8*g);
    qr0[hh] = bf2f(Qr2[(((size_t)b*1024 + s)*272 + 0)*16 + (h0+hh)]);
    qr1[hh] = bf2f(Qr2[(((size_t)b*1024 + s)*272 + 256)*16 + (h0+hh)]);
  }

  f4 o[2][4];
#pragma unroll
  for (int hh=0; hh<2; ++hh)
#pragma unroll
    for (int df=0; df<4; ++df) o[hh][df] = fz;
  float tl0[2] = {0.f,0.f};
  float tl1[2] = {0.f,0.f};

  const int lim = part*16 + 16;
  const int nlo = st - 8, nhi = st + 8;

  bfx8 kc[2][2]; bfx4 vc[2][4]; f4 is;
  bfx8 kn[2][2]; bfx4 vn[2][4]; f4 isn;

  int ti = part*16;
  if (ti >= nlo && ti <= nhi) ti = nhi + 1;
  if (ti < lim){
    const int t0 = ti << 4;
#pragma unroll
    for (int hh=0; hh<2; ++hh){
      size_t bh = (size_t)(b*16 + h0 + hh);
      kc[hh][0] = *(const bfx8*)(Kb + (bh*1024 + t0 + p)*64 + 8*g);
      kc[hh][1] = *(const bfx8*)(Kb + (bh*1024 + t0 + p)*64 + 32 + 8*g);
#pragma unroll
      for (int df=0; df<4; ++df)
        vc[hh][df] = *(const bfx4*)(VT + (bh*64 + df*16 + p)*1024 + t0 + 4*g);
    }
    is = *(const f4*)(invS + ((size_t)b*1024 + s)*1024 + t0 + 4*g);
  }

  while (ti < lim){
    int tn = ti + 1;
    if (tn >= nlo && tn <= nhi) tn = nhi + 1;
    if (tn < lim){
      const int t1 = tn << 4;
#pragma unroll
      for (int hh=0; hh<2; ++hh){
        size_t bh = (size_t)(b*16 + h0 + hh);
        kn[hh][0] = *(const bfx8*)(Kb + (bh*1024 + t1 + p)*64 + 8*g);
        kn[hh][1] = *(const bfx8*)(Kb + (bh*1024 + t1 + p)*64 + 32 + 8*g);
#pragma unroll
        for (int df=0; df<4; ++df)
          vn[hh][df] = *(const bfx4*)(VT + (bh*64 + df*16 + p)*1024 + t1 + 4*g);
      }
      isn = *(const f4*)(invS + ((size_t)b*1024 + s)*1024 + t1 + 4*g);
    }

    const bool hiSide = (ti < st);
#pragma unroll
    for (int hh=0; hh<2; ++hh){
      f4 sc = mfma32(kc[hh][1], qf[hh][1], mfma32(kc[hh][0], qf[hh][0], fz));
      const float qa = hiSide ? qr1[hh] : qr0[hh];
      f4 at;
#pragma unroll
      for (int r=0; r<4; ++r) at[r] = __expf(sc[r] + qa) * is[r];
      float tsum = at[0] + at[1] + at[2] + at[3];
      if (hiSide) tl1[hh] += tsum; else tl0[hh] += tsum;
      bfx4 pk;
#pragma unroll
      for (int r=0; r<4; ++r) pk[r] = (short)f2bf(at[r]);
#pragma unroll
      for (int df=0; df<4; ++df)
        o[hh][df] = mfma16(vc[hh][df], pk, o[hh][df]);
    }

    if (tn < lim){
#pragma unroll
      for (int hh=0; hh<2; ++hh){
        kc[hh][0] = kn[hh][0]; kc[hh][1] = kn[hh][1];
#pragma unroll
        for (int df=0; df<4; ++df) vc[hh][df] = vn[hh][df];
      }
      is = isn;
    }
    ti = tn;
  }

  // tail buckets for this part
#pragma unroll
  for (int hh=0; hh<2; ++hh){
    float v0 = tl0[hh];
    v0 += __shfl_xor(v0, 16, 64);
    v0 += __shfl_xor(v0, 32, 64);
    float v1 = tl1[hh];
    v1 += __shfl_xor(v1, 16, 64);
    v1 += __shfl_xor(v1, 32, 64);
    if (g == 0){
      size_t tix = ((size_t)(part*64 + b*16 + h0 + hh)*1024 + s)*2;
      tails[tix + 0] = v0;
      tails[tix + 1] = v1;
    }
  }

  // transpose epilogue -> bf16 partial output for this part
  unsigned short* dst = op + (size_t)part * 4194304;
#pragma unroll
  for (int hh=0; hh<2; ++hh){
    float (*tb)[68] = slab[w];
#pragma unroll
    for (int df=0; df<4; ++df)
      *(f4*)&tb[p][df*16 + 4*g] = o[hh][df];
    __syncthreads();
    const int srow = lane >> 2, quad = lane & 3;
    f4 r0 = *(const f4*)&tb[srow][quad*16 + 0];
    f4 r1 = *(const f4*)&tb[srow][quad*16 + 4];
    f4 r2 = *(const f4*)&tb[srow][quad*16 + 8];
    f4 r3 = *(const f4*)&tb[srow][quad*16 + 12];
    bfx8 pa, pb;
#pragma unroll
    for (int j=0; j<4; ++j){
      pa[j]   = (short)f2bf(r0[j]);
      pa[j+4] = (short)f2bf(r1[j]);
      pb[j]   = (short)f2bf(r2[j]);
      pb[j+4] = (short)f2bf(r3[j]);
    }
    size_t addr = ((size_t)b*1024 + s0 + srow)*1024 + (h0+hh)*64 + quad*16;
    *(bfx8*)(dst + addr) = pa;
    *(bfx8*)(dst + addr + 8) = pb;
    __syncthreads();
  }
}

// ---------------- near attention (17 tiles), barrier-free loop + fused rel_v GEMM ----------------
// 8 waves x 2 heads; skew rows wave-disjoint; invS preloaded.
__global__ __launch_bounds__(512, 2) void k_near(
    const unsigned short* __restrict__ Qb, const unsigned short* __restrict__ Kb,
    const unsigned short* __restrict__ VT, const unsigned short* __restrict__ Qr2,
    const float* __restrict__ invS, const unsigned short* __restrict__ relvT,
    const float* __restrict__ relv, const float* __restrict__ tails,
    const unsigned short* __restrict__ op, unsigned short* __restrict__ out1)
{
  __shared__ __align__(16) unsigned short skew[256*264];  // 135,168 B; aliased as slabs at end
  const int pbid = blockIdx.x;
  const int xcd = pbid & 7;
  const int b = xcd >> 1;
  const int st = ((pbid >> 3) << 1) | (xcd & 1);
  const int s0 = st << 4;
  const int w = threadIdx.x >> 6;
  const int lane = threadIdx.x & 63;
  const int p = lane & 15, g = lane >> 4;
  const int s = s0 + p;
  const int h0 = w * 2;
  const f4 fz = {0.f,0.f,0.f,0.f};

  // zero own-wave skew rows (rows w*32 .. w*32+31) -- wave-local, no barrier needed
  {
    unsigned* zp = (unsigned*)skew + w*4224;
    for (int i = lane; i < 4224; i += 64) zp[i] = 0u;
  }

  bfx8 qf[2][2];
#pragma unroll
  for (int hh=0; hh<2; ++hh){
    size_t base = ((size_t)(b*16 + h0 + hh) * 1024 + s) * 64;
#pragma unroll
    for (int kf=0; kf<2; ++kf)
      qf[hh][kf] = *(const bfx8*)(Qb + base + kf*32 + 8*g);
  }

  f4 o[2][4];
#pragma unroll
  for (int hh=0; hh<2; ++hh)
#pragma unroll
    for (int df=0; df<4; ++df) o[hh][df] = fz;

  float tl0[2] = {0.f,0.f};
  float tl1[2] = {0.f,0.f};

  const int tlo = (st-8 < 0) ? 0 : st-8;
  const int thi = (st+8 > 63) ? 63 : st+8;
  const int tbase = tlo << 4;

  bfx8 kc[2][2]; bfx4 vc[2][4]; unsigned short qc[2][4]; f4 is;
  bfx8 kn[2][2]; bfx4 vn[2][4]; unsigned short qn[2][4]; f4 isn;

#pragma unroll
  for (int hh=0; hh<2; ++hh){
    size_t bh = (size_t)(b*16 + h0 + hh);
#pragma unroll
    for (int kf=0; kf<2; ++kf)
      kc[hh][kf] = *(const bfx8*)(Kb + (bh*1024 + tbase + p)*64 + kf*32 + 8*g);
#pragma unroll
    for (int df=0; df<4; ++df)
      vc[hh][df] = *(const bfx4*)(VT + (bh*64 + df*16 + p)*1024 + tbase + 4*g);
#pragma unroll
    for (int r=0; r<4; ++r){
      int t = tbase + 4*g + r;
      int u = s - t + 128; u = u < 0 ? 0 : (u > 256 ? 256 : u);
      qc[hh][r] = Qr2[(((size_t)b*1024 + s)*272 + u)*16 + (h0+hh)];
    }
  }
  is = *(const f4*)(invS + ((size_t)b*1024 + s)*1024 + tbase + 4*g);

  for (int ti = tlo; ti <= thi; ++ti){
    const int t0 = ti << 4;

    if (ti < thi){
      const int t1 = t0 + 16;
#pragma unroll
      for (int hh=0; hh<2; ++hh){
        size_t bh = (size_t)(b*16 + h0 + hh);
#pragma unroll
        for (int kf=0; kf<2; ++kf)
          kn[hh][kf] = *(const bfx8*)(Kb + (bh*1024 + t1 + p)*64 + kf*32 + 8*g);
#pragma unroll
        for (int df=0; df<4; ++df)
          vn[hh][df] = *(const bfx4*)(VT + (bh*64 + df*16 + p)*1024 + t1 + 4*g);
#pragma unroll
        for (int r=0; r<4; ++r){
          int t = t1 + 4*g + r;
          int u = s - t + 128; u = u < 0 ? 0 : (u > 256 ? 256 : u);
          qn[hh][r] = Qr2[(((size_t)b*1024 + s)*272 + u)*16 + (h0+hh)];
        }
      }
      isn = *(const f4*)(invS + ((size_t)b*1024 + s)*1024 + t1 + 4*g);
    }

#pragma unroll
    for (int hh=0; hh<2; ++hh){
      f4 sc = mfma32(kc[hh][1], qf[hh][1], mfma32(kc[hh][0], qf[hh][0], fz));
      f4 at;
#pragma unroll
      for (int r=0; r<4; ++r) at[r] = __expf(sc[r] + bf2f(qc[hh][r])) * is[r];
      const int row = (h0 + hh)*16 + p;
#pragma unroll
      for (int r=0; r<4; ++r){
        int t = t0 + 4*g + r;
        int u = s - t + 128;
        float a = at[r];
        if (u <= 0) tl0[hh] += a;
        else if (u >= 256) tl1[hh] += a;
        else skew[row*264 + u] = f2bf(a);
      }
      bfx4 pk;
#pragma unroll
      for (int r=0; r<4; ++r) pk[r] = (short)f2bf(at[r]);
#pragma unroll
      for (int df=0; df<4; ++df)
        o[hh][df] = mfma16(vc[hh][df], pk, o[hh][df]);
    }

    if (ti < thi){
#pragma unroll
      for (int hh=0; hh<2; ++hh){
#pragma unroll
        for (int kf=0; kf<2; ++kf) kc[hh][kf] = kn[hh][kf];
#pragma unroll
        for (int df=0; df<4; ++df) vc[hh][df] = vn[hh][df];
#pragma unroll
        for (int r=0; r<4; ++r) qc[hh][r] = qn[hh][r];
      }
      is = isn;
    }
  }

  __syncthreads();  // ensure all skew writes visible (safety; reads are wave-local)

  // ---- fused out2 = rel_v^T @ skew (own-wave rows only) ----
  f4 acc2[2][4];
#pragma unroll
  for (int hh=0; hh<2; ++hh)
#pragma unroll
    for (int df=0; df<4; ++df) acc2[hh][df] = fz;
#pragma unroll
  for (int k0=0; k0<256; k0+=32){
    bfx8 bb0 = *(const bfx8*)&skew[(h0*16 + p)*264 + k0 + 8*g];
    bfx8 bb1 = *(const bfx8*)&skew[((h0+1)*16 + p)*264 + k0 + 8*g];
#pragma unroll
    for (int df=0; df<4; ++df){
      bfx8 a = *(const bfx8*)(relvT + (size_t)(df*16 + p)*288 + k0 + 8*g);
      acc2[0][df] = mfma32(a, bb0, acc2[0][df]);
      acc2[1][df] = mfma32(a, bb1, acc2[1][df]);
    }
  }

  // ---- tails (near in-register + 4 far parts) x rel_v rows 0 / 256 ----
  f4 rv0[4], rv1[4];
#pragma unroll
  for (int df=0; df<4; ++df){
    rv0[df] = *(const f4*)(relv + df*16 + 4*g);
    rv1[df] = *(const f4*)(relv + 16384 + df*16 + 4*g);
  }
#pragma unroll
  for (int hh=0; hh<2; ++hh){
    float tv0 = tl0[hh];
    tv0 += __shfl_xor(tv0, 16, 64);
    tv0 += __shfl_xor(tv0, 32, 64);
    float tv1 = tl1[hh];
    tv1 += __shfl_xor(tv1, 16, 64);
    tv1 += __shfl_xor(tv1, 32, 64);
    size_t bh = (size_t)(b*16 + h0 + hh);
#pragma unroll
    for (int part=0; part<4; ++part){
      size_t tix = ((size_t)(part*64) + bh)*2048 + (size_t)s*2;
      tv0 += tails[tix + 0];
      tv1 += tails[tix + 1];
    }
#pragma unroll
    for (int df=0; df<4; ++df)
#pragma unroll
      for (int r=0; r<4; ++r)
        o[hh][df][r] += acc2[hh][df][r] + tv0*rv0[df][r] + tv1*rv1[df][r];
  }

  __syncthreads();  // skew GEMM reads complete; alias as transpose slabs

  float* slabBase = (float*)skew;
  float (*tb)[68] = (float(*)[68])(slabBase + w*(16*68));
#pragma unroll
  for (int hh=0; hh<2; ++hh){
#pragma unroll
    for (int df=0; df<4; ++df)
      *(f4*)&tb[p][df*16 + 4*g] = o[hh][df];
    __syncthreads();
    const int srow = lane >> 2, quad = lane & 3;
    f4 r0 = *(const f4*)&tb[srow][quad*16 + 0];
    f4 r1 = *(const f4*)&tb[srow][quad*16 + 4];
    f4 r2 = *(const f4*)&tb[srow][quad*16 + 8];
    f4 r3 = *(const f4*)&tb[srow][quad*16 + 12];
    size_t addr = ((size_t)b*1024 + s0 + srow)*1024 + (h0+hh)*64 + quad*16;
    bfx8 pa, pb;
#pragma unroll
    for (int j=0; j<4; ++j){
      float a0 = r0[j], a1 = r1[j], a2 = r2[j], a3 = r3[j];
#pragma unroll
      for (int part=0; part<4; ++part){
        const unsigned short* pp = op + (size_t)part*4194304 + addr;
        bfx8 q0 = *(const bfx8*)pp;
        bfx8 q1 = *(const bfx8*)(pp + 8);
        a0 += bf2f((unsigned short)q0[j]);
        a1 += bf2f((unsigned short)q0[j+4]);
        a2 += bf2f((unsigned short)q1[j]);
        a3 += bf2f((unsigned short)q1[j+4]);
      }
      pa[j]   = (short)f2bf(a0);
      pa[j+4] = (short)f2bf(a1);
      pb[j]   = (short)f2bf(a2);
      pb[j+4] = (short)f2bf(a3);
    }
    *(bfx8*)(out1 + addr) = pa;
    *(bfx8*)(out1 + addr + 8) = pb;
    __syncthreads();
  }
}

// ---------------- final projection: d_out[(s,b)][n] = out1 @ w_o^T + b_o ----------------
__global__ __launch_bounds__(256) void k_wo(
    const unsigned short* __restrict__ out1, const unsigned short* __restrict__ wo,
    const float* __restrict__ bo, float* __restrict__ dout)
{
  const int bm = blockIdx.x;
  const int b = bm >> 4;
  const int w = threadIdx.x >> 6, lane = threadIdx.x & 63;
  const int p = lane & 15, g = lane >> 4;
  const int s0 = (bm & 15)*64 + w*16;
  const int n0 = blockIdx.y*64;
  const f4 fz = {0.f,0.f,0.f,0.f};
  f4 acc[4] = {fz,fz,fz,fz};
  const unsigned short* arow = out1 + ((size_t)b*1024 + s0 + p)*1024;
  for (int k0=0; k0<1024; k0+=32){
    bfx8 a = *(const bfx8*)(arow + k0 + 8*g);
#pragma unroll
    for (int f=0; f<4; ++f){
      bfx8 bb = *(const bfx8*)(wo + (size_t)(n0 + 16*f + p)*1024 + k0 + 8*g);
      acc[f] = mfma32(a, bb, acc[f]);
    }
  }
#pragma unroll
  for (int f=0; f<4; ++f){
    int col = n0 + 16*f + p;
    float bias = bo[col];
#pragma unroll
    for (int r=0; r<4; ++r){
      int srow = s0 + 4*g + r;
      dout[((size_t)srow*4 + b)*1024 + col] = acc[f][r] + bias;
    }
  }
}

extern "C" void kernel_launch(void* const* d_in, const int* in_sizes, int n_in,
                              void* d_out, int out_size, void* d_ws, size_t ws_size,
                              hipStream_t stream){
  const float* x   = (const float*)d_in[0];
  const float* wq  = (const float*)d_in[1];
  const float* wk  = (const float*)d_in[2];
  const float* wv  = (const float*)d_in[3];
  const float* wo  = (const float*)d_in[4];
  const float* bo  = (const float*)d_in[5];
  const float* rlk = (const float*)d_in[6];
  const float* rlv = (const float*)d_in[7];
  char* ws = (char*)d_ws;

  unsigned short* x_bf    = (unsigned short*)(ws + 0);
  unsigned short* wq_bf   = (unsigned short*)(ws + 8388608);
  unsigned short* wk_bf   = (unsigned short*)(ws + 10485760);
  unsigned short* wv_bf   = (unsigned short*)(ws + 12582912);
  unsigned short* wo_bf   = (unsigned short*)(ws + 14680064);
  unsigned short* relk_bf = (unsigned short*)(ws + 16777216);
  unsigned short* relvT_bf= (unsigned short*)(ws + 16812032);
  unsigned short* Qb      = (unsigned short*)(ws + 16848896);
  unsigned short* Kb      = (unsigned short*)(ws + 25237504);
  unsigned short* VT      = (unsigned short*)(ws + 33626112);
  unsigned short* Qr2     = (unsigned short*)(ws + 42014720);   // 35.65 MB -> 77666304
  float*          tails   = (float*)        (ws + 77666304);   // 2 MB -> 79763456
  unsigned short* op      = (unsigned short*)(ws + 79763456);   // 32 MB (4 parts) -> 113317888
  unsigned short* out1    = (unsigned short*)(ws + 113317888);  // 8 MB -> 121706496
  float*          invS    = (float*)        (ws + 121706496);  // 16 MB -> 138483712

  k_cast<<<4096, 256, 0, stream>>>(x,  x_bf,  1048576);
  k_cast<<<1024, 256, 0, stream>>>(wq, wq_bf, 262144);
  k_cast<<<1024, 256, 0, stream>>>(wk, wk_bf, 262144);
  k_cast<<<1024, 256, 0, stream>>>(wv, wv_bf, 262144);
  k_cast<<<1024, 256, 0, stream>>>(wo, wo_bf, 262144);
  k_relprep<<<72, 256, 0, stream>>>(rlk, rlv, relk_bf, relvT_bf);

  k_qk<<<dim3(64,32), 256, 0, stream>>>(x_bf, wq_bf, wk_bf, Qb, Kb);
  k_v <<<dim3(16,64), 256, 0, stream>>>(x_bf, wv_bf, VT);
  k_qr<<<dim3(64,16), 256, 0, stream>>>(Qb, relk_bf, Qr2);

  k_s  <<<4096, 256, 0, stream>>>(Qb, Kb, Qr2, invS);
  k_far<<<2048, 256, 0, stream>>>(Qb, Kb, VT, Qr2, invS, tails, op);
  k_near<<<256, 512, 0, stream>>>(Qb, Kb, VT, Qr2, invS, relvT_bf, rlv, tails, op, out1);
  k_wo<<<dim3(64,16), 256, 0, stream>>>(out1, wo_bf, bo, (float*)d_out);
}

// Round 7
// 526.349 us; speedup vs baseline: 1.4939x; 1.4406x over previous
//
#include <hip/hip_runtime.h>
#include <stdint.h>

#define DI __device__ __forceinline__

typedef __attribute__((ext_vector_type(8))) short bfx8;
typedef __attribute__((ext_vector_type(4))) short bfx4;
typedef __attribute__((ext_vector_type(4))) float f4;

DI unsigned short f2bf(float x){
  unsigned u = __float_as_uint(x);
  u = (u + 0x7FFFu + ((u >> 16) & 1u)) >> 16;
  return (unsigned short)u;
}
DI float bf2f(unsigned short h){ return __uint_as_float(((unsigned)h) << 16); }

DI f4 mfma32(bfx8 a, bfx8 b, f4 c){
  return __builtin_amdgcn_mfma_f32_16x16x32_bf16(a, b, c, 0, 0, 0);
}
#if __has_builtin(__builtin_amdgcn_mfma_f32_16x16x16bf16_1k)
DI f4 mfma16(bfx4 a, bfx4 b, f4 c){
  return __builtin_amdgcn_mfma_f32_16x16x16bf16_1k(a, b, c, 0, 0, 0);
}
#else
DI f4 mfma16(bfx4 a, bfx4 b, f4 c){
  f4 d = c;
  asm volatile("v_mfma_f32_16x16x16_bf16 %0, %1, %2, %0" : "+v"(d) : "v"(a), "v"(b));
  return d;
}
#endif

// Fragment layouts (all 16-bit elems):
//   Qf/Kf[bh][tile][lane][16]: elem[kf*8+j] = M[tile*16 + (lane&15)][kf*32 + 8*(lane>>4) + j]
//   Vf  [bh][tile][lane][16]: elem[df*4+j] = V[tile*16 + 4*(lane>>4) + j][df*16 + (lane&15)]
//   ivf [b][tt][st][lane][4]: elem[r] = 1/S at (s = st*16 + (lane&15), t = tt*16 + 4*(lane>>4) + r)

// ---------------- cast f32 -> bf16 (4-wide) ----------------
__global__ void k_cast(const float* __restrict__ src, unsigned short* __restrict__ dst, int n4){
  int i = blockIdx.x*256 + threadIdx.x;
  if (i < n4){
    const float4 v = ((const float4*)src)[i];
    bfx4 o;
    o[0] = (short)f2bf(v.x); o[1] = (short)f2bf(v.y);
    o[2] = (short)f2bf(v.z); o[3] = (short)f2bf(v.w);
    *(bfx4*)(dst + (size_t)i*4) = o;
  }
}

// relk_bf: [272][64] zero-padded rows; relvT_bf: [64][288] = rel_v^T zero-padded cols
__global__ void k_relprep(const float* __restrict__ rlk, const float* __restrict__ rlv,
                          unsigned short* __restrict__ relk_bf, unsigned short* __restrict__ relvT_bf){
  int i = blockIdx.x*256 + threadIdx.x;
  if (i < 272*64){
    int r = i >> 6, d = i & 63;
    relk_bf[i] = (r < 257) ? f2bf(rlk[r*64 + d]) : (unsigned short)0;
  }
  if (i < 64*288){
    int d = i / 288, r = i % 288;
    relvT_bf[i] = (r < 257) ? f2bf(rlv[(size_t)r*64 + d]) : (unsigned short)0;
  }
}

// ---------------- QK projection -> fragment layout Qf/Kf ----------------
__global__ __launch_bounds__(256) void k_qk(
    const unsigned short* __restrict__ xbf, const unsigned short* __restrict__ wq,
    const unsigned short* __restrict__ wk, unsigned short* __restrict__ Qf,
    unsigned short* __restrict__ Kf)
{
  __shared__ __align__(16) float slab[4][16][68];
  const int w = threadIdx.x >> 6, lane = threadIdx.x & 63;
  const int p = lane & 15, g = lane >> 4;
  const int r0 = blockIdx.x*64 + w*16;
  const int b = r0 >> 10, s0 = r0 & 1023;
  const int n0 = blockIdx.y*64;
  const bool isQ = (n0 < 1024);
  const unsigned short* wsel = isQ ? wq : wk;
  const int nn0 = n0 & 1023;
  const f4 fz = {0.f,0.f,0.f,0.f};
  f4 acc[4] = {fz,fz,fz,fz};
  const unsigned short* arow = xbf + ((size_t)((s0 + p)*4 + b))*1024;
  for (int k0=0; k0<1024; k0+=32){
    bfx8 a = *(const bfx8*)(arow + k0 + 8*g);
#pragma unroll
    for (int f=0; f<4; ++f){
      bfx8 bb = *(const bfx8*)(wsel + (size_t)(nn0 + 16*f + p)*1024 + k0 + 8*g);
      acc[f] = mfma32(a, bb, acc[f]);
    }
  }
  const float scl = isQ ? 0.125f : 1.0f;
  float (*tb)[68] = slab[w];
#pragma unroll
  for (int f=0; f<4; ++f)
#pragma unroll
    for (int r=0; r<4; ++r)
      tb[4*g + r][16*f + p] = acc[f][r] * scl;
  __syncthreads();
  f4 v0 = *(const f4*)&tb[p][8*g];
  f4 v1 = *(const f4*)&tb[p][8*g + 4];
  f4 v2 = *(const f4*)&tb[p][32 + 8*g];
  f4 v3 = *(const f4*)&tb[p][32 + 8*g + 4];
  bfx8 lo, hi;
#pragma unroll
  for (int j=0; j<4; ++j){
    lo[j]   = (short)f2bf(v0[j]);
    lo[j+4] = (short)f2bf(v1[j]);
    hi[j]   = (short)f2bf(v2[j]);
    hi[j+4] = (short)f2bf(v3[j]);
  }
  const int h = nn0 >> 6;
  const int tile = s0 >> 4;
  unsigned short* dst = isQ ? Qf : Kf;
  size_t fb = ((size_t)(b*16 + h)*64 + tile)*1024 + (size_t)lane*16;
  *(bfx8*)(dst + fb) = lo;
  *(bfx8*)(dst + fb + 8) = hi;
}

// ---------------- V projection -> fragment layout Vf ----------------
__global__ __launch_bounds__(256) void k_v(
    const unsigned short* __restrict__ xbf, const unsigned short* __restrict__ wv,
    unsigned short* __restrict__ Vf)
{
  __shared__ __align__(16) float lds[64][68];  // [d][t-local]
  const int w = threadIdx.x >> 6, lane = threadIdx.x & 63;
  const int p = lane & 15, g = lane >> 4;
  const int n0 = blockIdx.x*64 + w*16;         // head = blockIdx.x, d-local = w*16..+15
  const int c0 = blockIdx.y*64;
  const int b = c0 >> 10, s0 = c0 & 1023;      // t range s0..s0+63
  const f4 fz = {0.f,0.f,0.f,0.f};
  f4 acc[4] = {fz,fz,fz,fz};
  const unsigned short* arow = wv + (size_t)(n0 + p)*1024;
  for (int k0=0; k0<1024; k0+=32){
    bfx8 a = *(const bfx8*)(arow + k0 + 8*g);
#pragma unroll
    for (int f=0; f<4; ++f){
      bfx8 bb = *(const bfx8*)(xbf + ((size_t)((s0 + 16*f + p)*4 + b))*1024 + k0 + 8*g);
      acc[f] = mfma32(a, bb, acc[f]);
    }
  }
  // acc[f][r] = V[t = s0+16f+p][d-local = w*16+4g+r]
#pragma unroll
  for (int f=0; f<4; ++f)
#pragma unroll
    for (int r=0; r<4; ++r)
      lds[w*16 + 4*g + r][16*f + p] = acc[f][r];
  __syncthreads();
  // wave w writes t-tile (s0>>4)+w
  f4 vv[4];
#pragma unroll
  for (int df=0; df<4; ++df)
    vv[df] = *(const f4*)&lds[df*16 + p][w*16 + 4*g];
  bfx8 lo, hi;
#pragma unroll
  for (int j=0; j<4; ++j){
    lo[j]   = (short)f2bf(vv[0][j]);
    lo[j+4] = (short)f2bf(vv[1][j]);
    hi[j]   = (short)f2bf(vv[2][j]);
    hi[j+4] = (short)f2bf(vv[3][j]);
  }
  const int tile = (s0 >> 4) + w;
  size_t fb = ((size_t)(b*16 + blockIdx.x)*64 + tile)*1024 + (size_t)lane*16;
  *(bfx8*)(Vf + fb) = lo;
  *(bfx8*)(Vf + fb + 8) = hi;
}

// ---------------- Qr2[b][s][u(272)][h(16)] = Qscaled @ rel_k^T (bf16, head-last layout) ----------------
__global__ __launch_bounds__(256) void k_qr(
    const unsigned short* __restrict__ Qf, const unsigned short* __restrict__ relk,
    unsigned short* __restrict__ Qr2)
{
  const int bh = blockIdx.x;
  const int b = bh >> 4, h = bh & 15;
  const int w = threadIdx.x >> 6, lane = threadIdx.x & 63;
  const int p = lane & 15, g = lane >> 4;
  const int s0 = blockIdx.y*64 + w*16;
  const int tile = s0 >> 4;
  const f4 fz = {0.f,0.f,0.f,0.f};
  size_t fb = ((size_t)bh*64 + tile)*1024 + (size_t)lane*16;
  bfx8 a0 = *(const bfx8*)(Qf + fb);
  bfx8 a1 = *(const bfx8*)(Qf + fb + 8);
  for (int r0=0; r0<272; r0+=16){
    f4 acc = fz;
    bfx8 b0 = *(const bfx8*)(relk + (size_t)(r0 + p)*64 + 8*g);
    bfx8 b1 = *(const bfx8*)(relk + (size_t)(r0 + p)*64 + 32 + 8*g);
    acc = mfma32(a0, b0, acc);
    acc = mfma32(a1, b1, acc);
#pragma unroll
    for (int r=0; r<4; ++r)
      Qr2[(((size_t)b*1024 + s0 + 4*g + r)*272 + r0 + p)*16 + h] = f2bf(acc[r]);
  }
}

// ---------------- softmax denominator -> ivf (fragment layout, coalesced) ----------------
// ONE WAVE per (b, s-tile, t-tile), all 16 heads in-lane. No LDS, no barriers, no cross-lane.
__global__ __launch_bounds__(256, 3) void k_s(
    const unsigned short* __restrict__ Qf, const unsigned short* __restrict__ Kf,
    const unsigned short* __restrict__ Qr2, float* __restrict__ ivf)
{
  const int pbid = blockIdx.x;            // (st<<6)|(ttg<<2)|b
  const int b   = pbid & 3;
  const int ttg = (pbid >> 2) & 15;
  const int st  = pbid >> 6;
  const int w = threadIdx.x >> 6, lane = threadIdx.x & 63;
  const int tt = ttg*4 + w;
  const int p = lane & 15, g = lane >> 4;
  const int s0 = st << 4, t0 = tt << 4;
  const int s = s0 + p;
  const f4 fz = {0.f,0.f,0.f,0.f};

  bfx8 rv[4][2];
#pragma unroll
  for (int r=0; r<4; ++r){
    int t = t0 + 4*g + r;
    int u = s - t + 128; u = u < 0 ? 0 : (u > 256 ? 256 : u);
    const unsigned short* q = Qr2 + (((size_t)b*1024 + s)*272 + u)*16;
    rv[r][0] = *(const bfx8*)q;
    rv[r][1] = *(const bfx8*)(q + 8);
  }

  f4 ps = fz;
#pragma unroll
  for (int hg=0; hg<2; ++hg){
    f4 sc[8];
#pragma unroll
    for (int h8=0; h8<8; ++h8){
      size_t bh = (size_t)(b*16 + hg*8 + h8);
      size_t qb = (bh*64 + st)*1024 + (size_t)lane*16;
      size_t kb = (bh*64 + tt)*1024 + (size_t)lane*16;
      bfx8 q0 = *(const bfx8*)(Qf + qb);
      bfx8 q1 = *(const bfx8*)(Qf + qb + 8);
      bfx8 k0 = *(const bfx8*)(Kf + kb);
      bfx8 k1 = *(const bfx8*)(Kf + kb + 8);
      sc[h8] = mfma32(k1, q1, mfma32(k0, q0, fz));
    }
#pragma unroll
    for (int h8=0; h8<8; ++h8)
#pragma unroll
      for (int r=0; r<4; ++r)
        ps[r] += __expf(sc[h8][r] + bf2f((unsigned short)rv[r][hg][h8]));
  }

  f4 inv;
#pragma unroll
  for (int r=0; r<4; ++r) inv[r] = 1.0f / ps[r];
  *(f4*)(ivf + (((size_t)(b*64 + tt)*64 + st)*64 + lane)*4) = inv;
}

// ---------------- far attention: barrier-free, fragment loads, balanced strided far list ----------------
__global__ __launch_bounds__(256, 3) void k_far(
    const unsigned short* __restrict__ Qf, const unsigned short* __restrict__ Kf,
    const unsigned short* __restrict__ Vf, const unsigned short* __restrict__ Qr2,
    const float* __restrict__ ivf, float* __restrict__ tails,
    unsigned short* __restrict__ op)
{
  __shared__ __align__(16) float slab[4][16][68];
  const int pbid  = blockIdx.x;
  const int b     = pbid & 3;
  const int part  = (pbid >> 2) & 3;
  const int hhalf = (pbid >> 4) & 1;
  const int st    = pbid >> 5;
  const int s0 = st << 4;
  const int w = threadIdx.x >> 6, lane = threadIdx.x & 63;
  const int p = lane & 15, g = lane >> 4;
  const int s = s0 + p;
  const int h0 = hhalf*8 + w*2;
  const f4 fz = {0.f,0.f,0.f,0.f};

  bfx8 qf[2][2]; float qr0[2], qr1[2];
#pragma unroll
  for (int hh=0; hh<2; ++hh){
    size_t bh = (size_t)(b*16 + h0 + hh);
    size_t qb = (bh*64 + st)*1024 + (size_t)lane*16;
    qf[hh][0] = *(const bfx8*)(Qf + qb);
    qf[hh][1] = *(const bfx8*)(Qf + qb + 8);
    qr0[hh] = bf2f(Qr2[(((size_t)b*1024 + s)*272 + 0)*16 + (h0+hh)]);
    qr1[hh] = bf2f(Qr2[(((size_t)b*1024 + s)*272 + 256)*16 + (h0+hh)]);
  }

  f4 o[2][4];
#pragma unroll
  for (int hh=0; hh<2; ++hh)
#pragma unroll
    for (int df=0; df<4; ++df) o[hh][df] = fz;
  float tl0[2] = {0.f,0.f};
  float tl1[2] = {0.f,0.f};

  const int tlo = (st-8 < 0) ? 0 : st-8;
  const int thi = (st+8 > 63) ? 63 : st+8;
  const int nband = thi - tlo + 1;
  const int nfar = 64 - nband;

  bfx8 kc[2][2]; bfx4 vc[2][4]; f4 is;
  bfx8 kn[2][2]; bfx4 vn[2][4]; f4 isn;

  int idx = part;
  {
    const int ti = (idx < tlo) ? idx : idx + nband;
#pragma unroll
    for (int hh=0; hh<2; ++hh){
      size_t fb = (((size_t)(b*16 + h0 + hh))*64 + ti)*1024 + (size_t)lane*16;
      kc[hh][0] = *(const bfx8*)(Kf + fb);
      kc[hh][1] = *(const bfx8*)(Kf + fb + 8);
#pragma unroll
      for (int df=0; df<4; ++df)
        vc[hh][df] = *(const bfx4*)(Vf + fb + df*4);
    }
    is = *(const f4*)(ivf + (((size_t)(b*64 + ti)*64 + st)*64 + lane)*4);
  }

  while (idx < nfar){
    const int idn = idx + 4;
    if (idn < nfar){
      const int tn = (idn < tlo) ? idn : idn + nband;
#pragma unroll
      for (int hh=0; hh<2; ++hh){
        size_t fb = (((size_t)(b*16 + h0 + hh))*64 + tn)*1024 + (size_t)lane*16;
        kn[hh][0] = *(const bfx8*)(Kf + fb);
        kn[hh][1] = *(const bfx8*)(Kf + fb + 8);
#pragma unroll
        for (int df=0; df<4; ++df)
          vn[hh][df] = *(const bfx4*)(Vf + fb + df*4);
      }
      isn = *(const f4*)(ivf + (((size_t)(b*64 + tn)*64 + st)*64 + lane)*4);
    }

    const int ti = (idx < tlo) ? idx : idx + nband;
    const bool hiSide = (ti < st);
#pragma unroll
    for (int hh=0; hh<2; ++hh){
      f4 sc = mfma32(kc[hh][1], qf[hh][1], mfma32(kc[hh][0], qf[hh][0], fz));
      const float qa = hiSide ? qr1[hh] : qr0[hh];
      f4 at;
#pragma unroll
      for (int r=0; r<4; ++r) at[r] = __expf(sc[r] + qa) * is[r];
      float tsum = at[0] + at[1] + at[2] + at[3];
      if (hiSide) tl1[hh] += tsum; else tl0[hh] += tsum;
      bfx4 pk;
#pragma unroll
      for (int r=0; r<4; ++r) pk[r] = (short)f2bf(at[r]);
#pragma unroll
      for (int df=0; df<4; ++df)
        o[hh][df] = mfma16(vc[hh][df], pk, o[hh][df]);
    }

    if (idn < nfar){
#pragma unroll
      for (int hh=0; hh<2; ++hh){
        kc[hh][0] = kn[hh][0]; kc[hh][1] = kn[hh][1];
#pragma unroll
        for (int df=0; df<4; ++df) vc[hh][df] = vn[hh][df];
      }
      is = isn;
    }
    idx = idn;
  }

  // tail buckets for this part
#pragma unroll
  for (int hh=0; hh<2; ++hh){
    float v0 = tl0[hh];
    v0 += __shfl_xor(v0, 16, 64);
    v0 += __shfl_xor(v0, 32, 64);
    float v1 = tl1[hh];
    v1 += __shfl_xor(v1, 16, 64);
    v1 += __shfl_xor(v1, 32, 64);
    if (g == 0){
      size_t tix = ((size_t)(part*64 + b*16 + h0 + hh)*1024 + s)*2;
      tails[tix + 0] = v0;
      tails[tix + 1] = v1;
    }
  }

  // transpose epilogue -> bf16 partial output for this part
  unsigned short* dst = op + (size_t)part * 4194304;
#pragma unroll
  for (int hh=0; hh<2; ++hh){
    float (*tb)[68] = slab[w];
#pragma unroll
    for (int df=0; df<4; ++df)
      *(f4*)&tb[p][df*16 + 4*g] = o[hh][df];
    __syncthreads();
    const int srow = lane >> 2, quad = lane & 3;
    f4 r0 = *(const f4*)&tb[srow][quad*16 + 0];
    f4 r1 = *(const f4*)&tb[srow][quad*16 + 4];
    f4 r2 = *(const f4*)&tb[srow][quad*16 + 8];
    f4 r3 = *(const f4*)&tb[srow][quad*16 + 12];
    bfx8 pa, pb;
#pragma unroll
    for (int j=0; j<4; ++j){
      pa[j]   = (short)f2bf(r0[j]);
      pa[j+4] = (short)f2bf(r1[j]);
      pb[j]   = (short)f2bf(r2[j]);
      pb[j+4] = (short)f2bf(r3[j]);
    }
    size_t addr = ((size_t)b*1024 + s0 + srow)*1024 + (h0+hh)*64 + quad*16;
    *(bfx8*)(dst + addr) = pa;
    *(bfx8*)(dst + addr + 8) = pb;
    __syncthreads();
  }
}

// ---------------- near attention (17 tiles) + fused rel_v GEMM + final out1 ----------------
__global__ __launch_bounds__(512, 2) void k_near(
    const unsigned short* __restrict__ Qf, const unsigned short* __restrict__ Kf,
    const unsigned short* __restrict__ Vf, const unsigned short* __restrict__ Qr2,
    const float* __restrict__ ivf, const unsigned short* __restrict__ relvT,
    const float* __restrict__ relv, const float* __restrict__ tails,
    const unsigned short* __restrict__ op, unsigned short* __restrict__ out1)
{
  __shared__ __align__(16) unsigned short skew[256*264];  // 135,168 B; aliased as slabs at end
  const int pbid = blockIdx.x;
  const int xcd = pbid & 7;
  const int b = xcd >> 1;
  const int st = ((pbid >> 3) << 1) | (xcd & 1);
  const int s0 = st << 4;
  const int w = threadIdx.x >> 6;
  const int lane = threadIdx.x & 63;
  const int p = lane & 15, g = lane >> 4;
  const int s = s0 + p;
  const int h0 = w * 2;
  const f4 fz = {0.f,0.f,0.f,0.f};

  {
    unsigned* zp = (unsigned*)skew + w*4224;
    for (int i = lane; i < 4224; i += 64) zp[i] = 0u;
  }

  bfx8 qf[2][2];
#pragma unroll
  for (int hh=0; hh<2; ++hh){
    size_t qb = (((size_t)(b*16 + h0 + hh))*64 + st)*1024 + (size_t)lane*16;
    qf[hh][0] = *(const bfx8*)(Qf + qb);
    qf[hh][1] = *(const bfx8*)(Qf + qb + 8);
  }

  f4 o[2][4];
#pragma unroll
  for (int hh=0; hh<2; ++hh)
#pragma unroll
    for (int df=0; df<4; ++df) o[hh][df] = fz;

  float tl0[2] = {0.f,0.f};
  float tl1[2] = {0.f,0.f};

  const int tlo = (st-8 < 0) ? 0 : st-8;
  const int thi = (st+8 > 63) ? 63 : st+8;

  bfx8 kc[2][2]; bfx4 vc[2][4]; unsigned short qc[2][4]; f4 is;
  bfx8 kn[2][2]; bfx4 vn[2][4]; unsigned short qn[2][4]; f4 isn;

#pragma unroll
  for (int hh=0; hh<2; ++hh){
    size_t bh = (size_t)(b*16 + h0 + hh);
    size_t fb = (bh*64 + tlo)*1024 + (size_t)lane*16;
    kc[hh][0] = *(const bfx8*)(Kf + fb);
    kc[hh][1] = *(const bfx8*)(Kf + fb + 8);
#pragma unroll
    for (int df=0; df<4; ++df)
      vc[hh][df] = *(const bfx4*)(Vf + fb + df*4);
#pragma unroll
    for (int r=0; r<4; ++r){
      int t = (tlo<<4) + 4*g + r;
      int u = s - t + 128; u = u < 0 ? 0 : (u > 256 ? 256 : u);
      qc[hh][r] = Qr2[(((size_t)b*1024 + s)*272 + u)*16 + (h0+hh)];
    }
  }
  is = *(const f4*)(ivf + (((size_t)(b*64 + tlo)*64 + st)*64 + lane)*4);

  for (int ti = tlo; ti <= thi; ++ti){
    const int t0 = ti << 4;

    if (ti < thi){
      const int tn = ti + 1;
#pragma unroll
      for (int hh=0; hh<2; ++hh){
        size_t bh = (size_t)(b*16 + h0 + hh);
        size_t fb = (bh*64 + tn)*1024 + (size_t)lane*16;
        kn[hh][0] = *(const bfx8*)(Kf + fb);
        kn[hh][1] = *(const bfx8*)(Kf + fb + 8);
#pragma unroll
        for (int df=0; df<4; ++df)
          vn[hh][df] = *(const bfx4*)(Vf + fb + df*4);
#pragma unroll
        for (int r=0; r<4; ++r){
          int t = (tn<<4) + 4*g + r;
          int u = s - t + 128; u = u < 0 ? 0 : (u > 256 ? 256 : u);
          qn[hh][r] = Qr2[(((size_t)b*1024 + s)*272 + u)*16 + (h0+hh)];
        }
      }
      isn = *(const f4*)(ivf + (((size_t)(b*64 + tn)*64 + st)*64 + lane)*4);
    }

#pragma unroll
    for (int hh=0; hh<2; ++hh){
      f4 sc = mfma32(kc[hh][1], qf[hh][1], mfma32(kc[hh][0], qf[hh][0], fz));
      f4 at;
#pragma unroll
      for (int r=0; r<4; ++r) at[r] = __expf(sc[r] + bf2f(qc[hh][r])) * is[r];
      const int row = (h0 + hh)*16 + p;
#pragma unroll
      for (int r=0; r<4; ++r){
        int t = t0 + 4*g + r;
        int u = s - t + 128;
        float a = at[r];
        if (u <= 0) tl0[hh] += a;
        else if (u >= 256) tl1[hh] += a;
        else skew[row*264 + u] = f2bf(a);
      }
      bfx4 pk;
#pragma unroll
      for (int r=0; r<4; ++r) pk[r] = (short)f2bf(at[r]);
#pragma unroll
      for (int df=0; df<4; ++df)
        o[hh][df] = mfma16(vc[hh][df], pk, o[hh][df]);
    }

    if (ti < thi){
#pragma unroll
      for (int hh=0; hh<2; ++hh){
#pragma unroll
        for (int kf=0; kf<2; ++kf) kc[hh][kf] = kn[hh][kf];
#pragma unroll
        for (int df=0; df<4; ++df) vc[hh][df] = vn[hh][df];
#pragma unroll
        for (int r=0; r<4; ++r) qc[hh][r] = qn[hh][r];
      }
      is = isn;
    }
  }

  __syncthreads();

  // ---- fused out2 = rel_v^T @ skew (own-wave rows only) ----
  f4 acc2[2][4];
#pragma unroll
  for (int hh=0; hh<2; ++hh)
#pragma unroll
    for (int df=0; df<4; ++df) acc2[hh][df] = fz;
#pragma unroll
  for (int k0=0; k0<256; k0+=32){
    bfx8 bb0 = *(const bfx8*)&skew[(h0*16 + p)*264 + k0 + 8*g];
    bfx8 bb1 = *(const bfx8*)&skew[((h0+1)*16 + p)*264 + k0 + 8*g];
#pragma unroll
    for (int df=0; df<4; ++df){
      bfx8 a = *(const bfx8*)(relvT + (size_t)(df*16 + p)*288 + k0 + 8*g);
      acc2[0][df] = mfma32(a, bb0, acc2[0][df]);
      acc2[1][df] = mfma32(a, bb1, acc2[1][df]);
    }
  }

  f4 rv0[4], rv1[4];
#pragma unroll
  for (int df=0; df<4; ++df){
    rv0[df] = *(const f4*)(relv + df*16 + 4*g);
    rv1[df] = *(const f4*)(relv + 16384 + df*16 + 4*g);
  }
#pragma unroll
  for (int hh=0; hh<2; ++hh){
    float tv0 = tl0[hh];
    tv0 += __shfl_xor(tv0, 16, 64);
    tv0 += __shfl_xor(tv0, 32, 64);
    float tv1 = tl1[hh];
    tv1 += __shfl_xor(tv1, 16, 64);
    tv1 += __shfl_xor(tv1, 32, 64);
    size_t bh = (size_t)(b*16 + h0 + hh);
#pragma unroll
    for (int part=0; part<4; ++part){
      size_t tix = ((size_t)(part*64) + bh)*2048 + (size_t)s*2;
      tv0 += tails[tix + 0];
      tv1 += tails[tix + 1];
    }
#pragma unroll
    for (int df=0; df<4; ++df)
#pragma unroll
      for (int r=0; r<4; ++r)
        o[hh][df][r] += acc2[hh][df][r] + tv0*rv0[df][r] + tv1*rv1[df][r];
  }

  __syncthreads();

  float* slabBase = (float*)skew;
  float (*tb)[68] = (float(*)[68])(slabBase + w*(16*68));
#pragma unroll
  for (int hh=0; hh<2; ++hh){
#pragma unroll
    for (int df=0; df<4; ++df)
      *(f4*)&tb[p][df*16 + 4*g] = o[hh][df];
    __syncthreads();
    const int srow = lane >> 2, quad = lane & 3;
    f4 r0 = *(const f4*)&tb[srow][quad*16 + 0];
    f4 r1 = *(const f4*)&tb[srow][quad*16 + 4];
    f4 r2 = *(const f4*)&tb[srow][quad*16 + 8];
    f4 r3 = *(const f4*)&tb[srow][quad*16 + 12];
    size_t addr = ((size_t)b*1024 + s0 + srow)*1024 + (h0+hh)*64 + quad*16;
    bfx8 pa, pb;
#pragma unroll
    for (int j=0; j<4; ++j){
      float a0 = r0[j], a1 = r1[j], a2 = r2[j], a3 = r3[j];
#pragma unroll
      for (int part=0; part<4; ++part){
        const unsigned short* pp = op + (size_t)part*4194304 + addr;
        bfx8 q0 = *(const bfx8*)pp;
        bfx8 q1 = *(const bfx8*)(pp + 8);
        a0 += bf2f((unsigned short)q0[j]);
        a1 += bf2f((unsigned short)q0[j+4]);
        a2 += bf2f((unsigned short)q1[j]);
        a3 += bf2f((unsigned short)q1[j+4]);
      }
      pa[j]   = (short)f2bf(a0);
      pa[j+4] = (short)f2bf(a1);
      pb[j]   = (short)f2bf(a2);
      pb[j+4] = (short)f2bf(a3);
    }
    *(bfx8*)(out1 + addr) = pa;
    *(bfx8*)(out1 + addr + 8) = pb;
    __syncthreads();
  }
}

// ---------------- final projection: d_out[(s,b)][n] = out1 @ w_o^T + b_o ----------------
__global__ __launch_bounds__(256) void k_wo(
    const unsigned short* __restrict__ out1, const unsigned short* __restrict__ wo,
    const float* __restrict__ bo, float* __restrict__ dout)
{
  const int bm = blockIdx.x;
  const int b = bm >> 4;
  const int w = threadIdx.x >> 6, lane = threadIdx.x & 63;
  const int p = lane & 15, g = lane >> 4;
  const int s0 = (bm & 15)*64 + w*16;
  const int n0 = blockIdx.y*64;
  const f4 fz = {0.f,0.f,0.f,0.f};
  f4 acc[4] = {fz,fz,fz,fz};
  const unsigned short* arow = out1 + ((size_t)b*1024 + s0 + p)*1024;
  for (int k0=0; k0<1024; k0+=32){
    bfx8 a = *(const bfx8*)(arow + k0 + 8*g);
#pragma unroll
    for (int f=0; f<4; ++f){
      bfx8 bb = *(const bfx8*)(wo + (size_t)(n0 + 16*f + p)*1024 + k0 + 8*g);
      acc[f] = mfma32(a, bb, acc[f]);
    }
  }
#pragma unroll
  for (int f=0; f<4; ++f){
    int col = n0 + 16*f + p;
    float bias = bo[col];
#pragma unroll
    for (int r=0; r<4; ++r){
      int srow = s0 + 4*g + r;
      dout[((size_t)srow*4 + b)*1024 + col] = acc[f][r] + bias;
    }
  }
}

extern "C" void kernel_launch(void* const* d_in, const int* in_sizes, int n_in,
                              void* d_out, int out_size, void* d_ws, size_t ws_size,
                              hipStream_t stream){
  const float* x   = (const float*)d_in[0];
  const float* wq  = (const float*)d_in[1];
  const float* wk  = (const float*)d_in[2];
  const float* wv  = (const float*)d_in[3];
  const float* wo  = (const float*)d_in[4];
  const float* bo  = (const float*)d_in[5];
  const float* rlk = (const float*)d_in[6];
  const float* rlv = (const float*)d_in[7];
  char* ws = (char*)d_ws;

  unsigned short* x_bf    = (unsigned short*)(ws + 0);
  unsigned short* wq_bf   = (unsigned short*)(ws + 8388608);
  unsigned short* wk_bf   = (unsigned short*)(ws + 10485760);
  unsigned short* wv_bf   = (unsigned short*)(ws + 12582912);
  unsigned short* wo_bf   = (unsigned short*)(ws + 14680064);
  unsigned short* relk_bf = (unsigned short*)(ws + 16777216);
  unsigned short* relvT_bf= (unsigned short*)(ws + 16812032);
  unsigned short* Qf      = (unsigned short*)(ws + 16848896);   // fragment layout
  unsigned short* Kf      = (unsigned short*)(ws + 25237504);   // fragment layout
  unsigned short* Vf      = (unsigned short*)(ws + 33626112);   // fragment layout
  unsigned short* Qr2     = (unsigned short*)(ws + 42014720);   // 35.65 MB -> 77666304
  float*          tails   = (float*)        (ws + 77666304);   // 2 MB -> 79763456
  unsigned short* op      = (unsigned short*)(ws + 79763456);   // 32 MB (4 parts) -> 113317888
  unsigned short* out1    = (unsigned short*)(ws + 113317888);  // 8 MB -> 121706496
  float*          ivf     = (float*)        (ws + 121706496);  // 16 MB -> 138483712

  k_cast<<<4096, 256, 0, stream>>>(x,  x_bf,  1048576);
  k_cast<<<1024, 256, 0, stream>>>(wq, wq_bf, 262144);
  k_cast<<<1024, 256, 0, stream>>>(wk, wk_bf, 262144);
  k_cast<<<1024, 256, 0, stream>>>(wv, wv_bf, 262144);
  k_cast<<<1024, 256, 0, stream>>>(wo, wo_bf, 262144);
  k_relprep<<<72, 256, 0, stream>>>(rlk, rlv, relk_bf, relvT_bf);

  k_qk<<<dim3(64,32), 256, 0, stream>>>(x_bf, wq_bf, wk_bf, Qf, Kf);
  k_v <<<dim3(16,64), 256, 0, stream>>>(x_bf, wv_bf, Vf);
  k_qr<<<dim3(64,16), 256, 0, stream>>>(Qf, relk_bf, Qr2);

  k_s  <<<4096, 256, 0, stream>>>(Qf, Kf, Qr2, ivf);
  k_far<<<2048, 256, 0, stream>>>(Qf, Kf, Vf, Qr2, ivf, tails, op);
  k_near<<<256, 512, 0, stream>>>(Qf, Kf, Vf, Qr2, ivf, relvT_bf, rlv, tails, op, out1);
  k_wo<<<dim3(64,16), 256, 0, stream>>>(out1, wo_bf, bo, (float*)d_out);
}

// Round 8
// 336.834 us; speedup vs baseline: 2.3344x; 1.5626x over previous
//
#include <hip/hip_runtime.h>
#include <stdint.h>

#define DI __device__ __forceinline__

typedef __attribute__((ext_vector_type(8))) short bfx8;
typedef __attribute__((ext_vector_type(4))) short bfx4;
typedef __attribute__((ext_vector_type(4))) float f4;

DI unsigned short f2bf(float x){
  unsigned u = __float_as_uint(x);
  u = (u + 0x7FFFu + ((u >> 16) & 1u)) >> 16;
  return (unsigned short)u;
}
DI float bf2f(unsigned short h){ return __uint_as_float(((unsigned)h) << 16); }

DI f4 mfma32(bfx8 a, bfx8 b, f4 c){
  return __builtin_amdgcn_mfma_f32_16x16x32_bf16(a, b, c, 0, 0, 0);
}
#if __has_builtin(__builtin_amdgcn_mfma_f32_16x16x16bf16_1k)
DI f4 mfma16(bfx4 a, bfx4 b, f4 c){
  return __builtin_amdgcn_mfma_f32_16x16x16bf16_1k(a, b, c, 0, 0, 0);
}
#else
DI f4 mfma16(bfx4 a, bfx4 b, f4 c){
  f4 d = c;
  asm volatile("v_mfma_f32_16x16x16_bf16 %0, %1, %2, %0" : "+v"(d) : "v"(a), "v"(b));
  return d;
}
#endif

// async global->LDS, 16B per lane; LDS dest = wave-uniform base + lane*16
DI void gload16(const void* g, void* l){
  __builtin_amdgcn_global_load_lds(
      (__attribute__((address_space(1))) void*)g,
      (__attribute__((address_space(3))) void*)l, 16, 0, 0);
}

// Fragment layouts (all 16-bit elems):
//   Qf/Kf[bh][tile][lane][16]: elem[kf*8+j] = M[tile*16 + (lane&15)][kf*32 + 8*(lane>>4) + j]
//   Vf  [bh][tile][lane][16]: elem[df*4+j] = V[tile*16 + 4*(lane>>4) + j][df*16 + (lane&15)]
//   ivf [b][tt][st][lane][4]: elem[r] = 1/S at (s = st*16 + (lane&15), t = tt*16 + 4*(lane>>4) + r)

// ---------------- cast f32 -> bf16 (4-wide) ----------------
__global__ void k_cast(const float* __restrict__ src, unsigned short* __restrict__ dst, int n4){
  int i = blockIdx.x*256 + threadIdx.x;
  if (i < n4){
    const float4 v = ((const float4*)src)[i];
    bfx4 o;
    o[0] = (short)f2bf(v.x); o[1] = (short)f2bf(v.y);
    o[2] = (short)f2bf(v.z); o[3] = (short)f2bf(v.w);
    *(bfx4*)(dst + (size_t)i*4) = o;
  }
}

// relk_bf: [272][64] zero-padded rows; relvT_bf: [64][288] = rel_v^T zero-padded cols
__global__ void k_relprep(const float* __restrict__ rlk, const float* __restrict__ rlv,
                          unsigned short* __restrict__ relk_bf, unsigned short* __restrict__ relvT_bf){
  int i = blockIdx.x*256 + threadIdx.x;
  if (i < 272*64){
    int r = i >> 6, d = i & 63;
    relk_bf[i] = (r < 257) ? f2bf(rlk[r*64 + d]) : (unsigned short)0;
  }
  if (i < 64*288){
    int d = i / 288, r = i % 288;
    relvT_bf[i] = (r < 257) ? f2bf(rlv[(size_t)r*64 + d]) : (unsigned short)0;
  }
}

// ---------------- QKV projections, LDS-staged (fragment-order staging) ----------------
// C[s(128)][n(128)] per block; n spans [wq|wk|wv] rows (contiguous buffers).
// grid (24 nt, 4 b, 8 st), 256 thr. Epilogue writes Qf/Kf/Vf fragment layouts.
__global__ __launch_bounds__(256) void k_qkv(
    const unsigned short* __restrict__ xbf, const unsigned short* __restrict__ wqkv,
    unsigned short* __restrict__ Qf, unsigned short* __restrict__ Kf,
    unsigned short* __restrict__ Vf)
{
  __shared__ __align__(16) unsigned short Al[4096];   // 8 fragment-blocks x 512 elems
  __shared__ __align__(16) unsigned short Bl[4096];
  __shared__ __align__(16) float eslab[4][1280];      // per-wave epilogue slab
  const int nt = blockIdx.x;
  const int b  = blockIdx.y;
  const int st = blockIdx.z;
  const int w = threadIdx.x >> 6, lane = threadIdx.x & 63;
  const int wr = w >> 1, wc = w & 1;
  const int p = lane & 15, g = lane >> 4;
  const int s0 = st*128;
  const int n0 = nt*128;
  const f4 fz = {0.f,0.f,0.f,0.f};
  f4 acc[4][4];
#pragma unroll
  for (int m=0;m<4;++m)
#pragma unroll
    for (int n=0;n<4;++n) acc[m][n] = fz;

  const int j0 = w*2, j1 = w*2 + 1;
  const unsigned short* gA = xbf  + (size_t)((s0 + p)*4 + b)*1024 + g*8;
  const unsigned short* gB = wqkv + (size_t)(n0 + p)*1024 + g*8;

  for (int k0=0; k0<1024; k0+=32){
    gload16(gA + (size_t)j0*65536 + k0, Al + j0*512);
    gload16(gA + (size_t)j1*65536 + k0, Al + j1*512);
    gload16(gB + (size_t)j0*16384 + k0, Bl + j0*512);
    gload16(gB + (size_t)j1*16384 + k0, Bl + j1*512);
    __syncthreads();
    bfx8 af[4], bf[4];
#pragma unroll
    for (int m=0;m<4;++m) af[m] = *(const bfx8*)(Al + (wr*4+m)*512 + lane*8);
#pragma unroll
    for (int n=0;n<4;++n) bf[n] = *(const bfx8*)(Bl + (wc*4+n)*512 + lane*8);
#pragma unroll
    for (int m=0;m<4;++m)
#pragma unroll
      for (int n=0;n<4;++n)
        acc[m][n] = mfma32(af[m], bf[n], acc[m][n]);
    __syncthreads();
  }

  const int n64 = n0 + wc*64;
  const int sec = n64 >> 10;            // 0 Q, 1 K, 2 V  (uniform per block)
  const int h = (n64 & 1023) >> 6;
  float* es = eslab[w];

  if (sec < 2){
    const float scl = (sec == 0) ? 0.125f : 1.0f;
    unsigned short* dst = (sec == 0) ? Qf : Kf;
#pragma unroll
    for (int m=0;m<4;++m){
#pragma unroll
      for (int n=0;n<4;++n)
#pragma unroll
        for (int r=0;r<4;++r)
          es[(4*g + r)*80 + 16*n + p] = acc[m][n][r] * scl;
      __syncthreads();
      f4 v0 = *(const f4*)&es[p*80 + 8*g];
      f4 v1 = *(const f4*)&es[p*80 + 8*g + 4];
      f4 v2 = *(const f4*)&es[p*80 + 32 + 8*g];
      f4 v3 = *(const f4*)&es[p*80 + 32 + 8*g + 4];
      bfx8 lo, hi;
#pragma unroll
      for (int j=0;j<4;++j){
        lo[j]   = (short)f2bf(v0[j]);
        lo[j+4] = (short)f2bf(v1[j]);
        hi[j]   = (short)f2bf(v2[j]);
        hi[j+4] = (short)f2bf(v3[j]);
      }
      size_t fb = ((size_t)(b*16 + h)*64 + (st*8 + wr*4 + m))*1024 + (size_t)lane*16;
      *(bfx8*)(dst + fb) = lo;
      *(bfx8*)(dst + fb + 8) = hi;
      __syncthreads();
    }
  } else {
#pragma unroll
    for (int m=0;m<4;++m){
#pragma unroll
      for (int n=0;n<4;++n)
        *(f4*)&es[(16*n + p)*20 + 4*g] = acc[m][n];   // transposed: [d][t-local]
      __syncthreads();
      f4 vv0 = *(const f4*)&es[(p)*20 + 4*g];
      f4 vv1 = *(const f4*)&es[(16 + p)*20 + 4*g];
      f4 vv2 = *(const f4*)&es[(32 + p)*20 + 4*g];
      f4 vv3 = *(const f4*)&es[(48 + p)*20 + 4*g];
      bfx8 lo, hi;
#pragma unroll
      for (int j=0;j<4;++j){
        lo[j]   = (short)f2bf(vv0[j]);
        lo[j+4] = (short)f2bf(vv1[j]);
        hi[j]   = (short)f2bf(vv2[j]);
        hi[j+4] = (short)f2bf(vv3[j]);
      }
      size_t fb = ((size_t)(b*16 + h)*64 + (st*8 + wr*4 + m))*1024 + (size_t)lane*16;
      *(bfx8*)(Vf + fb) = lo;
      *(bfx8*)(Vf + fb + 8) = hi;
      __syncthreads();
    }
  }
}

// ---------------- Qr2[b][s][u(272)][h(16)] = Qscaled @ rel_k^T (bf16, head-last layout) ----------------
__global__ __launch_bounds__(256) void k_qr(
    const unsigned short* __restrict__ Qf, const unsigned short* __restrict__ relk,
    unsigned short* __restrict__ Qr2)
{
  const int bh = blockIdx.x;
  const int b = bh >> 4, h = bh & 15;
  const int w = threadIdx.x >> 6, lane = threadIdx.x & 63;
  const int p = lane & 15, g = lane >> 4;
  const int s0 = blockIdx.y*64 + w*16;
  const int tile = s0 >> 4;
  const f4 fz = {0.f,0.f,0.f,0.f};
  size_t fb = ((size_t)bh*64 + tile)*1024 + (size_t)lane*16;
  bfx8 a0 = *(const bfx8*)(Qf + fb);
  bfx8 a1 = *(const bfx8*)(Qf + fb + 8);
  for (int r0=0; r0<272; r0+=16){
    f4 acc = fz;
    bfx8 b0 = *(const bfx8*)(relk + (size_t)(r0 + p)*64 + 8*g);
    bfx8 b1 = *(const bfx8*)(relk + (size_t)(r0 + p)*64 + 32 + 8*g);
    acc = mfma32(a0, b0, acc);
    acc = mfma32(a1, b1, acc);
#pragma unroll
    for (int r=0; r<4; ++r)
      Qr2[(((size_t)b*1024 + s0 + 4*g + r)*272 + r0 + p)*16 + h] = f2bf(acc[r]);
  }
}

// ---------------- softmax denominator -> ivf (fragment layout, coalesced) ----------------
__global__ __launch_bounds__(256, 3) void k_s(
    const unsigned short* __restrict__ Qf, const unsigned short* __restrict__ Kf,
    const unsigned short* __restrict__ Qr2, float* __restrict__ ivf)
{
  const int pbid = blockIdx.x;            // (st<<6)|(ttg<<2)|b
  const int b   = pbid & 3;
  const int ttg = (pbid >> 2) & 15;
  const int st  = pbid >> 6;
  const int w = threadIdx.x >> 6, lane = threadIdx.x & 63;
  const int tt = ttg*4 + w;
  const int p = lane & 15, g = lane >> 4;
  const int s0 = st << 4, t0 = tt << 4;
  const int s = s0 + p;
  const f4 fz = {0.f,0.f,0.f,0.f};

  bfx8 rv[4][2];
#pragma unroll
  for (int r=0; r<4; ++r){
    int t = t0 + 4*g + r;
    int u = s - t + 128; u = u < 0 ? 0 : (u > 256 ? 256 : u);
    const unsigned short* q = Qr2 + (((size_t)b*1024 + s)*272 + u)*16;
    rv[r][0] = *(const bfx8*)q;
    rv[r][1] = *(const bfx8*)(q + 8);
  }

  f4 ps = fz;
#pragma unroll
  for (int hg=0; hg<2; ++hg){
    f4 sc[8];
#pragma unroll
    for (int h8=0; h8<8; ++h8){
      size_t bh = (size_t)(b*16 + hg*8 + h8);
      size_t qb = (bh*64 + st)*1024 + (size_t)lane*16;
      size_t kb = (bh*64 + tt)*1024 + (size_t)lane*16;
      bfx8 q0 = *(const bfx8*)(Qf + qb);
      bfx8 q1 = *(const bfx8*)(Qf + qb + 8);
      bfx8 k0 = *(const bfx8*)(Kf + kb);
      bfx8 k1 = *(const bfx8*)(Kf + kb + 8);
      sc[h8] = mfma32(k1, q1, mfma32(k0, q0, fz));
    }
#pragma unroll
    for (int h8=0; h8<8; ++h8)
#pragma unroll
      for (int r=0; r<4; ++r)
        ps[r] += __expf(sc[h8][r] + bf2f((unsigned short)rv[r][hg][h8]));
  }

  f4 inv;
#pragma unroll
  for (int r=0; r<4; ++r) inv[r] = 1.0f / ps[r];
  *(f4*)(ivf + (((size_t)(b*64 + tt)*64 + st)*64 + lane)*4) = inv;
}

// ---------------- far attention: barrier-free, fragment loads, balanced strided far list ----------------
__global__ __launch_bounds__(256, 3) void k_far(
    const unsigned short* __restrict__ Qf, const unsigned short* __restrict__ Kf,
    const unsigned short* __restrict__ Vf, const unsigned short* __restrict__ Qr2,
    const float* __restrict__ ivf, float* __restrict__ tails,
    unsigned short* __restrict__ op)
{
  __shared__ __align__(16) float slab[4][16][68];
  const int pbid  = blockIdx.x;
  const int b     = pbid & 3;
  const int part  = (pbid >> 2) & 3;
  const int hhalf = (pbid >> 4) & 1;
  const int st    = pbid >> 5;
  const int s0 = st << 4;
  const int w = threadIdx.x >> 6, lane = threadIdx.x & 63;
  const int p = lane & 15, g = lane >> 4;
  const int s = s0 + p;
  const int h0 = hhalf*8 + w*2;
  const f4 fz = {0.f,0.f,0.f,0.f};

  bfx8 qf[2][2]; float qr0[2], qr1[2];
#pragma unroll
  for (int hh=0; hh<2; ++hh){
    size_t bh = (size_t)(b*16 + h0 + hh);
    size_t qb = (bh*64 + st)*1024 + (size_t)lane*16;
    qf[hh][0] = *(const bfx8*)(Qf + qb);
    qf[hh][1] = *(const bfx8*)(Qf + qb + 8);
    qr0[hh] = bf2f(Qr2[(((size_t)b*1024 + s)*272 + 0)*16 + (h0+hh)]);
    qr1[hh] = bf2f(Qr2[(((size_t)b*1024 + s)*272 + 256)*16 + (h0+hh)]);
  }

  f4 o[2][4];
#pragma unroll
  for (int hh=0; hh<2; ++hh)
#pragma unroll
    for (int df=0; df<4; ++df) o[hh][df] = fz;
  float tl0[2] = {0.f,0.f};
  float tl1[2] = {0.f,0.f};

  const int tlo = (st-8 < 0) ? 0 : st-8;
  const int thi = (st+8 > 63) ? 63 : st+8;
  const int nband = thi - tlo + 1;
  const int nfar = 64 - nband;

  bfx8 kc[2][2]; bfx4 vc[2][4]; f4 is;
  bfx8 kn[2][2]; bfx4 vn[2][4]; f4 isn;

  int idx = part;
  {
    const int ti = (idx < tlo) ? idx : idx + nband;
#pragma unroll
    for (int hh=0; hh<2; ++hh){
      size_t fb = (((size_t)(b*16 + h0 + hh))*64 + ti)*1024 + (size_t)lane*16;
      kc[hh][0] = *(const bfx8*)(Kf + fb);
      kc[hh][1] = *(const bfx8*)(Kf + fb + 8);
#pragma unroll
      for (int df=0; df<4; ++df)
        vc[hh][df] = *(const bfx4*)(Vf + fb + df*4);
    }
    is = *(const f4*)(ivf + (((size_t)(b*64 + ti)*64 + st)*64 + lane)*4);
  }

  while (idx < nfar){
    const int idn = idx + 4;
    if (idn < nfar){
      const int tn = (idn < tlo) ? idn : idn + nband;
#pragma unroll
      for (int hh=0; hh<2; ++hh){
        size_t fb = (((size_t)(b*16 + h0 + hh))*64 + tn)*1024 + (size_t)lane*16;
        kn[hh][0] = *(const bfx8*)(Kf + fb);
        kn[hh][1] = *(const bfx8*)(Kf + fb + 8);
#pragma unroll
        for (int df=0; df<4; ++df)
          vn[hh][df] = *(const bfx4*)(Vf + fb + df*4);
      }
      isn = *(const f4*)(ivf + (((size_t)(b*64 + tn)*64 + st)*64 + lane)*4);
    }

    const int ti = (idx < tlo) ? idx : idx + nband;
    const bool hiSide = (ti < st);
#pragma unroll
    for (int hh=0; hh<2; ++hh){
      f4 sc = mfma32(kc[hh][1], qf[hh][1], mfma32(kc[hh][0], qf[hh][0], fz));
      const float qa = hiSide ? qr1[hh] : qr0[hh];
      f4 at;
#pragma unroll
      for (int r=0; r<4; ++r) at[r] = __expf(sc[r] + qa) * is[r];
      float tsum = at[0] + at[1] + at[2] + at[3];
      if (hiSide) tl1[hh] += tsum; else tl0[hh] += tsum;
      bfx4 pk;
#pragma unroll
      for (int r=0; r<4; ++r) pk[r] = (short)f2bf(at[r]);
#pragma unroll
      for (int df=0; df<4; ++df)
        o[hh][df] = mfma16(vc[hh][df], pk, o[hh][df]);
    }

    if (idn < nfar){
#pragma unroll
      for (int hh=0; hh<2; ++hh){
        kc[hh][0] = kn[hh][0]; kc[hh][1] = kn[hh][1];
#pragma unroll
        for (int df=0; df<4; ++df) vc[hh][df] = vn[hh][df];
      }
      is = isn;
    }
    idx = idn;
  }

  // tail buckets for this part
#pragma unroll
  for (int hh=0; hh<2; ++hh){
    float v0 = tl0[hh];
    v0 += __shfl_xor(v0, 16, 64);
    v0 += __shfl_xor(v0, 32, 64);
    float v1 = tl1[hh];
    v1 += __shfl_xor(v1, 16, 64);
    v1 += __shfl_xor(v1, 32, 64);
    if (g == 0){
      size_t tix = ((size_t)(part*64 + b*16 + h0 + hh)*1024 + s)*2;
      tails[tix + 0] = v0;
      tails[tix + 1] = v1;
    }
  }

  // transpose epilogue -> bf16 partial output for this part
  unsigned short* dst = op + (size_t)part * 4194304;
#pragma unroll
  for (int hh=0; hh<2; ++hh){
    float (*tb)[68] = slab[w];
#pragma unroll
    for (int df=0; df<4; ++df)
      *(f4*)&tb[p][df*16 + 4*g] = o[hh][df];
    __syncthreads();
    const int srow = lane >> 2, quad = lane & 3;
    f4 r0 = *(const f4*)&tb[srow][quad*16 + 0];
    f4 r1 = *(const f4*)&tb[srow][quad*16 + 4];
    f4 r2 = *(const f4*)&tb[srow][quad*16 + 8];
    f4 r3 = *(const f4*)&tb[srow][quad*16 + 12];
    bfx8 pa, pb;
#pragma unroll
    for (int j=0; j<4; ++j){
      pa[j]   = (short)f2bf(r0[j]);
      pa[j+4] = (short)f2bf(r1[j]);
      pb[j]   = (short)f2bf(r2[j]);
      pb[j+4] = (short)f2bf(r3[j]);
    }
    size_t addr = ((size_t)b*1024 + s0 + srow)*1024 + (h0+hh)*64 + quad*16;
    *(bfx8*)(dst + addr) = pa;
    *(bfx8*)(dst + addr + 8) = pb;
    __syncthreads();
  }
}

// ---------------- near attention (17 tiles) + fused rel_v GEMM + final out1 ----------------
__global__ __launch_bounds__(512, 2) void k_near(
    const unsigned short* __restrict__ Qf, const unsigned short* __restrict__ Kf,
    const unsigned short* __restrict__ Vf, const unsigned short* __restrict__ Qr2,
    const float* __restrict__ ivf, const unsigned short* __restrict__ relvT,
    const float* __restrict__ relv, const float* __restrict__ tails,
    const unsigned short* __restrict__ op, unsigned short* __restrict__ out1)
{
  __shared__ __align__(16) unsigned short skew[256*264];
  const int pbid = blockIdx.x;
  const int xcd = pbid & 7;
  const int b = xcd >> 1;
  const int st = ((pbid >> 3) << 1) | (xcd & 1);
  const int s0 = st << 4;
  const int w = threadIdx.x >> 6;
  const int lane = threadIdx.x & 63;
  const int p = lane & 15, g = lane >> 4;
  const int s = s0 + p;
  const int h0 = w * 2;
  const f4 fz = {0.f,0.f,0.f,0.f};

  {
    unsigned* zp = (unsigned*)skew + w*4224;
    for (int i = lane; i < 4224; i += 64) zp[i] = 0u;
  }

  bfx8 qf[2][2];
#pragma unroll
  for (int hh=0; hh<2; ++hh){
    size_t qb = (((size_t)(b*16 + h0 + hh))*64 + st)*1024 + (size_t)lane*16;
    qf[hh][0] = *(const bfx8*)(Qf + qb);
    qf[hh][1] = *(const bfx8*)(Qf + qb + 8);
  }

  f4 o[2][4];
#pragma unroll
  for (int hh=0; hh<2; ++hh)
#pragma unroll
    for (int df=0; df<4; ++df) o[hh][df] = fz;

  float tl0[2] = {0.f,0.f};
  float tl1[2] = {0.f,0.f};

  const int tlo = (st-8 < 0) ? 0 : st-8;
  const int thi = (st+8 > 63) ? 63 : st+8;

  bfx8 kc[2][2]; bfx4 vc[2][4]; unsigned short qc[2][4]; f4 is;
  bfx8 kn[2][2]; bfx4 vn[2][4]; unsigned short qn[2][4]; f4 isn;

#pragma unroll
  for (int hh=0; hh<2; ++hh){
    size_t bh = (size_t)(b*16 + h0 + hh);
    size_t fb = (bh*64 + tlo)*1024 + (size_t)lane*16;
    kc[hh][0] = *(const bfx8*)(Kf + fb);
    kc[hh][1] = *(const bfx8*)(Kf + fb + 8);
#pragma unroll
    for (int df=0; df<4; ++df)
      vc[hh][df] = *(const bfx4*)(Vf + fb + df*4);
#pragma unroll
    for (int r=0; r<4; ++r){
      int t = (tlo<<4) + 4*g + r;
      int u = s - t + 128; u = u < 0 ? 0 : (u > 256 ? 256 : u);
      qc[hh][r] = Qr2[(((size_t)b*1024 + s)*272 + u)*16 + (h0+hh)];
    }
  }
  is = *(const f4*)(ivf + (((size_t)(b*64 + tlo)*64 + st)*64 + lane)*4);

  for (int ti = tlo; ti <= thi; ++ti){
    const int t0 = ti << 4;

    if (ti < thi){
      const int tn = ti + 1;
#pragma unroll
      for (int hh=0; hh<2; ++hh){
        size_t bh = (size_t)(b*16 + h0 + hh);
        size_t fb = (bh*64 + tn)*1024 + (size_t)lane*16;
        kn[hh][0] = *(const bfx8*)(Kf + fb);
        kn[hh][1] = *(const bfx8*)(Kf + fb + 8);
#pragma unroll
        for (int df=0; df<4; ++df)
          vn[hh][df] = *(const bfx4*)(Vf + fb + df*4);
#pragma unroll
        for (int r=0; r<4; ++r){
          int t = (tn<<4) + 4*g + r;
          int u = s - t + 128; u = u < 0 ? 0 : (u > 256 ? 256 : u);
          qn[hh][r] = Qr2[(((size_t)b*1024 + s)*272 + u)*16 + (h0+hh)];
        }
      }
      isn = *(const f4*)(ivf + (((size_t)(b*64 + tn)*64 + st)*64 + lane)*4);
    }

#pragma unroll
    for (int hh=0; hh<2; ++hh){
      f4 sc = mfma32(kc[hh][1], qf[hh][1], mfma32(kc[hh][0], qf[hh][0], fz));
      f4 at;
#pragma unroll
      for (int r=0; r<4; ++r) at[r] = __expf(sc[r] + bf2f(qc[hh][r])) * is[r];
      const int row = (h0 + hh)*16 + p;
#pragma unroll
      for (int r=0; r<4; ++r){
        int t = t0 + 4*g + r;
        int u = s - t + 128;
        float a = at[r];
        if (u <= 0) tl0[hh] += a;
        else if (u >= 256) tl1[hh] += a;
        else skew[row*264 + u] = f2bf(a);
      }
      bfx4 pk;
#pragma unroll
      for (int r=0; r<4; ++r) pk[r] = (short)f2bf(at[r]);
#pragma unroll
      for (int df=0; df<4; ++df)
        o[hh][df] = mfma16(vc[hh][df], pk, o[hh][df]);
    }

    if (ti < thi){
#pragma unroll
      for (int hh=0; hh<2; ++hh){
#pragma unroll
        for (int kf=0; kf<2; ++kf) kc[hh][kf] = kn[hh][kf];
#pragma unroll
        for (int df=0; df<4; ++df) vc[hh][df] = vn[hh][df];
#pragma unroll
        for (int r=0; r<4; ++r) qc[hh][r] = qn[hh][r];
      }
      is = isn;
    }
  }

  __syncthreads();

  // ---- fused out2 = rel_v^T @ skew (own-wave rows only) ----
  f4 acc2[2][4];
#pragma unroll
  for (int hh=0; hh<2; ++hh)
#pragma unroll
    for (int df=0; df<4; ++df) acc2[hh][df] = fz;
#pragma unroll
  for (int k0=0; k0<256; k0+=32){
    bfx8 bb0 = *(const bfx8*)&skew[(h0*16 + p)*264 + k0 + 8*g];
    bfx8 bb1 = *(const bfx8*)&skew[((h0+1)*16 + p)*264 + k0 + 8*g];
#pragma unroll
    for (int df=0; df<4; ++df){
      bfx8 a = *(const bfx8*)(relvT + (size_t)(df*16 + p)*288 + k0 + 8*g);
      acc2[0][df] = mfma32(a, bb0, acc2[0][df]);
      acc2[1][df] = mfma32(a, bb1, acc2[1][df]);
    }
  }

  f4 rv0[4], rv1[4];
#pragma unroll
  for (int df=0; df<4; ++df){
    rv0[df] = *(const f4*)(relv + df*16 + 4*g);
    rv1[df] = *(const f4*)(relv + 16384 + df*16 + 4*g);
  }
#pragma unroll
  for (int hh=0; hh<2; ++hh){
    float tv0 = tl0[hh];
    tv0 += __shfl_xor(tv0, 16, 64);
    tv0 += __shfl_xor(tv0, 32, 64);
    float tv1 = tl1[hh];
    tv1 += __shfl_xor(tv1, 16, 64);
    tv1 += __shfl_xor(tv1, 32, 64);
    size_t bh = (size_t)(b*16 + h0 + hh);
#pragma unroll
    for (int part=0; part<4; ++part){
      size_t tix = ((size_t)(part*64) + bh)*2048 + (size_t)s*2;
      tv0 += tails[tix + 0];
      tv1 += tails[tix + 1];
    }
#pragma unroll
    for (int df=0; df<4; ++df)
#pragma unroll
      for (int r=0; r<4; ++r)
        o[hh][df][r] += acc2[hh][df][r] + tv0*rv0[df][r] + tv1*rv1[df][r];
  }

  __syncthreads();

  float* slabBase = (float*)skew;
  float (*tb)[68] = (float(*)[68])(slabBase + w*(16*68));
#pragma unroll
  for (int hh=0; hh<2; ++hh){
#pragma unroll
    for (int df=0; df<4; ++df)
      *(f4*)&tb[p][df*16 + 4*g] = o[hh][df];
    __syncthreads();
    const int srow = lane >> 2, quad = lane & 3;
    f4 r0 = *(const f4*)&tb[srow][quad*16 + 0];
    f4 r1 = *(const f4*)&tb[srow][quad*16 + 4];
    f4 r2 = *(const f4*)&tb[srow][quad*16 + 8];
    f4 r3 = *(const f4*)&tb[srow][quad*16 + 12];
    size_t addr = ((size_t)b*1024 + s0 + srow)*1024 + (h0+hh)*64 + quad*16;
    bfx8 pa, pb;
#pragma unroll
    for (int j=0; j<4; ++j){
      float a0 = r0[j], a1 = r1[j], a2 = r2[j], a3 = r3[j];
#pragma unroll
      for (int part=0; part<4; ++part){
        const unsigned short* pp = op + (size_t)part*4194304 + addr;
        bfx8 q0 = *(const bfx8*)pp;
        bfx8 q1 = *(const bfx8*)(pp + 8);
        a0 += bf2f((unsigned short)q0[j]);
        a1 += bf2f((unsigned short)q0[j+4]);
        a2 += bf2f((unsigned short)q1[j]);
        a3 += bf2f((unsigned short)q1[j+4]);
      }
      pa[j]   = (short)f2bf(a0);
      pa[j+4] = (short)f2bf(a1);
      pb[j]   = (short)f2bf(a2);
      pb[j+4] = (short)f2bf(a3);
    }
    *(bfx8*)(out1 + addr) = pa;
    *(bfx8*)(out1 + addr + 8) = pb;
    __syncthreads();
  }
}

// ---------------- final projection, LDS-staged: d_out[(s,b)][n] = out1 @ w_o^T + b_o ----------------
// tile 64(M) x 128(N); grid (8 nt, 64 mt).
__global__ __launch_bounds__(256) void k_wo(
    const unsigned short* __restrict__ out1, const unsigned short* __restrict__ wo,
    const float* __restrict__ bo, float* __restrict__ dout)
{
  __shared__ __align__(16) unsigned short Al[2048];   // 4 fragment-blocks
  __shared__ __align__(16) unsigned short Bl[4096];   // 8 fragment-blocks
  const int nt = blockIdx.x;
  const int mt = blockIdx.y;
  const int w = threadIdx.x >> 6, lane = threadIdx.x & 63;
  const int wr = w >> 1, wc = w & 1;
  const int p = lane & 15, g = lane >> 4;
  const int m0 = mt*64, n0 = nt*128;
  const f4 fz = {0.f,0.f,0.f,0.f};
  f4 acc[2][4];
#pragma unroll
  for (int m=0;m<2;++m)
#pragma unroll
    for (int n=0;n<4;++n) acc[m][n] = fz;

  const int j0 = w*2, j1 = w*2 + 1;
  const unsigned short* gA = out1 + (size_t)(m0 + p)*1024 + g*8;
  const unsigned short* gB = wo   + (size_t)(n0 + p)*1024 + g*8;

  for (int k0=0; k0<1024; k0+=32){
    gload16(gA + (size_t)w*16384 + k0, Al + w*512);
    gload16(gB + (size_t)j0*16384 + k0, Bl + j0*512);
    gload16(gB + (size_t)j1*16384 + k0, Bl + j1*512);
    __syncthreads();
    bfx8 af[2], bf[4];
#pragma unroll
    for (int m=0;m<2;++m) af[m] = *(const bfx8*)(Al + (wr*2+m)*512 + lane*8);
#pragma unroll
    for (int n=0;n<4;++n) bf[n] = *(const bfx8*)(Bl + (wc*4+n)*512 + lane*8);
#pragma unroll
    for (int m=0;m<2;++m)
#pragma unroll
      for (int n=0;n<4;++n)
        acc[m][n] = mfma32(af[m], bf[n], acc[m][n]);
    __syncthreads();
  }

#pragma unroll
  for (int n=0;n<4;++n){
    const int col = n0 + wc*64 + n*16 + p;
    const float bias = bo[col];
#pragma unroll
    for (int m=0;m<2;++m)
#pragma unroll
      for (int r=0;r<4;++r){
        int row = m0 + wr*32 + m*16 + 4*g + r;
        int bb = row >> 10, s = row & 1023;
        dout[((size_t)s*4 + bb)*1024 + col] = acc[m][n][r] + bias;
      }
  }
}

extern "C" void kernel_launch(void* const* d_in, const int* in_sizes, int n_in,
                              void* d_out, int out_size, void* d_ws, size_t ws_size,
                              hipStream_t stream){
  const float* x   = (const float*)d_in[0];
  const float* wq  = (const float*)d_in[1];
  const float* wk  = (const float*)d_in[2];
  const float* wv  = (const float*)d_in[3];
  const float* wo  = (const float*)d_in[4];
  const float* bo  = (const float*)d_in[5];
  const float* rlk = (const float*)d_in[6];
  const float* rlv = (const float*)d_in[7];
  char* ws = (char*)d_ws;

  unsigned short* x_bf    = (unsigned short*)(ws + 0);
  unsigned short* wq_bf   = (unsigned short*)(ws + 8388608);   // [wq|wk|wv] contiguous
  unsigned short* wk_bf   = (unsigned short*)(ws + 10485760);
  unsigned short* wv_bf   = (unsigned short*)(ws + 12582912);
  unsigned short* wo_bf   = (unsigned short*)(ws + 14680064);
  unsigned short* relk_bf = (unsigned short*)(ws + 16777216);
  unsigned short* relvT_bf= (unsigned short*)(ws + 16812032);
  unsigned short* Qf      = (unsigned short*)(ws + 16848896);   // fragment layout
  unsigned short* Kf      = (unsigned short*)(ws + 25237504);   // fragment layout
  unsigned short* Vf      = (unsigned short*)(ws + 33626112);   // fragment layout
  unsigned short* Qr2     = (unsigned short*)(ws + 42014720);   // 35.65 MB -> 77666304
  float*          tails   = (float*)        (ws + 77666304);   // 2 MB -> 79763456
  unsigned short* op      = (unsigned short*)(ws + 79763456);   // 32 MB (4 parts) -> 113317888
  unsigned short* out1    = (unsigned short*)(ws + 113317888);  // 8 MB -> 121706496
  float*          ivf     = (float*)        (ws + 121706496);  // 16 MB -> 138483712

  k_cast<<<4096, 256, 0, stream>>>(x,  x_bf,  1048576);
  k_cast<<<1024, 256, 0, stream>>>(wq, wq_bf, 262144);
  k_cast<<<1024, 256, 0, stream>>>(wk, wk_bf, 262144);
  k_cast<<<1024, 256, 0, stream>>>(wv, wv_bf, 262144);
  k_cast<<<1024, 256, 0, stream>>>(wo, wo_bf, 262144);
  k_relprep<<<72, 256, 0, stream>>>(rlk, rlv, relk_bf, relvT_bf);

  k_qkv<<<dim3(24,4,8), 256, 0, stream>>>(x_bf, wq_bf, Qf, Kf, Vf);
  k_qr<<<dim3(64,16), 256, 0, stream>>>(Qf, relk_bf, Qr2);

  k_s  <<<4096, 256, 0, stream>>>(Qf, Kf, Qr2, ivf);
  k_far<<<2048, 256, 0, stream>>>(Qf, Kf, Vf, Qr2, ivf, tails, op);
  k_near<<<256, 512, 0, stream>>>(Qf, Kf, Vf, Qr2, ivf, relvT_bf, rlv, tails, op, out1);
  k_wo<<<dim3(8,64), 256, 0, stream>>>(out1, wo_bf, bo, (float*)d_out);
}

// Round 9
// 272.050 us; speedup vs baseline: 2.8903x; 1.2381x over previous
//
#include <hip/hip_runtime.h>
#include <stdint.h>

#define DI __device__ __forceinline__

typedef __attribute__((ext_vector_type(8))) short bfx8;
typedef __attribute__((ext_vector_type(4))) short bfx4;
typedef __attribute__((ext_vector_type(4))) float f4;

DI unsigned short f2bf(float x){
  unsigned u = __float_as_uint(x);
  u = (u + 0x7FFFu + ((u >> 16) & 1u)) >> 16;
  return (unsigned short)u;
}
DI float bf2f(unsigned short h){ return __uint_as_float(((unsigned)h) << 16); }

DI f4 mfma32(bfx8 a, bfx8 b, f4 c){
  return __builtin_amdgcn_mfma_f32_16x16x32_bf16(a, b, c, 0, 0, 0);
}
#if __has_builtin(__builtin_amdgcn_mfma_f32_16x16x16bf16_1k)
DI f4 mfma16(bfx4 a, bfx4 b, f4 c){
  return __builtin_amdgcn_mfma_f32_16x16x16bf16_1k(a, b, c, 0, 0, 0);
}
#else
DI f4 mfma16(bfx4 a, bfx4 b, f4 c){
  f4 d = c;
  asm volatile("v_mfma_f32_16x16x16_bf16 %0, %1, %2, %0" : "+v"(d) : "v"(a), "v"(b));
  return d;
}
#endif

// async global->LDS, 16B per lane; LDS dest = wave-uniform base + lane*16
DI void gload16(const void* g, void* l){
  __builtin_amdgcn_global_load_lds(
      (__attribute__((address_space(1))) void*)g,
      (__attribute__((address_space(3))) void*)l, 16, 0, 0);
}

// Fragment layouts (all 16-bit elems):
//   Qf/Kf[bh][tile][lane][16]: elem[kf*8+j] = M[tile*16 + (lane&15)][kf*32 + 8*(lane>>4) + j]
//   Vf  [bh][tile][lane][16]: elem[df*4+j] = V[tile*16 + 4*(lane>>4) + j][df*16 + (lane&15)]
//   ivf [b][tt][st][lane][4]: elem[r] = 1/S at (s = st*16 + (lane&15), t = tt*16 + 4*(lane>>4) + r)

// ---------------- cast f32 -> bf16 (4-wide) ----------------
__global__ void k_cast(const float* __restrict__ src, unsigned short* __restrict__ dst, int n4){
  int i = blockIdx.x*256 + threadIdx.x;
  if (i < n4){
    const float4 v = ((const float4*)src)[i];
    bfx4 o;
    o[0] = (short)f2bf(v.x); o[1] = (short)f2bf(v.y);
    o[2] = (short)f2bf(v.z); o[3] = (short)f2bf(v.w);
    *(bfx4*)(dst + (size_t)i*4) = o;
  }
}

// merged weight cast: 4 matrices (1024x1024 f32) -> contiguous bf16 dsts
__global__ void k_castw(const float* __restrict__ s0, const float* __restrict__ s1,
                        const float* __restrict__ s2, const float* __restrict__ s3,
                        unsigned short* __restrict__ dst){
  int i = blockIdx.x*256 + threadIdx.x;      // < 262144
  const float* src = (blockIdx.y==0) ? s0 : (blockIdx.y==1) ? s1 : (blockIdx.y==2) ? s2 : s3;
  const float4 v = ((const float4*)src)[i];
  bfx4 o;
  o[0] = (short)f2bf(v.x); o[1] = (short)f2bf(v.y);
  o[2] = (short)f2bf(v.z); o[3] = (short)f2bf(v.w);
  *(bfx4*)(dst + (size_t)blockIdx.y*1048576 + (size_t)i*4) = o;
}

// relk_bf: [272][64] zero-padded rows; relvT_bf: [64][288] = rel_v^T zero-padded cols
__global__ void k_relprep(const float* __restrict__ rlk, const float* __restrict__ rlv,
                          unsigned short* __restrict__ relk_bf, unsigned short* __restrict__ relvT_bf){
  int i = blockIdx.x*256 + threadIdx.x;
  if (i < 272*64){
    int r = i >> 6, d = i & 63;
    relk_bf[i] = (r < 257) ? f2bf(rlk[r*64 + d]) : (unsigned short)0;
  }
  if (i < 64*288){
    int d = i / 288, r = i % 288;
    relvT_bf[i] = (r < 257) ? f2bf(rlv[(size_t)r*64 + d]) : (unsigned short)0;
  }
}

// ---------------- QKV projections, LDS-staged (fragment-order staging) ----------------
__global__ __launch_bounds__(256) void k_qkv(
    const unsigned short* __restrict__ xbf, const unsigned short* __restrict__ wqkv,
    unsigned short* __restrict__ Qf, unsigned short* __restrict__ Kf,
    unsigned short* __restrict__ Vf)
{
  __shared__ __align__(16) unsigned short Al[4096];
  __shared__ __align__(16) unsigned short Bl[4096];
  __shared__ __align__(16) float eslab[4][1280];
  const int nt = blockIdx.x;
  const int b  = blockIdx.y;
  const int st = blockIdx.z;
  const int w = threadIdx.x >> 6, lane = threadIdx.x & 63;
  const int wr = w >> 1, wc = w & 1;
  const int p = lane & 15, g = lane >> 4;
  const int s0 = st*128;
  const int n0 = nt*128;
  const f4 fz = {0.f,0.f,0.f,0.f};
  f4 acc[4][4];
#pragma unroll
  for (int m=0;m<4;++m)
#pragma unroll
    for (int n=0;n<4;++n) acc[m][n] = fz;

  const int j0 = w*2, j1 = w*2 + 1;
  const unsigned short* gA = xbf  + (size_t)((s0 + p)*4 + b)*1024 + g*8;
  const unsigned short* gB = wqkv + (size_t)(n0 + p)*1024 + g*8;

  for (int k0=0; k0<1024; k0+=32){
    gload16(gA + (size_t)j0*65536 + k0, Al + j0*512);
    gload16(gA + (size_t)j1*65536 + k0, Al + j1*512);
    gload16(gB + (size_t)j0*16384 + k0, Bl + j0*512);
    gload16(gB + (size_t)j1*16384 + k0, Bl + j1*512);
    __syncthreads();
    bfx8 af[4], bf[4];
#pragma unroll
    for (int m=0;m<4;++m) af[m] = *(const bfx8*)(Al + (wr*4+m)*512 + lane*8);
#pragma unroll
    for (int n=0;n<4;++n) bf[n] = *(const bfx8*)(Bl + (wc*4+n)*512 + lane*8);
#pragma unroll
    for (int m=0;m<4;++m)
#pragma unroll
      for (int n=0;n<4;++n)
        acc[m][n] = mfma32(af[m], bf[n], acc[m][n]);
    __syncthreads();
  }

  const int n64 = n0 + wc*64;
  const int sec = n64 >> 10;            // 0 Q, 1 K, 2 V
  const int h = (n64 & 1023) >> 6;
  float* es = eslab[w];

  if (sec < 2){
    const float scl = (sec == 0) ? 0.125f : 1.0f;
    unsigned short* dst = (sec == 0) ? Qf : Kf;
#pragma unroll
    for (int m=0;m<4;++m){
#pragma unroll
      for (int n=0;n<4;++n)
#pragma unroll
        for (int r=0;r<4;++r)
          es[(4*g + r)*80 + 16*n + p] = acc[m][n][r] * scl;
      __syncthreads();
      f4 v0 = *(const f4*)&es[p*80 + 8*g];
      f4 v1 = *(const f4*)&es[p*80 + 8*g + 4];
      f4 v2 = *(const f4*)&es[p*80 + 32 + 8*g];
      f4 v3 = *(const f4*)&es[p*80 + 32 + 8*g + 4];
      bfx8 lo, hi;
#pragma unroll
      for (int j=0;j<4;++j){
        lo[j]   = (short)f2bf(v0[j]);
        lo[j+4] = (short)f2bf(v1[j]);
        hi[j]   = (short)f2bf(v2[j]);
        hi[j+4] = (short)f2bf(v3[j]);
      }
      size_t fb = ((size_t)(b*16 + h)*64 + (st*8 + wr*4 + m))*1024 + (size_t)lane*16;
      *(bfx8*)(dst + fb) = lo;
      *(bfx8*)(dst + fb + 8) = hi;
      __syncthreads();
    }
  } else {
#pragma unroll
    for (int m=0;m<4;++m){
#pragma unroll
      for (int n=0;n<4;++n)
        *(f4*)&es[(16*n + p)*20 + 4*g] = acc[m][n];
      __syncthreads();
      f4 vv0 = *(const f4*)&es[(p)*20 + 4*g];
      f4 vv1 = *(const f4*)&es[(16 + p)*20 + 4*g];
      f4 vv2 = *(const f4*)&es[(32 + p)*20 + 4*g];
      f4 vv3 = *(const f4*)&es[(48 + p)*20 + 4*g];
      bfx8 lo, hi;
#pragma unroll
      for (int j=0;j<4;++j){
        lo[j]   = (short)f2bf(vv0[j]);
        lo[j+4] = (short)f2bf(vv1[j]);
        hi[j]   = (short)f2bf(vv2[j]);
        hi[j+4] = (short)f2bf(vv3[j]);
      }
      size_t fb = ((size_t)(b*16 + h)*64 + (st*8 + wr*4 + m))*1024 + (size_t)lane*16;
      *(bfx8*)(Vf + fb) = lo;
      *(bfx8*)(Vf + fb + 8) = hi;
      __syncthreads();
    }
  }
}

// ---------------- Qr2 producer, write-coalesced: all 16 heads per block ----------------
// block = (b, s-tile, u-half); 4 waves x 4 heads; LDS stage [s][u][h(pad24)], 32B/thread stores.
__global__ __launch_bounds__(256) void k_qr(
    const unsigned short* __restrict__ Qf, const unsigned short* __restrict__ relk,
    unsigned short* __restrict__ Qr2)
{
  __shared__ __align__(16) unsigned short sst[16][16][24];
  const int bx = blockIdx.x;
  const int b  = bx & 3;
  const int st = (bx >> 2) & 63;
  const int uh = bx >> 8;
  const int w = threadIdx.x >> 6, lane = threadIdx.x & 63;
  const int p = lane & 15, g = lane >> 4;
  const int s0 = st << 4;
  const f4 fz = {0.f,0.f,0.f,0.f};

  bfx8 a0[4], a1[4];
#pragma unroll
  for (int hh=0; hh<4; ++hh){
    size_t fb = (((size_t)(b*16 + w*4 + hh))*64 + st)*1024 + (size_t)lane*16;
    a0[hh] = *(const bfx8*)(Qf + fb);
    a1[hh] = *(const bfx8*)(Qf + fb + 8);
  }

  const int c0 = uh ? 9 : 0;
  const int c1 = uh ? 17 : 9;
  const int so = threadIdx.x >> 4, uo = threadIdx.x & 15;

  for (int c=c0; c<c1; ++c){
    const int r0 = c << 4;
    bfx8 b0 = *(const bfx8*)(relk + (size_t)(r0 + p)*64 + 8*g);
    bfx8 b1 = *(const bfx8*)(relk + (size_t)(r0 + p)*64 + 32 + 8*g);
#pragma unroll
    for (int hh=0; hh<4; ++hh){
      f4 acc = mfma32(a1[hh], b1, mfma32(a0[hh], b0, fz));
#pragma unroll
      for (int r=0; r<4; ++r)
        sst[4*g + r][p][w*4 + hh] = f2bf(acc[r]);
    }
    __syncthreads();
    bfx8 v0 = *(const bfx8*)&sst[so][uo][0];
    bfx8 v1 = *(const bfx8*)&sst[so][uo][8];
    size_t ga = (((size_t)b*1024 + s0 + so)*272 + r0 + uo)*16;
    *(bfx8*)(Qr2 + ga) = v0;
    *(bfx8*)(Qr2 + ga + 8) = v1;
    __syncthreads();
  }
}

// ---------------- softmax denominator -> ivf (fragment layout, coalesced) ----------------
__global__ __launch_bounds__(256, 3) void k_s(
    const unsigned short* __restrict__ Qf, const unsigned short* __restrict__ Kf,
    const unsigned short* __restrict__ Qr2, float* __restrict__ ivf)
{
  const int pbid = blockIdx.x;            // (st<<6)|(ttg<<2)|b
  const int b   = pbid & 3;
  const int ttg = (pbid >> 2) & 15;
  const int st  = pbid >> 6;
  const int w = threadIdx.x >> 6, lane = threadIdx.x & 63;
  const int tt = ttg*4 + w;
  const int p = lane & 15, g = lane >> 4;
  const int s0 = st << 4, t0 = tt << 4;
  const int s = s0 + p;
  const f4 fz = {0.f,0.f,0.f,0.f};

  bfx8 rv[4][2];
#pragma unroll
  for (int r=0; r<4; ++r){
    int t = t0 + 4*g + r;
    int u = s - t + 128; u = u < 0 ? 0 : (u > 256 ? 256 : u);
    const unsigned short* q = Qr2 + (((size_t)b*1024 + s)*272 + u)*16;
    rv[r][0] = *(const bfx8*)q;
    rv[r][1] = *(const bfx8*)(q + 8);
  }

  f4 ps = fz;
#pragma unroll
  for (int hg=0; hg<2; ++hg){
    f4 sc[8];
#pragma unroll
    for (int h8=0; h8<8; ++h8){
      size_t bh = (size_t)(b*16 + hg*8 + h8);
      size_t qb = (bh*64 + st)*1024 + (size_t)lane*16;
      size_t kb = (bh*64 + tt)*1024 + (size_t)lane*16;
      bfx8 q0 = *(const bfx8*)(Qf + qb);
      bfx8 q1 = *(const bfx8*)(Qf + qb + 8);
      bfx8 k0 = *(const bfx8*)(Kf + kb);
      bfx8 k1 = *(const bfx8*)(Kf + kb + 8);
      sc[h8] = mfma32(k1, q1, mfma32(k0, q0, fz));
    }
#pragma unroll
    for (int h8=0; h8<8; ++h8)
#pragma unroll
      for (int r=0; r<4; ++r)
        ps[r] += __expf(sc[h8][r] + bf2f((unsigned short)rv[r][hg][h8]));
  }

  f4 inv;
#pragma unroll
  for (int r=0; r<4; ++r) inv[r] = 1.0f / ps[r];
  *(f4*)(ivf + (((size_t)(b*64 + tt)*64 + st)*64 + lane)*4) = inv;
}

// ---------------- far attention: barrier-free, fragment loads, balanced strided far list ----------------
__global__ __launch_bounds__(256, 3) void k_far(
    const unsigned short* __restrict__ Qf, const unsigned short* __restrict__ Kf,
    const unsigned short* __restrict__ Vf, const unsigned short* __restrict__ Qr2,
    const float* __restrict__ ivf, float* __restrict__ tails,
    unsigned short* __restrict__ op)
{
  __shared__ __align__(16) float slab[4][16][68];
  const int pbid  = blockIdx.x;
  const int b     = pbid & 3;
  const int part  = (pbid >> 2) & 3;
  const int hhalf = (pbid >> 4) & 1;
  const int st    = pbid >> 5;
  const int s0 = st << 4;
  const int w = threadIdx.x >> 6, lane = threadIdx.x & 63;
  const int p = lane & 15, g = lane >> 4;
  const int s = s0 + p;
  const int h0 = hhalf*8 + w*2;
  const f4 fz = {0.f,0.f,0.f,0.f};

  bfx8 qf[2][2]; float qr0[2], qr1[2];
#pragma unroll
  for (int hh=0; hh<2; ++hh){
    size_t bh = (size_t)(b*16 + h0 + hh);
    size_t qb = (bh*64 + st)*1024 + (size_t)lane*16;
    qf[hh][0] = *(const bfx8*)(Qf + qb);
    qf[hh][1] = *(const bfx8*)(Qf + qb + 8);
    qr0[hh] = bf2f(Qr2[(((size_t)b*1024 + s)*272 + 0)*16 + (h0+hh)]);
    qr1[hh] = bf2f(Qr2[(((size_t)b*1024 + s)*272 + 256)*16 + (h0+hh)]);
  }

  f4 o[2][4];
#pragma unroll
  for (int hh=0; hh<2; ++hh)
#pragma unroll
    for (int df=0; df<4; ++df) o[hh][df] = fz;
  float tl0[2] = {0.f,0.f};
  float tl1[2] = {0.f,0.f};

  const int tlo = (st-8 < 0) ? 0 : st-8;
  const int thi = (st+8 > 63) ? 63 : st+8;
  const int nband = thi - tlo + 1;
  const int nfar = 64 - nband;

  bfx8 kc[2][2]; bfx4 vc[2][4]; f4 is;
  bfx8 kn[2][2]; bfx4 vn[2][4]; f4 isn;

  int idx = part;
  {
    const int ti = (idx < tlo) ? idx : idx + nband;
#pragma unroll
    for (int hh=0; hh<2; ++hh){
      size_t fb = (((size_t)(b*16 + h0 + hh))*64 + ti)*1024 + (size_t)lane*16;
      kc[hh][0] = *(const bfx8*)(Kf + fb);
      kc[hh][1] = *(const bfx8*)(Kf + fb + 8);
#pragma unroll
      for (int df=0; df<4; ++df)
        vc[hh][df] = *(const bfx4*)(Vf + fb + df*4);
    }
    is = *(const f4*)(ivf + (((size_t)(b*64 + ti)*64 + st)*64 + lane)*4);
  }

  while (idx < nfar){
    const int idn = idx + 4;
    if (idn < nfar){
      const int tn = (idn < tlo) ? idn : idn + nband;
#pragma unroll
      for (int hh=0; hh<2; ++hh){
        size_t fb = (((size_t)(b*16 + h0 + hh))*64 + tn)*1024 + (size_t)lane*16;
        kn[hh][0] = *(const bfx8*)(Kf + fb);
        kn[hh][1] = *(const bfx8*)(Kf + fb + 8);
#pragma unroll
        for (int df=0; df<4; ++df)
          vn[hh][df] = *(const bfx4*)(Vf + fb + df*4);
      }
      isn = *(const f4*)(ivf + (((size_t)(b*64 + tn)*64 + st)*64 + lane)*4);
    }

    const int ti = (idx < tlo) ? idx : idx + nband;
    const bool hiSide = (ti < st);
#pragma unroll
    for (int hh=0; hh<2; ++hh){
      f4 sc = mfma32(kc[hh][1], qf[hh][1], mfma32(kc[hh][0], qf[hh][0], fz));
      const float qa = hiSide ? qr1[hh] : qr0[hh];
      f4 at;
#pragma unroll
      for (int r=0; r<4; ++r) at[r] = __expf(sc[r] + qa) * is[r];
      float tsum = at[0] + at[1] + at[2] + at[3];
      if (hiSide) tl1[hh] += tsum; else tl0[hh] += tsum;
      bfx4 pk;
#pragma unroll
      for (int r=0; r<4; ++r) pk[r] = (short)f2bf(at[r]);
#pragma unroll
      for (int df=0; df<4; ++df)
        o[hh][df] = mfma16(vc[hh][df], pk, o[hh][df]);
    }

    if (idn < nfar){
#pragma unroll
      for (int hh=0; hh<2; ++hh){
        kc[hh][0] = kn[hh][0]; kc[hh][1] = kn[hh][1];
#pragma unroll
        for (int df=0; df<4; ++df) vc[hh][df] = vn[hh][df];
      }
      is = isn;
    }
    idx = idn;
  }

  // tail buckets for this part
#pragma unroll
  for (int hh=0; hh<2; ++hh){
    float v0 = tl0[hh];
    v0 += __shfl_xor(v0, 16, 64);
    v0 += __shfl_xor(v0, 32, 64);
    float v1 = tl1[hh];
    v1 += __shfl_xor(v1, 16, 64);
    v1 += __shfl_xor(v1, 32, 64);
    if (g == 0){
      size_t tix = ((size_t)(part*64 + b*16 + h0 + hh)*1024 + s)*2;
      tails[tix + 0] = v0;
      tails[tix + 1] = v1;
    }
  }

  // transpose epilogue -> bf16 partial output for this part
  unsigned short* dst = op + (size_t)part * 4194304;
#pragma unroll
  for (int hh=0; hh<2; ++hh){
    float (*tb)[68] = slab[w];
#pragma unroll
    for (int df=0; df<4; ++df)
      *(f4*)&tb[p][df*16 + 4*g] = o[hh][df];
    __syncthreads();
    const int srow = lane >> 2, quad = lane & 3;
    f4 r0 = *(const f4*)&tb[srow][quad*16 + 0];
    f4 r1 = *(const f4*)&tb[srow][quad*16 + 4];
    f4 r2 = *(const f4*)&tb[srow][quad*16 + 8];
    f4 r3 = *(const f4*)&tb[srow][quad*16 + 12];
    bfx8 pa, pb;
#pragma unroll
    for (int j=0; j<4; ++j){
      pa[j]   = (short)f2bf(r0[j]);
      pa[j+4] = (short)f2bf(r1[j]);
      pb[j]   = (short)f2bf(r2[j]);
      pb[j+4] = (short)f2bf(r3[j]);
    }
    size_t addr = ((size_t)b*1024 + s0 + srow)*1024 + (h0+hh)*64 + quad*16;
    *(bfx8*)(dst + addr) = pa;
    *(bfx8*)(dst + addr + 8) = pb;
    __syncthreads();
  }
}

// ---------------- near attention (17 tiles) + fused rel_v GEMM + final out1 ----------------
__global__ __launch_bounds__(512, 2) void k_near(
    const unsigned short* __restrict__ Qf, const unsigned short* __restrict__ Kf,
    const unsigned short* __restrict__ Vf, const unsigned short* __restrict__ Qr2,
    const float* __restrict__ ivf, const unsigned short* __restrict__ relvT,
    const float* __restrict__ relv, const float* __restrict__ tails,
    const unsigned short* __restrict__ op, unsigned short* __restrict__ out1)
{
  __shared__ __align__(16) unsigned short skew[256*264];
  const int pbid = blockIdx.x;
  const int xcd = pbid & 7;
  const int b = xcd >> 1;
  const int st = ((pbid >> 3) << 1) | (xcd & 1);
  const int s0 = st << 4;
  const int w = threadIdx.x >> 6;
  const int lane = threadIdx.x & 63;
  const int p = lane & 15, g = lane >> 4;
  const int s = s0 + p;
  const int h0 = w * 2;
  const f4 fz = {0.f,0.f,0.f,0.f};

  {
    unsigned* zp = (unsigned*)skew + w*4224;
    for (int i = lane; i < 4224; i += 64) zp[i] = 0u;
  }

  bfx8 qf[2][2];
#pragma unroll
  for (int hh=0; hh<2; ++hh){
    size_t qb = (((size_t)(b*16 + h0 + hh))*64 + st)*1024 + (size_t)lane*16;
    qf[hh][0] = *(const bfx8*)(Qf + qb);
    qf[hh][1] = *(const bfx8*)(Qf + qb + 8);
  }

  f4 o[2][4];
#pragma unroll
  for (int hh=0; hh<2; ++hh)
#pragma unroll
    for (int df=0; df<4; ++df) o[hh][df] = fz;

  float tl0[2] = {0.f,0.f};
  float tl1[2] = {0.f,0.f};

  const int tlo = (st-8 < 0) ? 0 : st-8;
  const int thi = (st+8 > 63) ? 63 : st+8;

  bfx8 kc[2][2]; bfx4 vc[2][4]; unsigned short qc[2][4]; f4 is;
  bfx8 kn[2][2]; bfx4 vn[2][4]; unsigned short qn[2][4]; f4 isn;

#pragma unroll
  for (int hh=0; hh<2; ++hh){
    size_t bh = (size_t)(b*16 + h0 + hh);
    size_t fb = (bh*64 + tlo)*1024 + (size_t)lane*16;
    kc[hh][0] = *(const bfx8*)(Kf + fb);
    kc[hh][1] = *(const bfx8*)(Kf + fb + 8);
#pragma unroll
    for (int df=0; df<4; ++df)
      vc[hh][df] = *(const bfx4*)(Vf + fb + df*4);
#pragma unroll
    for (int r=0; r<4; ++r){
      int t = (tlo<<4) + 4*g + r;
      int u = s - t + 128; u = u < 0 ? 0 : (u > 256 ? 256 : u);
      qc[hh][r] = Qr2[(((size_t)b*1024 + s)*272 + u)*16 + (h0+hh)];
    }
  }
  is = *(const f4*)(ivf + (((size_t)(b*64 + tlo)*64 + st)*64 + lane)*4);

  for (int ti = tlo; ti <= thi; ++ti){
    const int t0 = ti << 4;

    if (ti < thi){
      const int tn = ti + 1;
#pragma unroll
      for (int hh=0; hh<2; ++hh){
        size_t bh = (size_t)(b*16 + h0 + hh);
        size_t fb = (bh*64 + tn)*1024 + (size_t)lane*16;
        kn[hh][0] = *(const bfx8*)(Kf + fb);
        kn[hh][1] = *(const bfx8*)(Kf + fb + 8);
#pragma unroll
        for (int df=0; df<4; ++df)
          vn[hh][df] = *(const bfx4*)(Vf + fb + df*4);
#pragma unroll
        for (int r=0; r<4; ++r){
          int t = (tn<<4) + 4*g + r;
          int u = s - t + 128; u = u < 0 ? 0 : (u > 256 ? 256 : u);
          qn[hh][r] = Qr2[(((size_t)b*1024 + s)*272 + u)*16 + (h0+hh)];
        }
      }
      isn = *(const f4*)(ivf + (((size_t)(b*64 + tn)*64 + st)*64 + lane)*4);
    }

#pragma unroll
    for (int hh=0; hh<2; ++hh){
      f4 sc = mfma32(kc[hh][1], qf[hh][1], mfma32(kc[hh][0], qf[hh][0], fz));
      f4 at;
#pragma unroll
      for (int r=0; r<4; ++r) at[r] = __expf(sc[r] + bf2f(qc[hh][r])) * is[r];
      const int row = (h0 + hh)*16 + p;
#pragma unroll
      for (int r=0; r<4; ++r){
        int t = t0 + 4*g + r;
        int u = s - t + 128;
        float a = at[r];
        if (u <= 0) tl0[hh] += a;
        else if (u >= 256) tl1[hh] += a;
        else skew[row*264 + u] = f2bf(a);
      }
      bfx4 pk;
#pragma unroll
      for (int r=0; r<4; ++r) pk[r] = (short)f2bf(at[r]);
#pragma unroll
      for (int df=0; df<4; ++df)
        o[hh][df] = mfma16(vc[hh][df], pk, o[hh][df]);
    }

    if (ti < thi){
#pragma unroll
      for (int hh=0; hh<2; ++hh){
#pragma unroll
        for (int kf=0; kf<2; ++kf) kc[hh][kf] = kn[hh][kf];
#pragma unroll
        for (int df=0; df<4; ++df) vc[hh][df] = vn[hh][df];
#pragma unroll
        for (int r=0; r<4; ++r) qc[hh][r] = qn[hh][r];
      }
      is = isn;
    }
  }

  __syncthreads();

  // ---- fused out2 = rel_v^T @ skew (own-wave rows only) ----
  f4 acc2[2][4];
#pragma unroll
  for (int hh=0; hh<2; ++hh)
#pragma unroll
    for (int df=0; df<4; ++df) acc2[hh][df] = fz;
#pragma unroll
  for (int k0=0; k0<256; k0+=32){
    bfx8 bb0 = *(const bfx8*)&skew[(h0*16 + p)*264 + k0 + 8*g];
    bfx8 bb1 = *(const bfx8*)&skew[((h0+1)*16 + p)*264 + k0 + 8*g];
#pragma unroll
    for (int df=0; df<4; ++df){
      bfx8 a = *(const bfx8*)(relvT + (size_t)(df*16 + p)*288 + k0 + 8*g);
      acc2[0][df] = mfma32(a, bb0, acc2[0][df]);
      acc2[1][df] = mfma32(a, bb1, acc2[1][df]);
    }
  }

  f4 rv0[4], rv1[4];
#pragma unroll
  for (int df=0; df<4; ++df){
    rv0[df] = *(const f4*)(relv + df*16 + 4*g);
    rv1[df] = *(const f4*)(relv + 16384 + df*16 + 4*g);
  }
#pragma unroll
  for (int hh=0; hh<2; ++hh){
    float tv0 = tl0[hh];
    tv0 += __shfl_xor(tv0, 16, 64);
    tv0 += __shfl_xor(tv0, 32, 64);
    float tv1 = tl1[hh];
    tv1 += __shfl_xor(tv1, 16, 64);
    tv1 += __shfl_xor(tv1, 32, 64);
    size_t bh = (size_t)(b*16 + h0 + hh);
#pragma unroll
    for (int part=0; part<4; ++part){
      size_t tix = ((size_t)(part*64) + bh)*2048 + (size_t)s*2;
      tv0 += tails[tix + 0];
      tv1 += tails[tix + 1];
    }
#pragma unroll
    for (int df=0; df<4; ++df)
#pragma unroll
      for (int r=0; r<4; ++r)
        o[hh][df][r] += acc2[hh][df][r] + tv0*rv0[df][r] + tv1*rv1[df][r];
  }

  __syncthreads();

  float* slabBase = (float*)skew;
  float (*tb)[68] = (float(*)[68])(slabBase + w*(16*68));
#pragma unroll
  for (int hh=0; hh<2; ++hh){
#pragma unroll
    for (int df=0; df<4; ++df)
      *(f4*)&tb[p][df*16 + 4*g] = o[hh][df];
    __syncthreads();
    const int srow = lane >> 2, quad = lane & 3;
    f4 r0 = *(const f4*)&tb[srow][quad*16 + 0];
    f4 r1 = *(const f4*)&tb[srow][quad*16 + 4];
    f4 r2 = *(const f4*)&tb[srow][quad*16 + 8];
    f4 r3 = *(const f4*)&tb[srow][quad*16 + 12];
    size_t addr = ((size_t)b*1024 + s0 + srow)*1024 + (h0+hh)*64 + quad*16;
    bfx8 pa, pb;
#pragma unroll
    for (int j=0; j<4; ++j){
      float a0 = r0[j], a1 = r1[j], a2 = r2[j], a3 = r3[j];
#pragma unroll
      for (int part=0; part<4; ++part){
        const unsigned short* pp = op + (size_t)part*4194304 + addr;
        bfx8 q0 = *(const bfx8*)pp;
        bfx8 q1 = *(const bfx8*)(pp + 8);
        a0 += bf2f((unsigned short)q0[j]);
        a1 += bf2f((unsigned short)q0[j+4]);
        a2 += bf2f((unsigned short)q1[j]);
        a3 += bf2f((unsigned short)q1[j+4]);
      }
      pa[j]   = (short)f2bf(a0);
      pa[j+4] = (short)f2bf(a1);
      pb[j]   = (short)f2bf(a2);
      pb[j+4] = (short)f2bf(a3);
    }
    *(bfx8*)(out1 + addr) = pa;
    *(bfx8*)(out1 + addr + 8) = pb;
    __syncthreads();
  }
}

// ---------------- final projection, LDS-staged: d_out[(s,b)][n] = out1 @ w_o^T + b_o ----------------
__global__ __launch_bounds__(256) void k_wo(
    const unsigned short* __restrict__ out1, const unsigned short* __restrict__ wo,
    const float* __restrict__ bo, float* __restrict__ dout)
{
  __shared__ __align__(16) unsigned short Al[2048];
  __shared__ __align__(16) unsigned short Bl[4096];
  const int nt = blockIdx.x;
  const int mt = blockIdx.y;
  const int w = threadIdx.x >> 6, lane = threadIdx.x & 63;
  const int wr = w >> 1, wc = w & 1;
  const int p = lane & 15, g = lane >> 4;
  const int m0 = mt*64, n0 = nt*128;
  const f4 fz = {0.f,0.f,0.f,0.f};
  f4 acc[2][4];
#pragma unroll
  for (int m=0;m<2;++m)
#pragma unroll
    for (int n=0;n<4;++n) acc[m][n] = fz;

  const int j0 = w*2, j1 = w*2 + 1;
  const unsigned short* gA = out1 + (size_t)(m0 + p)*1024 + g*8;
  const unsigned short* gB = wo   + (size_t)(n0 + p)*1024 + g*8;

  for (int k0=0; k0<1024; k0+=32){
    gload16(gA + (size_t)w*16384 + k0, Al + w*512);
    gload16(gB + (size_t)j0*16384 + k0, Bl + j0*512);
    gload16(gB + (size_t)j1*16384 + k0, Bl + j1*512);
    __syncthreads();
    bfx8 af[2], bf[4];
#pragma unroll
    for (int m=0;m<2;++m) af[m] = *(const bfx8*)(Al + (wr*2+m)*512 + lane*8);
#pragma unroll
    for (int n=0;n<4;++n) bf[n] = *(const bfx8*)(Bl + (wc*4+n)*512 + lane*8);
#pragma unroll
    for (int m=0;m<2;++m)
#pragma unroll
      for (int n=0;n<4;++n)
        acc[m][n] = mfma32(af[m], bf[n], acc[m][n]);
    __syncthreads();
  }

#pragma unroll
  for (int n=0;n<4;++n){
    const int col = n0 + wc*64 + n*16 + p;
    const float bias = bo[col];
#pragma unroll
    for (int m=0;m<2;++m)
#pragma unroll
      for (int r=0;r<4;++r){
        int row = m0 + wr*32 + m*16 + 4*g + r;
        int bb = row >> 10, s = row & 1023;
        dout[((size_t)s*4 + bb)*1024 + col] = acc[m][n][r] + bias;
      }
  }
}

extern "C" void kernel_launch(void* const* d_in, const int* in_sizes, int n_in,
                              void* d_out, int out_size, void* d_ws, size_t ws_size,
                              hipStream_t stream){
  const float* x   = (const float*)d_in[0];
  const float* wq  = (const float*)d_in[1];
  const float* wk  = (const float*)d_in[2];
  const float* wv  = (const float*)d_in[3];
  const float* wo  = (const float*)d_in[4];
  const float* bo  = (const float*)d_in[5];
  const float* rlk = (const float*)d_in[6];
  const float* rlv = (const float*)d_in[7];
  char* ws = (char*)d_ws;

  unsigned short* x_bf    = (unsigned short*)(ws + 0);
  unsigned short* wq_bf   = (unsigned short*)(ws + 8388608);   // [wq|wk|wv|wo] contiguous
  unsigned short* relk_bf = (unsigned short*)(ws + 16777216);
  unsigned short* relvT_bf= (unsigned short*)(ws + 16812032);
  unsigned short* Qf      = (unsigned short*)(ws + 16848896);   // fragment layout
  unsigned short* Kf      = (unsigned short*)(ws + 25237504);   // fragment layout
  unsigned short* Vf      = (unsigned short*)(ws + 33626112);   // fragment layout
  unsigned short* Qr2     = (unsigned short*)(ws + 42014720);   // 35.65 MB -> 77666304
  float*          tails   = (float*)        (ws + 77666304);   // 2 MB -> 79763456
  unsigned short* op      = (unsigned short*)(ws + 79763456);   // 32 MB (4 parts) -> 113317888
  unsigned short* out1    = (unsigned short*)(ws + 113317888);  // 8 MB -> 121706496
  float*          ivf     = (float*)        (ws + 121706496);  // 16 MB -> 138483712
  unsigned short* wo_bf   = (unsigned short*)(ws + 14680064);

  k_cast<<<4096, 256, 0, stream>>>(x, x_bf, 1048576);
  k_castw<<<dim3(1024,4), 256, 0, stream>>>(wq, wk, wv, wo, wq_bf);
  k_relprep<<<72, 256, 0, stream>>>(rlk, rlv, relk_bf, relvT_bf);

  k_qkv<<<dim3(24,4,8), 256, 0, stream>>>(x_bf, wq_bf, Qf, Kf, Vf);
  k_qr<<<512, 256, 0, stream>>>(Qf, relk_bf, Qr2);

  k_s  <<<4096, 256, 0, stream>>>(Qf, Kf, Qr2, ivf);
  k_far<<<2048, 256, 0, stream>>>(Qf, Kf, Vf, Qr2, ivf, tails, op);
  k_near<<<256, 512, 0, stream>>>(Qf, Kf, Vf, Qr2, ivf, relvT_bf, rlv, tails, op, out1);
  k_wo<<<dim3(8,64), 256, 0, stream>>>(out1, wo_bf, bo, (float*)d_out);
}

// Round 10
// 266.367 us; speedup vs baseline: 2.9520x; 1.0213x over previous
//
#include <hip/hip_runtime.h>
#include <stdint.h>

#define DI __device__ __forceinline__

typedef __attribute__((ext_vector_type(8))) short bfx8;
typedef __attribute__((ext_vector_type(4))) short bfx4;
typedef __attribute__((ext_vector_type(4))) float f4;

DI unsigned short f2bf(float x){
  unsigned u = __float_as_uint(x);
  u = (u + 0x7FFFu + ((u >> 16) & 1u)) >> 16;
  return (unsigned short)u;
}
DI float bf2f(unsigned short h){ return __uint_as_float(((unsigned)h) << 16); }

DI f4 mfma32(bfx8 a, bfx8 b, f4 c){
  return __builtin_amdgcn_mfma_f32_16x16x32_bf16(a, b, c, 0, 0, 0);
}
#if __has_builtin(__builtin_amdgcn_mfma_f32_16x16x16bf16_1k)
DI f4 mfma16(bfx4 a, bfx4 b, f4 c){
  return __builtin_amdgcn_mfma_f32_16x16x16bf16_1k(a, b, c, 0, 0, 0);
}
#else
DI f4 mfma16(bfx4 a, bfx4 b, f4 c){
  f4 d = c;
  asm volatile("v_mfma_f32_16x16x16_bf16 %0, %1, %2, %0" : "+v"(d) : "v"(a), "v"(b));
  return d;
}
#endif

// async global->LDS, 16B per lane; LDS dest = wave-uniform base + lane*16
DI void gload16(const void* g, void* l){
  __builtin_amdgcn_global_load_lds(
      (__attribute__((address_space(1))) void*)g,
      (__attribute__((address_space(3))) void*)l, 16, 0, 0);
}

// Fragment layouts (all 16-bit elems):
//   Qf/Kf[bh][tile][lane][16]: elem[kf*8+j] = M[tile*16 + (lane&15)][kf*32 + 8*(lane>>4) + j]
//   Vf  [bh][tile][lane][16]: elem[df*4+j] = V[tile*16 + 4*(lane>>4) + j][df*16 + (lane&15)]
//   ivf [b][tt][st][lane][4]: elem[r] = 1/S at (s = st*16 + (lane&15), t = tt*16 + 4*(lane>>4) + r)

// ---------------- cast f32 -> bf16 (4-wide) ----------------
__global__ void k_cast(const float* __restrict__ src, unsigned short* __restrict__ dst, int n4){
  int i = blockIdx.x*256 + threadIdx.x;
  if (i < n4){
    const float4 v = ((const float4*)src)[i];
    bfx4 o;
    o[0] = (short)f2bf(v.x); o[1] = (short)f2bf(v.y);
    o[2] = (short)f2bf(v.z); o[3] = (short)f2bf(v.w);
    *(bfx4*)(dst + (size_t)i*4) = o;
  }
}

// merged weight cast: 4 matrices (1024x1024 f32) -> contiguous bf16 dsts
__global__ void k_castw(const float* __restrict__ s0, const float* __restrict__ s1,
                        const float* __restrict__ s2, const float* __restrict__ s3,
                        unsigned short* __restrict__ dst){
  int i = blockIdx.x*256 + threadIdx.x;      // < 262144
  const float* src = (blockIdx.y==0) ? s0 : (blockIdx.y==1) ? s1 : (blockIdx.y==2) ? s2 : s3;
  const float4 v = ((const float4*)src)[i];
  bfx4 o;
  o[0] = (short)f2bf(v.x); o[1] = (short)f2bf(v.y);
  o[2] = (short)f2bf(v.z); o[3] = (short)f2bf(v.w);
  *(bfx4*)(dst + (size_t)blockIdx.y*1048576 + (size_t)i*4) = o;
}

// relk_bf: [272][64] zero-padded rows; relvT_bf: [64][288] = rel_v^T zero-padded cols
__global__ void k_relprep(const float* __restrict__ rlk, const float* __restrict__ rlv,
                          unsigned short* __restrict__ relk_bf, unsigned short* __restrict__ relvT_bf){
  int i = blockIdx.x*256 + threadIdx.x;
  if (i < 272*64){
    int r = i >> 6, d = i & 63;
    relk_bf[i] = (r < 257) ? f2bf(rlk[r*64 + d]) : (unsigned short)0;
  }
  if (i < 64*288){
    int d = i / 288, r = i % 288;
    relvT_bf[i] = (r < 257) ? f2bf(rlv[(size_t)r*64 + d]) : (unsigned short)0;
  }
}

// ---------------- QKV projections: 2-phase double-buffered LDS staging ----------------
// Loop: STAGE(buf^1, k+32) async -> compute(buf) -> one __syncthreads -> swap.
__global__ __launch_bounds__(256) void k_qkv(
    const unsigned short* __restrict__ xbf, const unsigned short* __restrict__ wqkv,
    unsigned short* __restrict__ Qf, unsigned short* __restrict__ Kf,
    unsigned short* __restrict__ Vf)
{
  __shared__ __align__(16) unsigned short smem[2][8192];   // 2 x 16 KB: A blocks 0-7, B blocks 8-15
  const int nt = blockIdx.x;
  const int b  = blockIdx.y;
  const int st = blockIdx.z;
  const int w = threadIdx.x >> 6, lane = threadIdx.x & 63;
  const int wr = w >> 1, wc = w & 1;
  const int p = lane & 15, g = lane >> 4;
  const int s0 = st*128;
  const int n0 = nt*128;
  const f4 fz = {0.f,0.f,0.f,0.f};
  f4 acc[4][4];
#pragma unroll
  for (int m=0;m<4;++m)
#pragma unroll
    for (int n=0;n<4;++n) acc[m][n] = fz;

  const int j0 = w*2, j1 = w*2 + 1;
  const unsigned short* gA = xbf  + (size_t)((s0 + p)*4 + b)*1024 + g*8;
  const unsigned short* gB = wqkv + (size_t)(n0 + p)*1024 + g*8;

  // prologue: stage k=0 into buf 0
  {
    unsigned short* d0 = &smem[0][0];
    gload16(gA + (size_t)j0*65536, d0 + j0*512);
    gload16(gA + (size_t)j1*65536, d0 + j1*512);
    gload16(gB + (size_t)j0*16384, d0 + 4096 + j0*512);
    gload16(gB + (size_t)j1*16384, d0 + 4096 + j1*512);
  }
  __syncthreads();

  int cur = 0;
  for (int k0=0; k0<1024; k0+=32){
    const int kn = k0 + 32;
    if (kn < 1024){
      unsigned short* dn = &smem[cur^1][0];
      gload16(gA + (size_t)j0*65536 + kn, dn + j0*512);
      gload16(gA + (size_t)j1*65536 + kn, dn + j1*512);
      gload16(gB + (size_t)j0*16384 + kn, dn + 4096 + j0*512);
      gload16(gB + (size_t)j1*16384 + kn, dn + 4096 + j1*512);
    }
    const unsigned short* Ab = &smem[cur][0];
    bfx8 af[4], bfr[4];
#pragma unroll
    for (int m=0;m<4;++m) af[m] = *(const bfx8*)(Ab + (wr*4+m)*512 + lane*8);
#pragma unroll
    for (int n=0;n<4;++n) bfr[n] = *(const bfx8*)(Ab + 4096 + (wc*4+n)*512 + lane*8);
#pragma unroll
    for (int m=0;m<4;++m)
#pragma unroll
      for (int n=0;n<4;++n)
        acc[m][n] = mfma32(af[m], bfr[n], acc[m][n]);
    __syncthreads();   // drains next-tile loads (after compute) + protects buffer reuse
    cur ^= 1;
  }

  const int n64 = n0 + wc*64;
  const int sec = n64 >> 10;            // 0 Q, 1 K, 2 V
  const int h = (n64 & 1023) >> 6;
  float* es = (float*)&smem[0][0] + w*1280;   // alias tile LDS as per-wave epilogue slab

  if (sec < 2){
    const float scl = (sec == 0) ? 0.125f : 1.0f;
    unsigned short* dst = (sec == 0) ? Qf : Kf;
#pragma unroll
    for (int m=0;m<4;++m){
#pragma unroll
      for (int n=0;n<4;++n)
#pragma unroll
        for (int r=0;r<4;++r)
          es[(4*g + r)*80 + 16*n + p] = acc[m][n][r] * scl;
      __syncthreads();
      f4 v0 = *(const f4*)&es[p*80 + 8*g];
      f4 v1 = *(const f4*)&es[p*80 + 8*g + 4];
      f4 v2 = *(const f4*)&es[p*80 + 32 + 8*g];
      f4 v3 = *(const f4*)&es[p*80 + 32 + 8*g + 4];
      bfx8 lo, hi;
#pragma unroll
      for (int j=0;j<4;++j){
        lo[j]   = (short)f2bf(v0[j]);
        lo[j+4] = (short)f2bf(v1[j]);
        hi[j]   = (short)f2bf(v2[j]);
        hi[j+4] = (short)f2bf(v3[j]);
      }
      size_t fb = ((size_t)(b*16 + h)*64 + (st*8 + wr*4 + m))*1024 + (size_t)lane*16;
      *(bfx8*)(dst + fb) = lo;
      *(bfx8*)(dst + fb + 8) = hi;
      __syncthreads();
    }
  } else {
#pragma unroll
    for (int m=0;m<4;++m){
#pragma unroll
      for (int n=0;n<4;++n)
        *(f4*)&es[(16*n + p)*20 + 4*g] = acc[m][n];
      __syncthreads();
      f4 vv0 = *(const f4*)&es[(p)*20 + 4*g];
      f4 vv1 = *(const f4*)&es[(16 + p)*20 + 4*g];
      f4 vv2 = *(const f4*)&es[(32 + p)*20 + 4*g];
      f4 vv3 = *(const f4*)&es[(48 + p)*20 + 4*g];
      bfx8 lo, hi;
#pragma unroll
      for (int j=0;j<4;++j){
        lo[j]   = (short)f2bf(vv0[j]);
        lo[j+4] = (short)f2bf(vv1[j]);
        hi[j]   = (short)f2bf(vv2[j]);
        hi[j+4] = (short)f2bf(vv3[j]);
      }
      size_t fb = ((size_t)(b*16 + h)*64 + (st*8 + wr*4 + m))*1024 + (size_t)lane*16;
      *(bfx8*)(Vf + fb) = lo;
      *(bfx8*)(Vf + fb + 8) = hi;
      __syncthreads();
    }
  }
}

// ---------------- Qr2 producer, write-coalesced: all 16 heads per block ----------------
__global__ __launch_bounds__(256) void k_qr(
    const unsigned short* __restrict__ Qf, const unsigned short* __restrict__ relk,
    unsigned short* __restrict__ Qr2)
{
  __shared__ __align__(16) unsigned short sst[16][16][24];
  const int bx = blockIdx.x;
  const int b  = bx & 3;
  const int st = (bx >> 2) & 63;
  const int uh = bx >> 8;
  const int w = threadIdx.x >> 6, lane = threadIdx.x & 63;
  const int p = lane & 15, g = lane >> 4;
  const int s0 = st << 4;
  const f4 fz = {0.f,0.f,0.f,0.f};

  bfx8 a0[4], a1[4];
#pragma unroll
  for (int hh=0; hh<4; ++hh){
    size_t fb = (((size_t)(b*16 + w*4 + hh))*64 + st)*1024 + (size_t)lane*16;
    a0[hh] = *(const bfx8*)(Qf + fb);
    a1[hh] = *(const bfx8*)(Qf + fb + 8);
  }

  const int c0 = uh ? 9 : 0;
  const int c1 = uh ? 17 : 9;
  const int so = threadIdx.x >> 4, uo = threadIdx.x & 15;

  for (int c=c0; c<c1; ++c){
    const int r0 = c << 4;
    bfx8 b0 = *(const bfx8*)(relk + (size_t)(r0 + p)*64 + 8*g);
    bfx8 b1 = *(const bfx8*)(relk + (size_t)(r0 + p)*64 + 32 + 8*g);
#pragma unroll
    for (int hh=0; hh<4; ++hh){
      f4 acc = mfma32(a1[hh], b1, mfma32(a0[hh], b0, fz));
#pragma unroll
      for (int r=0; r<4; ++r)
        sst[4*g + r][p][w*4 + hh] = f2bf(acc[r]);
    }
    __syncthreads();
    bfx8 v0 = *(const bfx8*)&sst[so][uo][0];
    bfx8 v1 = *(const bfx8*)&sst[so][uo][8];
    size_t ga = (((size_t)b*1024 + s0 + so)*272 + r0 + uo)*16;
    *(bfx8*)(Qr2 + ga) = v0;
    *(bfx8*)(Qr2 + ga + 8) = v1;
    __syncthreads();
  }
}

// ---------------- softmax denominator -> ivf (fragment layout, coalesced) ----------------
__global__ __launch_bounds__(256, 3) void k_s(
    const unsigned short* __restrict__ Qf, const unsigned short* __restrict__ Kf,
    const unsigned short* __restrict__ Qr2, float* __restrict__ ivf)
{
  const int pbid = blockIdx.x;            // (st<<6)|(ttg<<2)|b
  const int b   = pbid & 3;
  const int ttg = (pbid >> 2) & 15;
  const int st  = pbid >> 6;
  const int w = threadIdx.x >> 6, lane = threadIdx.x & 63;
  const int tt = ttg*4 + w;
  const int p = lane & 15, g = lane >> 4;
  const int s0 = st << 4, t0 = tt << 4;
  const int s = s0 + p;
  const f4 fz = {0.f,0.f,0.f,0.f};

  bfx8 rv[4][2];
#pragma unroll
  for (int r=0; r<4; ++r){
    int t = t0 + 4*g + r;
    int u = s - t + 128; u = u < 0 ? 0 : (u > 256 ? 256 : u);
    const unsigned short* q = Qr2 + (((size_t)b*1024 + s)*272 + u)*16;
    rv[r][0] = *(const bfx8*)q;
    rv[r][1] = *(const bfx8*)(q + 8);
  }

  f4 ps = fz;
#pragma unroll
  for (int hg=0; hg<2; ++hg){
    f4 sc[8];
#pragma unroll
    for (int h8=0; h8<8; ++h8){
      size_t bh = (size_t)(b*16 + hg*8 + h8);
      size_t qb = (bh*64 + st)*1024 + (size_t)lane*16;
      size_t kb = (bh*64 + tt)*1024 + (size_t)lane*16;
      bfx8 q0 = *(const bfx8*)(Qf + qb);
      bfx8 q1 = *(const bfx8*)(Qf + qb + 8);
      bfx8 k0 = *(const bfx8*)(Kf + kb);
      bfx8 k1 = *(const bfx8*)(Kf + kb + 8);
      sc[h8] = mfma32(k1, q1, mfma32(k0, q0, fz));
    }
#pragma unroll
    for (int h8=0; h8<8; ++h8)
#pragma unroll
      for (int r=0; r<4; ++r)
        ps[r] += __expf(sc[h8][r] + bf2f((unsigned short)rv[r][hg][h8]));
  }

  f4 inv;
#pragma unroll
  for (int r=0; r<4; ++r) inv[r] = 1.0f / ps[r];
  *(f4*)(ivf + (((size_t)(b*64 + tt)*64 + st)*64 + lane)*4) = inv;
}

// ---------------- far attention: barrier-free, fragment loads, balanced strided far list ----------------
__global__ __launch_bounds__(256, 3) void k_far(
    const unsigned short* __restrict__ Qf, const unsigned short* __restrict__ Kf,
    const unsigned short* __restrict__ Vf, const unsigned short* __restrict__ Qr2,
    const float* __restrict__ ivf, float* __restrict__ tails,
    unsigned short* __restrict__ op)
{
  __shared__ __align__(16) float slab[4][16][68];
  const int pbid  = blockIdx.x;
  const int b     = pbid & 3;
  const int part  = (pbid >> 2) & 3;
  const int hhalf = (pbid >> 4) & 1;
  const int st    = pbid >> 5;
  const int s0 = st << 4;
  const int w = threadIdx.x >> 6, lane = threadIdx.x & 63;
  const int p = lane & 15, g = lane >> 4;
  const int s = s0 + p;
  const int h0 = hhalf*8 + w*2;
  const f4 fz = {0.f,0.f,0.f,0.f};

  bfx8 qf[2][2]; float qr0[2], qr1[2];
#pragma unroll
  for (int hh=0; hh<2; ++hh){
    size_t bh = (size_t)(b*16 + h0 + hh);
    size_t qb = (bh*64 + st)*1024 + (size_t)lane*16;
    qf[hh][0] = *(const bfx8*)(Qf + qb);
    qf[hh][1] = *(const bfx8*)(Qf + qb + 8);
    qr0[hh] = bf2f(Qr2[(((size_t)b*1024 + s)*272 + 0)*16 + (h0+hh)]);
    qr1[hh] = bf2f(Qr2[(((size_t)b*1024 + s)*272 + 256)*16 + (h0+hh)]);
  }

  f4 o[2][4];
#pragma unroll
  for (int hh=0; hh<2; ++hh)
#pragma unroll
    for (int df=0; df<4; ++df) o[hh][df] = fz;
  float tl0[2] = {0.f,0.f};
  float tl1[2] = {0.f,0.f};

  const int tlo = (st-8 < 0) ? 0 : st-8;
  const int thi = (st+8 > 63) ? 63 : st+8;
  const int nband = thi - tlo + 1;
  const int nfar = 64 - nband;

  bfx8 kc[2][2]; bfx4 vc[2][4]; f4 is;
  bfx8 kn[2][2]; bfx4 vn[2][4]; f4 isn;

  int idx = part;
  {
    const int ti = (idx < tlo) ? idx : idx + nband;
#pragma unroll
    for (int hh=0; hh<2; ++hh){
      size_t fb = (((size_t)(b*16 + h0 + hh))*64 + ti)*1024 + (size_t)lane*16;
      kc[hh][0] = *(const bfx8*)(Kf + fb);
      kc[hh][1] = *(const bfx8*)(Kf + fb + 8);
#pragma unroll
      for (int df=0; df<4; ++df)
        vc[hh][df] = *(const bfx4*)(Vf + fb + df*4);
    }
    is = *(const f4*)(ivf + (((size_t)(b*64 + ti)*64 + st)*64 + lane)*4);
  }

  while (idx < nfar){
    const int idn = idx + 4;
    if (idn < nfar){
      const int tn = (idn < tlo) ? idn : idn + nband;
#pragma unroll
      for (int hh=0; hh<2; ++hh){
        size_t fb = (((size_t)(b*16 + h0 + hh))*64 + tn)*1024 + (size_t)lane*16;
        kn[hh][0] = *(const bfx8*)(Kf + fb);
        kn[hh][1] = *(const bfx8*)(Kf + fb + 8);
#pragma unroll
        for (int df=0; df<4; ++df)
          vn[hh][df] = *(const bfx4*)(Vf + fb + df*4);
      }
      isn = *(const f4*)(ivf + (((size_t)(b*64 + tn)*64 + st)*64 + lane)*4);
    }

    const int ti = (idx < tlo) ? idx : idx + nband;
    const bool hiSide = (ti < st);
#pragma unroll
    for (int hh=0; hh<2; ++hh){
      f4 sc = mfma32(kc[hh][1], qf[hh][1], mfma32(kc[hh][0], qf[hh][0], fz));
      const float qa = hiSide ? qr1[hh] : qr0[hh];
      f4 at;
#pragma unroll
      for (int r=0; r<4; ++r) at[r] = __expf(sc[r] + qa) * is[r];
      float tsum = at[0] + at[1] + at[2] + at[3];
      if (hiSide) tl1[hh] += tsum; else tl0[hh] += tsum;
      bfx4 pk;
#pragma unroll
      for (int r=0; r<4; ++r) pk[r] = (short)f2bf(at[r]);
#pragma unroll
      for (int df=0; df<4; ++df)
        o[hh][df] = mfma16(vc[hh][df], pk, o[hh][df]);
    }

    if (idn < nfar){
#pragma unroll
      for (int hh=0; hh<2; ++hh){
        kc[hh][0] = kn[hh][0]; kc[hh][1] = kn[hh][1];
#pragma unroll
        for (int df=0; df<4; ++df) vc[hh][df] = vn[hh][df];
      }
      is = isn;
    }
    idx = idn;
  }

  // tail buckets for this part
#pragma unroll
  for (int hh=0; hh<2; ++hh){
    float v0 = tl0[hh];
    v0 += __shfl_xor(v0, 16, 64);
    v0 += __shfl_xor(v0, 32, 64);
    float v1 = tl1[hh];
    v1 += __shfl_xor(v1, 16, 64);
    v1 += __shfl_xor(v1, 32, 64);
    if (g == 0){
      size_t tix = ((size_t)(part*64 + b*16 + h0 + hh)*1024 + s)*2;
      tails[tix + 0] = v0;
      tails[tix + 1] = v1;
    }
  }

  // transpose epilogue -> bf16 partial output for this part
  unsigned short* dst = op + (size_t)part * 4194304;
#pragma unroll
  for (int hh=0; hh<2; ++hh){
    float (*tb)[68] = slab[w];
#pragma unroll
    for (int df=0; df<4; ++df)
      *(f4*)&tb[p][df*16 + 4*g] = o[hh][df];
    __syncthreads();
    const int srow = lane >> 2, quad = lane & 3;
    f4 r0 = *(const f4*)&tb[srow][quad*16 + 0];
    f4 r1 = *(const f4*)&tb[srow][quad*16 + 4];
    f4 r2 = *(const f4*)&tb[srow][quad*16 + 8];
    f4 r3 = *(const f4*)&tb[srow][quad*16 + 12];
    bfx8 pa, pb;
#pragma unroll
    for (int j=0; j<4; ++j){
      pa[j]   = (short)f2bf(r0[j]);
      pa[j+4] = (short)f2bf(r1[j]);
      pb[j]   = (short)f2bf(r2[j]);
      pb[j+4] = (short)f2bf(r3[j]);
    }
    size_t addr = ((size_t)b*1024 + s0 + srow)*1024 + (h0+hh)*64 + quad*16;
    *(bfx8*)(dst + addr) = pa;
    *(bfx8*)(dst + addr + 8) = pb;
    __syncthreads();
  }
}

// ---------------- near attention (17 tiles) + fused rel_v GEMM + final out1 ----------------
__global__ __launch_bounds__(512, 2) void k_near(
    const unsigned short* __restrict__ Qf, const unsigned short* __restrict__ Kf,
    const unsigned short* __restrict__ Vf, const unsigned short* __restrict__ Qr2,
    const float* __restrict__ ivf, const unsigned short* __restrict__ relvT,
    const float* __restrict__ relv, const float* __restrict__ tails,
    const unsigned short* __restrict__ op, unsigned short* __restrict__ out1)
{
  __shared__ __align__(16) unsigned short skew[256*264];
  const int pbid = blockIdx.x;
  const int xcd = pbid & 7;
  const int b = xcd >> 1;
  const int st = ((pbid >> 3) << 1) | (xcd & 1);
  const int s0 = st << 4;
  const int w = threadIdx.x >> 6;
  const int lane = threadIdx.x & 63;
  const int p = lane & 15, g = lane >> 4;
  const int s = s0 + p;
  const int h0 = w * 2;
  const f4 fz = {0.f,0.f,0.f,0.f};

  {
    unsigned* zp = (unsigned*)skew + w*4224;
    for (int i = lane; i < 4224; i += 64) zp[i] = 0u;
  }

  bfx8 qf[2][2];
#pragma unroll
  for (int hh=0; hh<2; ++hh){
    size_t qb = (((size_t)(b*16 + h0 + hh))*64 + st)*1024 + (size_t)lane*16;
    qf[hh][0] = *(const bfx8*)(Qf + qb);
    qf[hh][1] = *(const bfx8*)(Qf + qb + 8);
  }

  f4 o[2][4];
#pragma unroll
  for (int hh=0; hh<2; ++hh)
#pragma unroll
    for (int df=0; df<4; ++df) o[hh][df] = fz;

  float tl0[2] = {0.f,0.f};
  float tl1[2] = {0.f,0.f};

  const int tlo = (st-8 < 0) ? 0 : st-8;
  const int thi = (st+8 > 63) ? 63 : st+8;

  bfx8 kc[2][2]; bfx4 vc[2][4]; unsigned short qc[2][4]; f4 is;
  bfx8 kn[2][2]; bfx4 vn[2][4]; unsigned short qn[2][4]; f4 isn;

#pragma unroll
  for (int hh=0; hh<2; ++hh){
    size_t bh = (size_t)(b*16 + h0 + hh);
    size_t fb = (bh*64 + tlo)*1024 + (size_t)lane*16;
    kc[hh][0] = *(const bfx8*)(Kf + fb);
    kc[hh][1] = *(const bfx8*)(Kf + fb + 8);
#pragma unroll
    for (int df=0; df<4; ++df)
      vc[hh][df] = *(const bfx4*)(Vf + fb + df*4);
#pragma unroll
    for (int r=0; r<4; ++r){
      int t = (tlo<<4) + 4*g + r;
      int u = s - t + 128; u = u < 0 ? 0 : (u > 256 ? 256 : u);
      qc[hh][r] = Qr2[(((size_t)b*1024 + s)*272 + u)*16 + (h0+hh)];
    }
  }
  is = *(const f4*)(ivf + (((size_t)(b*64 + tlo)*64 + st)*64 + lane)*4);

  for (int ti = tlo; ti <= thi; ++ti){
    const int t0 = ti << 4;

    if (ti < thi){
      const int tn = ti + 1;
#pragma unroll
      for (int hh=0; hh<2; ++hh){
        size_t bh = (size_t)(b*16 + h0 + hh);
        size_t fb = (bh*64 + tn)*1024 + (size_t)lane*16;
        kn[hh][0] = *(const bfx8*)(Kf + fb);
        kn[hh][1] = *(const bfx8*)(Kf + fb + 8);
#pragma unroll
        for (int df=0; df<4; ++df)
          vn[hh][df] = *(const bfx4*)(Vf + fb + df*4);
#pragma unroll
        for (int r=0; r<4; ++r){
          int t = (tn<<4) + 4*g + r;
          int u = s - t + 128; u = u < 0 ? 0 : (u > 256 ? 256 : u);
          qn[hh][r] = Qr2[(((size_t)b*1024 + s)*272 + u)*16 + (h0+hh)];
        }
      }
      isn = *(const f4*)(ivf + (((size_t)(b*64 + tn)*64 + st)*64 + lane)*4);
    }

#pragma unroll
    for (int hh=0; hh<2; ++hh){
      f4 sc = mfma32(kc[hh][1], qf[hh][1], mfma32(kc[hh][0], qf[hh][0], fz));
      f4 at;
#pragma unroll
      for (int r=0; r<4; ++r) at[r] = __expf(sc[r] + bf2f(qc[hh][r])) * is[r];
      const int row = (h0 + hh)*16 + p;
#pragma unroll
      for (int r=0; r<4; ++r){
        int t = t0 + 4*g + r;
        int u = s - t + 128;
        float a = at[r];
        if (u <= 0) tl0[hh] += a;
        else if (u >= 256) tl1[hh] += a;
        else skew[row*264 + u] = f2bf(a);
      }
      bfx4 pk;
#pragma unroll
      for (int r=0; r<4; ++r) pk[r] = (short)f2bf(at[r]);
#pragma unroll
      for (int df=0; df<4; ++df)
        o[hh][df] = mfma16(vc[hh][df], pk, o[hh][df]);
    }

    if (ti < thi){
#pragma unroll
      for (int hh=0; hh<2; ++hh){
#pragma unroll
        for (int kf=0; kf<2; ++kf) kc[hh][kf] = kn[hh][kf];
#pragma unroll
        for (int df=0; df<4; ++df) vc[hh][df] = vn[hh][df];
#pragma unroll
        for (int r=0; r<4; ++r) qc[hh][r] = qn[hh][r];
      }
      is = isn;
    }
  }

  __syncthreads();

  // ---- fused out2 = rel_v^T @ skew (own-wave rows only) ----
  f4 acc2[2][4];
#pragma unroll
  for (int hh=0; hh<2; ++hh)
#pragma unroll
    for (int df=0; df<4; ++df) acc2[hh][df] = fz;
#pragma unroll
  for (int k0=0; k0<256; k0+=32){
    bfx8 bb0 = *(const bfx8*)&skew[(h0*16 + p)*264 + k0 + 8*g];
    bfx8 bb1 = *(const bfx8*)&skew[((h0+1)*16 + p)*264 + k0 + 8*g];
#pragma unroll
    for (int df=0; df<4; ++df){
      bfx8 a = *(const bfx8*)(relvT + (size_t)(df*16 + p)*288 + k0 + 8*g);
      acc2[0][df] = mfma32(a, bb0, acc2[0][df]);
      acc2[1][df] = mfma32(a, bb1, acc2[1][df]);
    }
  }

  f4 rv0[4], rv1[4];
#pragma unroll
  for (int df=0; df<4; ++df){
    rv0[df] = *(const f4*)(relv + df*16 + 4*g);
    rv1[df] = *(const f4*)(relv + 16384 + df*16 + 4*g);
  }
#pragma unroll
  for (int hh=0; hh<2; ++hh){
    float tv0 = tl0[hh];
    tv0 += __shfl_xor(tv0, 16, 64);
    tv0 += __shfl_xor(tv0, 32, 64);
    float tv1 = tl1[hh];
    tv1 += __shfl_xor(tv1, 16, 64);
    tv1 += __shfl_xor(tv1, 32, 64);
    size_t bh = (size_t)(b*16 + h0 + hh);
#pragma unroll
    for (int part=0; part<4; ++part){
      size_t tix = ((size_t)(part*64) + bh)*2048 + (size_t)s*2;
      tv0 += tails[tix + 0];
      tv1 += tails[tix + 1];
    }
#pragma unroll
    for (int df=0; df<4; ++df)
#pragma unroll
      for (int r=0; r<4; ++r)
        o[hh][df][r] += acc2[hh][df][r] + tv0*rv0[df][r] + tv1*rv1[df][r];
  }

  __syncthreads();

  float* slabBase = (float*)skew;
  float (*tb)[68] = (float(*)[68])(slabBase + w*(16*68));
#pragma unroll
  for (int hh=0; hh<2; ++hh){
#pragma unroll
    for (int df=0; df<4; ++df)
      *(f4*)&tb[p][df*16 + 4*g] = o[hh][df];
    __syncthreads();
    const int srow = lane >> 2, quad = lane & 3;
    f4 r0 = *(const f4*)&tb[srow][quad*16 + 0];
    f4 r1 = *(const f4*)&tb[srow][quad*16 + 4];
    f4 r2 = *(const f4*)&tb[srow][quad*16 + 8];
    f4 r3 = *(const f4*)&tb[srow][quad*16 + 12];
    size_t addr = ((size_t)b*1024 + s0 + srow)*1024 + (h0+hh)*64 + quad*16;
    bfx8 pa, pb;
#pragma unroll
    for (int j=0; j<4; ++j){
      float a0 = r0[j], a1 = r1[j], a2 = r2[j], a3 = r3[j];
#pragma unroll
      for (int part=0; part<4; ++part){
        const unsigned short* pp = op + (size_t)part*4194304 + addr;
        bfx8 q0 = *(const bfx8*)pp;
        bfx8 q1 = *(const bfx8*)(pp + 8);
        a0 += bf2f((unsigned short)q0[j]);
        a1 += bf2f((unsigned short)q0[j+4]);
        a2 += bf2f((unsigned short)q1[j]);
        a3 += bf2f((unsigned short)q1[j+4]);
      }
      pa[j]   = (short)f2bf(a0);
      pa[j+4] = (short)f2bf(a1);
      pb[j]   = (short)f2bf(a2);
      pb[j+4] = (short)f2bf(a3);
    }
    *(bfx8*)(out1 + addr) = pa;
    *(bfx8*)(out1 + addr + 8) = pb;
    __syncthreads();
  }
}

// ---------------- final projection: 2-phase double-buffered staging ----------------
__global__ __launch_bounds__(256) void k_wo(
    const unsigned short* __restrict__ out1, const unsigned short* __restrict__ wo,
    const float* __restrict__ bo, float* __restrict__ dout)
{
  __shared__ __align__(16) unsigned short smem[2][6144];   // 2 x 12 KB: A blocks 0-3, B blocks 4-11
  const int nt = blockIdx.x;
  const int mt = blockIdx.y;
  const int w = threadIdx.x >> 6, lane = threadIdx.x & 63;
  const int wr = w >> 1, wc = w & 1;
  const int p = lane & 15, g = lane >> 4;
  const int m0 = mt*64, n0 = nt*128;
  const f4 fz = {0.f,0.f,0.f,0.f};
  f4 acc[2][4];
#pragma unroll
  for (int m=0;m<2;++m)
#pragma unroll
    for (int n=0;n<4;++n) acc[m][n] = fz;

  const int j0 = w*2, j1 = w*2 + 1;
  const unsigned short* gA = out1 + (size_t)(m0 + p)*1024 + g*8;
  const unsigned short* gB = wo   + (size_t)(n0 + p)*1024 + g*8;

  {
    unsigned short* d0 = &smem[0][0];
    gload16(gA + (size_t)w*16384, d0 + w*512);
    gload16(gB + (size_t)j0*16384, d0 + 2048 + j0*512);
    gload16(gB + (size_t)j1*16384, d0 + 2048 + j1*512);
  }
  __syncthreads();

  int cur = 0;
  for (int k0=0; k0<1024; k0+=32){
    const int kn = k0 + 32;
    if (kn < 1024){
      unsigned short* dn = &smem[cur^1][0];
      gload16(gA + (size_t)w*16384 + kn, dn + w*512);
      gload16(gB + (size_t)j0*16384 + kn, dn + 2048 + j0*512);
      gload16(gB + (size_t)j1*16384 + kn, dn + 2048 + j1*512);
    }
    const unsigned short* Ab = &smem[cur][0];
    bfx8 af[2], bfr[4];
#pragma unroll
    for (int m=0;m<2;++m) af[m] = *(const bfx8*)(Ab + (wr*2+m)*512 + lane*8);
#pragma unroll
    for (int n=0;n<4;++n) bfr[n] = *(const bfx8*)(Ab + 2048 + (wc*4+n)*512 + lane*8);
#pragma unroll
    for (int m=0;m<2;++m)
#pragma unroll
      for (int n=0;n<4;++n)
        acc[m][n] = mfma32(af[m], bfr[n], acc[m][n]);
    __syncthreads();
    cur ^= 1;
  }

#pragma unroll
  for (int n=0;n<4;++n){
    const int col = n0 + wc*64 + n*16 + p;
    const float bias = bo[col];
#pragma unroll
    for (int m=0;m<2;++m)
#pragma unroll
      for (int r=0;r<4;++r){
        int row = m0 + wr*32 + m*16 + 4*g + r;
        int bb = row >> 10, s = row & 1023;
        dout[((size_t)s*4 + bb)*1024 + col] = acc[m][n][r] + bias;
      }
  }
}

extern "C" void kernel_launch(void* const* d_in, const int* in_sizes, int n_in,
                              void* d_out, int out_size, void* d_ws, size_t ws_size,
                              hipStream_t stream){
  const float* x   = (const float*)d_in[0];
  const float* wq  = (const float*)d_in[1];
  const float* wk  = (const float*)d_in[2];
  const float* wv  = (const float*)d_in[3];
  const float* wo  = (const float*)d_in[4];
  const float* bo  = (const float*)d_in[5];
  const float* rlk = (const float*)d_in[6];
  const float* rlv = (const float*)d_in[7];
  char* ws = (char*)d_ws;

  unsigned short* x_bf    = (unsigned short*)(ws + 0);
  unsigned short* wq_bf   = (unsigned short*)(ws + 8388608);   // [wq|wk|wv|wo] contiguous
  unsigned short* relk_bf = (unsigned short*)(ws + 16777216);
  unsigned short* relvT_bf= (unsigned short*)(ws + 16812032);
  unsigned short* Qf      = (unsigned short*)(ws + 16848896);   // fragment layout
  unsigned short* Kf      = (unsigned short*)(ws + 25237504);   // fragment layout
  unsigned short* Vf      = (unsigned short*)(ws + 33626112);   // fragment layout
  unsigned short* Qr2     = (unsigned short*)(ws + 42014720);   // 35.65 MB -> 77666304
  float*          tails   = (float*)        (ws + 77666304);   // 2 MB -> 79763456
  unsigned short* op      = (unsigned short*)(ws + 79763456);   // 32 MB (4 parts) -> 113317888
  unsigned short* out1    = (unsigned short*)(ws + 113317888);  // 8 MB -> 121706496
  float*          ivf     = (float*)        (ws + 121706496);  // 16 MB -> 138483712
  unsigned short* wo_bf   = (unsigned short*)(ws + 14680064);

  k_cast<<<4096, 256, 0, stream>>>(x, x_bf, 1048576);
  k_castw<<<dim3(1024,4), 256, 0, stream>>>(wq, wk, wv, wo, wq_bf);
  k_relprep<<<72, 256, 0, stream>>>(rlk, rlv, relk_bf, relvT_bf);

  k_qkv<<<dim3(24,4,8), 256, 0, stream>>>(x_bf, wq_bf, Qf, Kf, Vf);
  k_qr<<<512, 256, 0, stream>>>(Qf, relk_bf, Qr2);

  k_s  <<<4096, 256, 0, stream>>>(Qf, Kf, Qr2, ivf);
  k_far<<<2048, 256, 0, stream>>>(Qf, Kf, Vf, Qr2, ivf, tails, op);
  k_near<<<256, 512, 0, stream>>>(Qf, Kf, Vf, Qr2, ivf, relvT_bf, rlv, tails, op, out1);
  k_wo<<<dim3(8,64), 256, 0, stream>>>(out1, wo_bf, bo, (float*)d_out);
}

// Round 11
// 251.849 us; speedup vs baseline: 3.1222x; 1.0576x over previous
//
#include <hip/hip_runtime.h>
#include <stdint.h>

#define DI __device__ __forceinline__

typedef __attribute__((ext_vector_type(8))) short bfx8;
typedef __attribute__((ext_vector_type(4))) short bfx4;
typedef __attribute__((ext_vector_type(4))) float f4;

DI unsigned short f2bf(float x){
  unsigned u = __float_as_uint(x);
  u = (u + 0x7FFFu + ((u >> 16) & 1u)) >> 16;
  return (unsigned short)u;
}
DI float bf2f(unsigned short h){ return __uint_as_float(((unsigned)h) << 16); }

DI f4 mfma32(bfx8 a, bfx8 b, f4 c){
  return __builtin_amdgcn_mfma_f32_16x16x32_bf16(a, b, c, 0, 0, 0);
}
#if __has_builtin(__builtin_amdgcn_mfma_f32_16x16x16bf16_1k)
DI f4 mfma16(bfx4 a, bfx4 b, f4 c){
  return __builtin_amdgcn_mfma_f32_16x16x16bf16_1k(a, b, c, 0, 0, 0);
}
#else
DI f4 mfma16(bfx4 a, bfx4 b, f4 c){
  f4 d = c;
  asm volatile("v_mfma_f32_16x16x16_bf16 %0, %1, %2, %0" : "+v"(d) : "v"(a), "v"(b));
  return d;
}
#endif

// async global->LDS, 16B per lane; LDS dest = wave-uniform base + lane*16
DI void gload16(const void* g, void* l){
  __builtin_amdgcn_global_load_lds(
      (__attribute__((address_space(1))) void*)g,
      (__attribute__((address_space(3))) void*)l, 16, 0, 0);
}

// Fragment layouts (all 16-bit elems):
//   Qf/Kf[bh][tile][lane][16]: elem[kf*8+j] = M[tile*16 + (lane&15)][kf*32 + 8*(lane>>4) + j]
//   Vf  [bh][tile][lane][16]: elem[df*4+j] = V[tile*16 + 4*(lane>>4) + j][df*16 + (lane&15)]
//   ivf [b][tt][st][lane][4]: elem[r] = 1/S at (s = st*16 + (lane&15), t = tt*16 + 4*(lane>>4) + r)

// ---------------- cast f32 -> bf16 (4-wide) ----------------
__global__ void k_cast(const float* __restrict__ src, unsigned short* __restrict__ dst, int n4){
  int i = blockIdx.x*256 + threadIdx.x;
  if (i < n4){
    const float4 v = ((const float4*)src)[i];
    bfx4 o;
    o[0] = (short)f2bf(v.x); o[1] = (short)f2bf(v.y);
    o[2] = (short)f2bf(v.z); o[3] = (short)f2bf(v.w);
    *(bfx4*)(dst + (size_t)i*4) = o;
  }
}

// merged weight cast: 4 matrices (1024x1024 f32) -> contiguous bf16 dsts
__global__ void k_castw(const float* __restrict__ s0, const float* __restrict__ s1,
                        const float* __restrict__ s2, const float* __restrict__ s3,
                        unsigned short* __restrict__ dst){
  int i = blockIdx.x*256 + threadIdx.x;      // < 262144
  const float* src = (blockIdx.y==0) ? s0 : (blockIdx.y==1) ? s1 : (blockIdx.y==2) ? s2 : s3;
  const float4 v = ((const float4*)src)[i];
  bfx4 o;
  o[0] = (short)f2bf(v.x); o[1] = (short)f2bf(v.y);
  o[2] = (short)f2bf(v.z); o[3] = (short)f2bf(v.w);
  *(bfx4*)(dst + (size_t)blockIdx.y*1048576 + (size_t)i*4) = o;
}

// relk_bf: [272][64] zero-padded rows; relvT_bf: [64][288] = rel_v^T zero-padded cols
__global__ void k_relprep(const float* __restrict__ rlk, const float* __restrict__ rlv,
                          unsigned short* __restrict__ relk_bf, unsigned short* __restrict__ relvT_bf){
  int i = blockIdx.x*256 + threadIdx.x;
  if (i < 272*64){
    int r = i >> 6, d = i & 63;
    relk_bf[i] = (r < 257) ? f2bf(rlk[r*64 + d]) : (unsigned short)0;
  }
  if (i < 64*288){
    int d = i / 288, r = i % 288;
    relvT_bf[i] = (r < 257) ? f2bf(rlv[(size_t)r*64 + d]) : (unsigned short)0;
  }
}

// ---------------- QKV projections: counted-vmcnt double-buffered pipeline ----------------
// stage(buf^1) -> vmcnt(4) [next 4 stay in flight] -> barrier -> compute(buf) -> barrier.
__global__ __launch_bounds__(256, 3) void k_qkv(
    const unsigned short* __restrict__ xbf, const unsigned short* __restrict__ wqkv,
    unsigned short* __restrict__ Qf, unsigned short* __restrict__ Kf,
    unsigned short* __restrict__ Vf)
{
  __shared__ __align__(16) unsigned short smem[2][8192];   // 2 x 16 KB: A blocks 0-7, B blocks 8-15
  const int nt = blockIdx.x;
  const int b  = blockIdx.y;
  const int st = blockIdx.z;
  const int w = threadIdx.x >> 6, lane = threadIdx.x & 63;
  const int wr = w >> 1, wc = w & 1;
  const int p = lane & 15, g = lane >> 4;
  const int s0 = st*128;
  const int n0 = nt*128;
  const f4 fz = {0.f,0.f,0.f,0.f};
  f4 acc[4][4];
#pragma unroll
  for (int m=0;m<4;++m)
#pragma unroll
    for (int n=0;n<4;++n) acc[m][n] = fz;

  const int j0 = w*2, j1 = w*2 + 1;
  const unsigned short* gA = xbf  + (size_t)((s0 + p)*4 + b)*1024 + g*8;
  const unsigned short* gB = wqkv + (size_t)(n0 + p)*1024 + g*8;

  // prologue: stage k=0 into buf 0 (4 loads/wave)
  {
    unsigned short* d0 = &smem[0][0];
    gload16(gA + (size_t)j0*65536, d0 + j0*512);
    gload16(gA + (size_t)j1*65536, d0 + j1*512);
    gload16(gB + (size_t)j0*16384, d0 + 4096 + j0*512);
    gload16(gB + (size_t)j1*16384, d0 + 4096 + j1*512);
  }

  for (int it=0; it<32; ++it){
    const int cur = it & 1;
    if (it < 31){
      const int kn = (it+1)*32;
      unsigned short* dn = &smem[cur^1][0];
      gload16(gA + (size_t)j0*65536 + kn, dn + j0*512);
      gload16(gA + (size_t)j1*65536 + kn, dn + j1*512);
      gload16(gB + (size_t)j0*16384 + kn, dn + 4096 + j0*512);
      gload16(gB + (size_t)j1*16384 + kn, dn + 4096 + j1*512);
      asm volatile("s_waitcnt vmcnt(4)" ::: "memory");   // cur's 4 loads done; next 4 in flight
    } else {
      asm volatile("s_waitcnt vmcnt(0)" ::: "memory");
    }
    __builtin_amdgcn_sched_barrier(0);
    __builtin_amdgcn_s_barrier();                        // all waves' cur buffer ready
    __builtin_amdgcn_sched_barrier(0);
    {
      const unsigned short* Ab = &smem[cur][0];
      bfx8 af[4], bfr[4];
#pragma unroll
      for (int m=0;m<4;++m) af[m] = *(const bfx8*)(Ab + (wr*4+m)*512 + lane*8);
#pragma unroll
      for (int n=0;n<4;++n) bfr[n] = *(const bfx8*)(Ab + 4096 + (wc*4+n)*512 + lane*8);
#pragma unroll
      for (int m=0;m<4;++m)
#pragma unroll
        for (int n=0;n<4;++n)
          acc[m][n] = mfma32(af[m], bfr[n], acc[m][n]);
    }
    __builtin_amdgcn_sched_barrier(0);
    __builtin_amdgcn_s_barrier();                        // all waves done reading cur
    __builtin_amdgcn_sched_barrier(0);
  }

  const int n64 = n0 + wc*64;
  const int sec = n64 >> 10;            // 0 Q, 1 K, 2 V
  const int h = (n64 & 1023) >> 6;
  float* es = (float*)&smem[0][0] + w*1280;   // alias tile LDS as per-wave epilogue slab

  if (sec < 2){
    const float scl = (sec == 0) ? 0.125f : 1.0f;
    unsigned short* dst = (sec == 0) ? Qf : Kf;
#pragma unroll
    for (int m=0;m<4;++m){
#pragma unroll
      for (int n=0;n<4;++n)
#pragma unroll
        for (int r=0;r<4;++r)
          es[(4*g + r)*80 + 16*n + p] = acc[m][n][r] * scl;
      __syncthreads();
      f4 v0 = *(const f4*)&es[p*80 + 8*g];
      f4 v1 = *(const f4*)&es[p*80 + 8*g + 4];
      f4 v2 = *(const f4*)&es[p*80 + 32 + 8*g];
      f4 v3 = *(const f4*)&es[p*80 + 32 + 8*g + 4];
      bfx8 lo, hi;
#pragma unroll
      for (int j=0;j<4;++j){
        lo[j]   = (short)f2bf(v0[j]);
        lo[j+4] = (short)f2bf(v1[j]);
        hi[j]   = (short)f2bf(v2[j]);
        hi[j+4] = (short)f2bf(v3[j]);
      }
      size_t fb = ((size_t)(b*16 + h)*64 + (st*8 + wr*4 + m))*1024 + (size_t)lane*16;
      *(bfx8*)(dst + fb) = lo;
      *(bfx8*)(dst + fb + 8) = hi;
      __syncthreads();
    }
  } else {
#pragma unroll
    for (int m=0;m<4;++m){
#pragma unroll
      for (int n=0;n<4;++n)
        *(f4*)&es[(16*n + p)*20 + 4*g] = acc[m][n];
      __syncthreads();
      f4 vv0 = *(const f4*)&es[(p)*20 + 4*g];
      f4 vv1 = *(const f4*)&es[(16 + p)*20 + 4*g];
      f4 vv2 = *(const f4*)&es[(32 + p)*20 + 4*g];
      f4 vv3 = *(const f4*)&es[(48 + p)*20 + 4*g];
      bfx8 lo, hi;
#pragma unroll
      for (int j=0;j<4;++j){
        lo[j]   = (short)f2bf(vv0[j]);
        lo[j+4] = (short)f2bf(vv1[j]);
        hi[j]   = (short)f2bf(vv2[j]);
        hi[j+4] = (short)f2bf(vv3[j]);
      }
      size_t fb = ((size_t)(b*16 + h)*64 + (st*8 + wr*4 + m))*1024 + (size_t)lane*16;
      *(bfx8*)(Vf + fb) = lo;
      *(bfx8*)(Vf + fb + 8) = hi;
      __syncthreads();
    }
  }
}

// ---------------- Qr2 producer, write-coalesced: all 16 heads per block ----------------
__global__ __launch_bounds__(256) void k_qr(
    const unsigned short* __restrict__ Qf, const unsigned short* __restrict__ relk,
    unsigned short* __restrict__ Qr2)
{
  __shared__ __align__(16) unsigned short sst[16][16][24];
  const int bx = blockIdx.x;
  const int b  = bx & 3;
  const int st = (bx >> 2) & 63;
  const int uh = bx >> 8;
  const int w = threadIdx.x >> 6, lane = threadIdx.x & 63;
  const int p = lane & 15, g = lane >> 4;
  const int s0 = st << 4;
  const f4 fz = {0.f,0.f,0.f,0.f};

  bfx8 a0[4], a1[4];
#pragma unroll
  for (int hh=0; hh<4; ++hh){
    size_t fb = (((size_t)(b*16 + w*4 + hh))*64 + st)*1024 + (size_t)lane*16;
    a0[hh] = *(const bfx8*)(Qf + fb);
    a1[hh] = *(const bfx8*)(Qf + fb + 8);
  }

  const int c0 = uh ? 9 : 0;
  const int c1 = uh ? 17 : 9;
  const int so = threadIdx.x >> 4, uo = threadIdx.x & 15;

  for (int c=c0; c<c1; ++c){
    const int r0 = c << 4;
    bfx8 b0 = *(const bfx8*)(relk + (size_t)(r0 + p)*64 + 8*g);
    bfx8 b1 = *(const bfx8*)(relk + (size_t)(r0 + p)*64 + 32 + 8*g);
#pragma unroll
    for (int hh=0; hh<4; ++hh){
      f4 acc = mfma32(a1[hh], b1, mfma32(a0[hh], b0, fz));
#pragma unroll
      for (int r=0; r<4; ++r)
        sst[4*g + r][p][w*4 + hh] = f2bf(acc[r]);
    }
    __syncthreads();
    bfx8 v0 = *(const bfx8*)&sst[so][uo][0];
    bfx8 v1 = *(const bfx8*)&sst[so][uo][8];
    size_t ga = (((size_t)b*1024 + s0 + so)*272 + r0 + uo)*16;
    *(bfx8*)(Qr2 + ga) = v0;
    *(bfx8*)(Qr2 + ga + 8) = v1;
    __syncthreads();
  }
}

// ---------------- softmax denominator -> ivf (fragment layout, coalesced) ----------------
__global__ __launch_bounds__(256, 3) void k_s(
    const unsigned short* __restrict__ Qf, const unsigned short* __restrict__ Kf,
    const unsigned short* __restrict__ Qr2, float* __restrict__ ivf)
{
  const int pbid = blockIdx.x;            // (st<<6)|(ttg<<2)|b
  const int b   = pbid & 3;
  const int ttg = (pbid >> 2) & 15;
  const int st  = pbid >> 6;
  const int w = threadIdx.x >> 6, lane = threadIdx.x & 63;
  const int tt = ttg*4 + w;
  const int p = lane & 15, g = lane >> 4;
  const int s0 = st << 4, t0 = tt << 4;
  const int s = s0 + p;
  const f4 fz = {0.f,0.f,0.f,0.f};

  bfx8 rv[4][2];
#pragma unroll
  for (int r=0; r<4; ++r){
    int t = t0 + 4*g + r;
    int u = s - t + 128; u = u < 0 ? 0 : (u > 256 ? 256 : u);
    const unsigned short* q = Qr2 + (((size_t)b*1024 + s)*272 + u)*16;
    rv[r][0] = *(const bfx8*)q;
    rv[r][1] = *(const bfx8*)(q + 8);
  }

  f4 ps = fz;
#pragma unroll
  for (int hg=0; hg<2; ++hg){
    f4 sc[8];
#pragma unroll
    for (int h8=0; h8<8; ++h8){
      size_t bh = (size_t)(b*16 + hg*8 + h8);
      size_t qb = (bh*64 + st)*1024 + (size_t)lane*16;
      size_t kb = (bh*64 + tt)*1024 + (size_t)lane*16;
      bfx8 q0 = *(const bfx8*)(Qf + qb);
      bfx8 q1 = *(const bfx8*)(Qf + qb + 8);
      bfx8 k0 = *(const bfx8*)(Kf + kb);
      bfx8 k1 = *(const bfx8*)(Kf + kb + 8);
      sc[h8] = mfma32(k1, q1, mfma32(k0, q0, fz));
    }
#pragma unroll
    for (int h8=0; h8<8; ++h8)
#pragma unroll
      for (int r=0; r<4; ++r)
        ps[r] += __expf(sc[h8][r] + bf2f((unsigned short)rv[r][hg][h8]));
  }

  f4 inv;
#pragma unroll
  for (int r=0; r<4; ++r) inv[r] = 1.0f / ps[r];
  *(f4*)(ivf + (((size_t)(b*64 + tt)*64 + st)*64 + lane)*4) = inv;
}

// ---------------- far attention: barrier-free, fragment loads, balanced strided far list ----------------
__global__ __launch_bounds__(256, 3) void k_far(
    const unsigned short* __restrict__ Qf, const unsigned short* __restrict__ Kf,
    const unsigned short* __restrict__ Vf, const unsigned short* __restrict__ Qr2,
    const float* __restrict__ ivf, float* __restrict__ tails,
    unsigned short* __restrict__ op)
{
  __shared__ __align__(16) float slab[4][16][68];
  const int pbid  = blockIdx.x;
  const int b     = pbid & 3;
  const int part  = (pbid >> 2) & 3;
  const int hhalf = (pbid >> 4) & 1;
  const int st    = pbid >> 5;
  const int s0 = st << 4;
  const int w = threadIdx.x >> 6, lane = threadIdx.x & 63;
  const int p = lane & 15, g = lane >> 4;
  const int s = s0 + p;
  const int h0 = hhalf*8 + w*2;
  const f4 fz = {0.f,0.f,0.f,0.f};

  bfx8 qf[2][2]; float qr0[2], qr1[2];
#pragma unroll
  for (int hh=0; hh<2; ++hh){
    size_t bh = (size_t)(b*16 + h0 + hh);
    size_t qb = (bh*64 + st)*1024 + (size_t)lane*16;
    qf[hh][0] = *(const bfx8*)(Qf + qb);
    qf[hh][1] = *(const bfx8*)(Qf + qb + 8);
    qr0[hh] = bf2f(Qr2[(((size_t)b*1024 + s)*272 + 0)*16 + (h0+hh)]);
    qr1[hh] = bf2f(Qr2[(((size_t)b*1024 + s)*272 + 256)*16 + (h0+hh)]);
  }

  f4 o[2][4];
#pragma unroll
  for (int hh=0; hh<2; ++hh)
#pragma unroll
    for (int df=0; df<4; ++df) o[hh][df] = fz;
  float tl0[2] = {0.f,0.f};
  float tl1[2] = {0.f,0.f};

  const int tlo = (st-8 < 0) ? 0 : st-8;
  const int thi = (st+8 > 63) ? 63 : st+8;
  const int nband = thi - tlo + 1;
  const int nfar = 64 - nband;

  bfx8 kc[2][2]; bfx4 vc[2][4]; f4 is;
  bfx8 kn[2][2]; bfx4 vn[2][4]; f4 isn;

  int idx = part;
  {
    const int ti = (idx < tlo) ? idx : idx + nband;
#pragma unroll
    for (int hh=0; hh<2; ++hh){
      size_t fb = (((size_t)(b*16 + h0 + hh))*64 + ti)*1024 + (size_t)lane*16;
      kc[hh][0] = *(const bfx8*)(Kf + fb);
      kc[hh][1] = *(const bfx8*)(Kf + fb + 8);
#pragma unroll
      for (int df=0; df<4; ++df)
        vc[hh][df] = *(const bfx4*)(Vf + fb + df*4);
    }
    is = *(const f4*)(ivf + (((size_t)(b*64 + ti)*64 + st)*64 + lane)*4);
  }

  while (idx < nfar){
    const int idn = idx + 4;
    if (idn < nfar){
      const int tn = (idn < tlo) ? idn : idn + nband;
#pragma unroll
      for (int hh=0; hh<2; ++hh){
        size_t fb = (((size_t)(b*16 + h0 + hh))*64 + tn)*1024 + (size_t)lane*16;
        kn[hh][0] = *(const bfx8*)(Kf + fb);
        kn[hh][1] = *(const bfx8*)(Kf + fb + 8);
#pragma unroll
        for (int df=0; df<4; ++df)
          vn[hh][df] = *(const bfx4*)(Vf + fb + df*4);
      }
      isn = *(const f4*)(ivf + (((size_t)(b*64 + tn)*64 + st)*64 + lane)*4);
    }

    const int ti = (idx < tlo) ? idx : idx + nband;
    const bool hiSide = (ti < st);
#pragma unroll
    for (int hh=0; hh<2; ++hh){
      f4 sc = mfma32(kc[hh][1], qf[hh][1], mfma32(kc[hh][0], qf[hh][0], fz));
      const float qa = hiSide ? qr1[hh] : qr0[hh];
      f4 at;
#pragma unroll
      for (int r=0; r<4; ++r) at[r] = __expf(sc[r] + qa) * is[r];
      float tsum = at[0] + at[1] + at[2] + at[3];
      if (hiSide) tl1[hh] += tsum; else tl0[hh] += tsum;
      bfx4 pk;
#pragma unroll
      for (int r=0; r<4; ++r) pk[r] = (short)f2bf(at[r]);
#pragma unroll
      for (int df=0; df<4; ++df)
        o[hh][df] = mfma16(vc[hh][df], pk, o[hh][df]);
    }

    if (idn < nfar){
#pragma unroll
      for (int hh=0; hh<2; ++hh){
        kc[hh][0] = kn[hh][0]; kc[hh][1] = kn[hh][1];
#pragma unroll
        for (int df=0; df<4; ++df) vc[hh][df] = vn[hh][df];
      }
      is = isn;
    }
    idx = idn;
  }

  // tail buckets for this part
#pragma unroll
  for (int hh=0; hh<2; ++hh){
    float v0 = tl0[hh];
    v0 += __shfl_xor(v0, 16, 64);
    v0 += __shfl_xor(v0, 32, 64);
    float v1 = tl1[hh];
    v1 += __shfl_xor(v1, 16, 64);
    v1 += __shfl_xor(v1, 32, 64);
    if (g == 0){
      size_t tix = ((size_t)(part*64 + b*16 + h0 + hh)*1024 + s)*2;
      tails[tix + 0] = v0;
      tails[tix + 1] = v1;
    }
  }

  // transpose epilogue -> bf16 partial output for this part
  unsigned short* dst = op + (size_t)part * 4194304;
#pragma unroll
  for (int hh=0; hh<2; ++hh){
    float (*tb)[68] = slab[w];
#pragma unroll
    for (int df=0; df<4; ++df)
      *(f4*)&tb[p][df*16 + 4*g] = o[hh][df];
    __syncthreads();
    const int srow = lane >> 2, quad = lane & 3;
    f4 r0 = *(const f4*)&tb[srow][quad*16 + 0];
    f4 r1 = *(const f4*)&tb[srow][quad*16 + 4];
    f4 r2 = *(const f4*)&tb[srow][quad*16 + 8];
    f4 r3 = *(const f4*)&tb[srow][quad*16 + 12];
    bfx8 pa, pb;
#pragma unroll
    for (int j=0; j<4; ++j){
      pa[j]   = (short)f2bf(r0[j]);
      pa[j+4] = (short)f2bf(r1[j]);
      pb[j]   = (short)f2bf(r2[j]);
      pb[j+4] = (short)f2bf(r3[j]);
    }
    size_t addr = ((size_t)b*1024 + s0 + srow)*1024 + (h0+hh)*64 + quad*16;
    *(bfx8*)(dst + addr) = pa;
    *(bfx8*)(dst + addr + 8) = pb;
    __syncthreads();
  }
}

// ---------------- near attention (17 tiles) + fused rel_v GEMM + final out1 ----------------
__global__ __launch_bounds__(512, 2) void k_near(
    const unsigned short* __restrict__ Qf, const unsigned short* __restrict__ Kf,
    const unsigned short* __restrict__ Vf, const unsigned short* __restrict__ Qr2,
    const float* __restrict__ ivf, const unsigned short* __restrict__ relvT,
    const float* __restrict__ relv, const float* __restrict__ tails,
    const unsigned short* __restrict__ op, unsigned short* __restrict__ out1)
{
  __shared__ __align__(16) unsigned short skew[256*264];
  const int pbid = blockIdx.x;
  const int xcd = pbid & 7;
  const int b = xcd >> 1;
  const int st = ((pbid >> 3) << 1) | (xcd & 1);
  const int s0 = st << 4;
  const int w = threadIdx.x >> 6;
  const int lane = threadIdx.x & 63;
  const int p = lane & 15, g = lane >> 4;
  const int s = s0 + p;
  const int h0 = w * 2;
  const f4 fz = {0.f,0.f,0.f,0.f};

  {
    unsigned* zp = (unsigned*)skew + w*4224;
    for (int i = lane; i < 4224; i += 64) zp[i] = 0u;
  }

  bfx8 qf[2][2];
#pragma unroll
  for (int hh=0; hh<2; ++hh){
    size_t qb = (((size_t)(b*16 + h0 + hh))*64 + st)*1024 + (size_t)lane*16;
    qf[hh][0] = *(const bfx8*)(Qf + qb);
    qf[hh][1] = *(const bfx8*)(Qf + qb + 8);
  }

  f4 o[2][4];
#pragma unroll
  for (int hh=0; hh<2; ++hh)
#pragma unroll
    for (int df=0; df<4; ++df) o[hh][df] = fz;

  float tl0[2] = {0.f,0.f};
  float tl1[2] = {0.f,0.f};

  const int tlo = (st-8 < 0) ? 0 : st-8;
  const int thi = (st+8 > 63) ? 63 : st+8;

  bfx8 kc[2][2]; bfx4 vc[2][4]; unsigned short qc[2][4]; f4 is;
  bfx8 kn[2][2]; bfx4 vn[2][4]; unsigned short qn[2][4]; f4 isn;

#pragma unroll
  for (int hh=0; hh<2; ++hh){
    size_t bh = (size_t)(b*16 + h0 + hh);
    size_t fb = (bh*64 + tlo)*1024 + (size_t)lane*16;
    kc[hh][0] = *(const bfx8*)(Kf + fb);
    kc[hh][1] = *(const bfx8*)(Kf + fb + 8);
#pragma unroll
    for (int df=0; df<4; ++df)
      vc[hh][df] = *(const bfx4*)(Vf + fb + df*4);
#pragma unroll
    for (int r=0; r<4; ++r){
      int t = (tlo<<4) + 4*g + r;
      int u = s - t + 128; u = u < 0 ? 0 : (u > 256 ? 256 : u);
      qc[hh][r] = Qr2[(((size_t)b*1024 + s)*272 + u)*16 + (h0+hh)];
    }
  }
  is = *(const f4*)(ivf + (((size_t)(b*64 + tlo)*64 + st)*64 + lane)*4);

  for (int ti = tlo; ti <= thi; ++ti){
    const int t0 = ti << 4;

    if (ti < thi){
      const int tn = ti + 1;
#pragma unroll
      for (int hh=0; hh<2; ++hh){
        size_t bh = (size_t)(b*16 + h0 + hh);
        size_t fb = (bh*64 + tn)*1024 + (size_t)lane*16;
        kn[hh][0] = *(const bfx8*)(Kf + fb);
        kn[hh][1] = *(const bfx8*)(Kf + fb + 8);
#pragma unroll
        for (int df=0; df<4; ++df)
          vn[hh][df] = *(const bfx4*)(Vf + fb + df*4);
#pragma unroll
        for (int r=0; r<4; ++r){
          int t = (tn<<4) + 4*g + r;
          int u = s - t + 128; u = u < 0 ? 0 : (u > 256 ? 256 : u);
          qn[hh][r] = Qr2[(((size_t)b*1024 + s)*272 + u)*16 + (h0+hh)];
        }
      }
      isn = *(const f4*)(ivf + (((size_t)(b*64 + tn)*64 + st)*64 + lane)*4);
    }

#pragma unroll
    for (int hh=0; hh<2; ++hh){
      f4 sc = mfma32(kc[hh][1], qf[hh][1], mfma32(kc[hh][0], qf[hh][0], fz));
      f4 at;
#pragma unroll
      for (int r=0; r<4; ++r) at[r] = __expf(sc[r] + bf2f(qc[hh][r])) * is[r];
      const int row = (h0 + hh)*16 + p;
#pragma unroll
      for (int r=0; r<4; ++r){
        int t = t0 + 4*g + r;
        int u = s - t + 128;
        float a = at[r];
        if (u <= 0) tl0[hh] += a;
        else if (u >= 256) tl1[hh] += a;
        else skew[row*264 + u] = f2bf(a);
      }
      bfx4 pk;
#pragma unroll
      for (int r=0; r<4; ++r) pk[r] = (short)f2bf(at[r]);
#pragma unroll
      for (int df=0; df<4; ++df)
        o[hh][df] = mfma16(vc[hh][df], pk, o[hh][df]);
    }

    if (ti < thi){
#pragma unroll
      for (int hh=0; hh<2; ++hh){
#pragma unroll
        for (int kf=0; kf<2; ++kf) kc[hh][kf] = kn[hh][kf];
#pragma unroll
        for (int df=0; df<4; ++df) vc[hh][df] = vn[hh][df];
#pragma unroll
        for (int r=0; r<4; ++r) qc[hh][r] = qn[hh][r];
      }
      is = isn;
    }
  }

  __syncthreads();

  // ---- fused out2 = rel_v^T @ skew (own-wave rows only) ----
  f4 acc2[2][4];
#pragma unroll
  for (int hh=0; hh<2; ++hh)
#pragma unroll
    for (int df=0; df<4; ++df) acc2[hh][df] = fz;
#pragma unroll
  for (int k0=0; k0<256; k0+=32){
    bfx8 bb0 = *(const bfx8*)&skew[(h0*16 + p)*264 + k0 + 8*g];
    bfx8 bb1 = *(const bfx8*)&skew[((h0+1)*16 + p)*264 + k0 + 8*g];
#pragma unroll
    for (int df=0; df<4; ++df){
      bfx8 a = *(const bfx8*)(relvT + (size_t)(df*16 + p)*288 + k0 + 8*g);
      acc2[0][df] = mfma32(a, bb0, acc2[0][df]);
      acc2[1][df] = mfma32(a, bb1, acc2[1][df]);
    }
  }

  f4 rv0[4], rv1[4];
#pragma unroll
  for (int df=0; df<4; ++df){
    rv0[df] = *(const f4*)(relv + df*16 + 4*g);
    rv1[df] = *(const f4*)(relv + 16384 + df*16 + 4*g);
  }
#pragma unroll
  for (int hh=0; hh<2; ++hh){
    float tv0 = tl0[hh];
    tv0 += __shfl_xor(tv0, 16, 64);
    tv0 += __shfl_xor(tv0, 32, 64);
    float tv1 = tl1[hh];
    tv1 += __shfl_xor(tv1, 16, 64);
    tv1 += __shfl_xor(tv1, 32, 64);
    size_t bh = (size_t)(b*16 + h0 + hh);
#pragma unroll
    for (int part=0; part<4; ++part){
      size_t tix = ((size_t)(part*64) + bh)*2048 + (size_t)s*2;
      tv0 += tails[tix + 0];
      tv1 += tails[tix + 1];
    }
#pragma unroll
    for (int df=0; df<4; ++df)
#pragma unroll
      for (int r=0; r<4; ++r)
        o[hh][df][r] += acc2[hh][df][r] + tv0*rv0[df][r] + tv1*rv1[df][r];
  }

  __syncthreads();

  float* slabBase = (float*)skew;
  float (*tb)[68] = (float(*)[68])(slabBase + w*(16*68));
#pragma unroll
  for (int hh=0; hh<2; ++hh){
#pragma unroll
    for (int df=0; df<4; ++df)
      *(f4*)&tb[p][df*16 + 4*g] = o[hh][df];
    __syncthreads();
    const int srow = lane >> 2, quad = lane & 3;
    f4 r0 = *(const f4*)&tb[srow][quad*16 + 0];
    f4 r1 = *(const f4*)&tb[srow][quad*16 + 4];
    f4 r2 = *(const f4*)&tb[srow][quad*16 + 8];
    f4 r3 = *(const f4*)&tb[srow][quad*16 + 12];
    size_t addr = ((size_t)b*1024 + s0 + srow)*1024 + (h0+hh)*64 + quad*16;
    bfx8 pa, pb;
#pragma unroll
    for (int j=0; j<4; ++j){
      float a0 = r0[j], a1 = r1[j], a2 = r2[j], a3 = r3[j];
#pragma unroll
      for (int part=0; part<4; ++part){
        const unsigned short* pp = op + (size_t)part*4194304 + addr;
        bfx8 q0 = *(const bfx8*)pp;
        bfx8 q1 = *(const bfx8*)(pp + 8);
        a0 += bf2f((unsigned short)q0[j]);
        a1 += bf2f((unsigned short)q0[j+4]);
        a2 += bf2f((unsigned short)q1[j]);
        a3 += bf2f((unsigned short)q1[j+4]);
      }
      pa[j]   = (short)f2bf(a0);
      pa[j+4] = (short)f2bf(a1);
      pb[j]   = (short)f2bf(a2);
      pb[j+4] = (short)f2bf(a3);
    }
    *(bfx8*)(out1 + addr) = pa;
    *(bfx8*)(out1 + addr + 8) = pb;
    __syncthreads();
  }
}

// ---------------- final projection: counted-vmcnt double-buffered pipeline ----------------
__global__ __launch_bounds__(256) void k_wo(
    const unsigned short* __restrict__ out1, const unsigned short* __restrict__ wo,
    const float* __restrict__ bo, float* __restrict__ dout)
{
  __shared__ __align__(16) unsigned short smem[2][6144];   // 2 x 12 KB: A blocks 0-3, B blocks 4-11
  const int nt = blockIdx.x;
  const int mt = blockIdx.y;
  const int w = threadIdx.x >> 6, lane = threadIdx.x & 63;
  const int wr = w >> 1, wc = w & 1;
  const int p = lane & 15, g = lane >> 4;
  const int m0 = mt*64, n0 = nt*128;
  const f4 fz = {0.f,0.f,0.f,0.f};
  f4 acc[2][4];
#pragma unroll
  for (int m=0;m<2;++m)
#pragma unroll
    for (int n=0;n<4;++n) acc[m][n] = fz;

  const int j0 = w*2, j1 = w*2 + 1;
  const unsigned short* gA = out1 + (size_t)(m0 + p)*1024 + g*8;
  const unsigned short* gB = wo   + (size_t)(n0 + p)*1024 + g*8;

  {
    unsigned short* d0 = &smem[0][0];
    gload16(gA + (size_t)w*16384, d0 + w*512);
    gload16(gB + (size_t)j0*16384, d0 + 2048 + j0*512);
    gload16(gB + (size_t)j1*16384, d0 + 2048 + j1*512);
  }

  for (int it=0; it<32; ++it){
    const int cur = it & 1;
    if (it < 31){
      const int kn = (it+1)*32;
      unsigned short* dn = &smem[cur^1][0];
      gload16(gA + (size_t)w*16384 + kn, dn + w*512);
      gload16(gB + (size_t)j0*16384 + kn, dn + 2048 + j0*512);
      gload16(gB + (size_t)j1*16384 + kn, dn + 2048 + j1*512);
      asm volatile("s_waitcnt vmcnt(3)" ::: "memory");
    } else {
      asm volatile("s_waitcnt vmcnt(0)" ::: "memory");
    }
    __builtin_amdgcn_sched_barrier(0);
    __builtin_amdgcn_s_barrier();
    __builtin_amdgcn_sched_barrier(0);
    {
      const unsigned short* Ab = &smem[cur][0];
      bfx8 af[2], bfr[4];
#pragma unroll
      for (int m=0;m<2;++m) af[m] = *(const bfx8*)(Ab + (wr*2+m)*512 + lane*8);
#pragma unroll
      for (int n=0;n<4;++n) bfr[n] = *(const bfx8*)(Ab + 2048 + (wc*4+n)*512 + lane*8);
#pragma unroll
      for (int m=0;m<2;++m)
#pragma unroll
        for (int n=0;n<4;++n)
          acc[m][n] = mfma32(af[m], bfr[n], acc[m][n]);
    }
    __builtin_amdgcn_sched_barrier(0);
    __builtin_amdgcn_s_barrier();
    __builtin_amdgcn_sched_barrier(0);
  }

#pragma unroll
  for (int n=0;n<4;++n){
    const int col = n0 + wc*64 + n*16 + p;
    const float bias = bo[col];
#pragma unroll
    for (int m=0;m<2;++m)
#pragma unroll
      for (int r=0;r<4;++r){
        int row = m0 + wr*32 + m*16 + 4*g + r;
        int bb = row >> 10, s = row & 1023;
        dout[((size_t)s*4 + bb)*1024 + col] = acc[m][n][r] + bias;
      }
  }
}

extern "C" void kernel_launch(void* const* d_in, const int* in_sizes, int n_in,
                              void* d_out, int out_size, void* d_ws, size_t ws_size,
                              hipStream_t stream){
  const float* x   = (const float*)d_in[0];
  const float* wq  = (const float*)d_in[1];
  const float* wk  = (const float*)d_in[2];
  const float* wv  = (const float*)d_in[3];
  const float* wo  = (const float*)d_in[4];
  const float* bo  = (const float*)d_in[5];
  const float* rlk = (const float*)d_in[6];
  const float* rlv = (const float*)d_in[7];
  char* ws = (char*)d_ws;

  unsigned short* x_bf    = (unsigned short*)(ws + 0);
  unsigned short* wq_bf   = (unsigned short*)(ws + 8388608);   // [wq|wk|wv|wo] contiguous
  unsigned short* relk_bf = (unsigned short*)(ws + 16777216);
  unsigned short* relvT_bf= (unsigned short*)(ws + 16812032);
  unsigned short* Qf      = (unsigned short*)(ws + 16848896);   // fragment layout
  unsigned short* Kf      = (unsigned short*)(ws + 25237504);   // fragment layout
  unsigned short* Vf      = (unsigned short*)(ws + 33626112);   // fragment layout
  unsigned short* Qr2     = (unsigned short*)(ws + 42014720);   // 35.65 MB -> 77666304
  float*          tails   = (float*)        (ws + 77666304);   // 2 MB -> 79763456
  unsigned short* op      = (unsigned short*)(ws + 79763456);   // 32 MB (4 parts) -> 113317888
  unsigned short* out1    = (unsigned short*)(ws + 113317888);  // 8 MB -> 121706496
  float*          ivf     = (float*)        (ws + 121706496);  // 16 MB -> 138483712
  unsigned short* wo_bf   = (unsigned short*)(ws + 14680064);

  k_cast<<<4096, 256, 0, stream>>>(x, x_bf, 1048576);
  k_castw<<<dim3(1024,4), 256, 0, stream>>>(wq, wk, wv, wo, wq_bf);
  k_relprep<<<72, 256, 0, stream>>>(rlk, rlv, relk_bf, relvT_bf);

  k_qkv<<<dim3(24,4,8), 256, 0, stream>>>(x_bf, wq_bf, Qf, Kf, Vf);
  k_qr<<<512, 256, 0, stream>>>(Qf, relk_bf, Qr2);

  k_s  <<<4096, 256, 0, stream>>>(Qf, Kf, Qr2, ivf);
  k_far<<<2048, 256, 0, stream>>>(Qf, Kf, Vf, Qr2, ivf, tails, op);
  k_near<<<256, 512, 0, stream>>>(Qf, Kf, Vf, Qr2, ivf, relvT_bf, rlv, tails, op, out1);
  k_wo<<<dim3(8,64), 256, 0, stream>>>(out1, wo_bf, bo, (float*)d_out);
}

// Round 12
// 248.082 us; speedup vs baseline: 3.1696x; 1.0152x over previous
//
#include <hip/hip_runtime.h>
#include <stdint.h>

#define DI __device__ __forceinline__

typedef __attribute__((ext_vector_type(8))) short bfx8;
typedef __attribute__((ext_vector_type(4))) short bfx4;
typedef __attribute__((ext_vector_type(4))) float f4;

DI unsigned short f2bf(float x){
  unsigned u = __float_as_uint(x);
  u = (u + 0x7FFFu + ((u >> 16) & 1u)) >> 16;
  return (unsigned short)u;
}
DI float bf2f(unsigned short h){ return __uint_as_float(((unsigned)h) << 16); }

DI f4 mfma32(bfx8 a, bfx8 b, f4 c){
  return __builtin_amdgcn_mfma_f32_16x16x32_bf16(a, b, c, 0, 0, 0);
}
#if __has_builtin(__builtin_amdgcn_mfma_f32_16x16x16bf16_1k)
DI f4 mfma16(bfx4 a, bfx4 b, f4 c){
  return __builtin_amdgcn_mfma_f32_16x16x16bf16_1k(a, b, c, 0, 0, 0);
}
#else
DI f4 mfma16(bfx4 a, bfx4 b, f4 c){
  f4 d = c;
  asm volatile("v_mfma_f32_16x16x16_bf16 %0, %1, %2, %0" : "+v"(d) : "v"(a), "v"(b));
  return d;
}
#endif

// async global->LDS, 16B per lane; LDS dest = wave-uniform base + lane*16
DI void gload16(const void* g, void* l){
  __builtin_amdgcn_global_load_lds(
      (__attribute__((address_space(1))) void*)g,
      (__attribute__((address_space(3))) void*)l, 16, 0, 0);
}

// Fragment layouts (all 16-bit elems):
//   Qf/Kf[bh][tile][lane][16]: elem[kf*8+j] = M[tile*16 + (lane&15)][kf*32 + 8*(lane>>4) + j]
//   Vf  [bh][tile][lane][16]: elem[df*4+j] = V[tile*16 + 4*(lane>>4) + j][df*16 + (lane&15)]
//   ivf [b][tt][st][lane][4]: elem[r] = 1/S at (s = st*16 + (lane&15), t = tt*16 + 4*(lane>>4) + r)

// ---------------- cast f32 -> bf16 (4-wide) ----------------
__global__ void k_cast(const float* __restrict__ src, unsigned short* __restrict__ dst, int n4){
  int i = blockIdx.x*256 + threadIdx.x;
  if (i < n4){
    const float4 v = ((const float4*)src)[i];
    bfx4 o;
    o[0] = (short)f2bf(v.x); o[1] = (short)f2bf(v.y);
    o[2] = (short)f2bf(v.z); o[3] = (short)f2bf(v.w);
    *(bfx4*)(dst + (size_t)i*4) = o;
  }
}

// merged weight cast: 4 matrices (1024x1024 f32) -> contiguous bf16 dsts
__global__ void k_castw(const float* __restrict__ s0, const float* __restrict__ s1,
                        const float* __restrict__ s2, const float* __restrict__ s3,
                        unsigned short* __restrict__ dst){
  int i = blockIdx.x*256 + threadIdx.x;      // < 262144
  const float* src = (blockIdx.y==0) ? s0 : (blockIdx.y==1) ? s1 : (blockIdx.y==2) ? s2 : s3;
  const float4 v = ((const float4*)src)[i];
  bfx4 o;
  o[0] = (short)f2bf(v.x); o[1] = (short)f2bf(v.y);
  o[2] = (short)f2bf(v.z); o[3] = (short)f2bf(v.w);
  *(bfx4*)(dst + (size_t)blockIdx.y*1048576 + (size_t)i*4) = o;
}

// relk_bf: [272][64] zero-padded rows; relvT_bf: [64][288] = rel_v^T zero-padded cols
__global__ void k_relprep(const float* __restrict__ rlk, const float* __restrict__ rlv,
                          unsigned short* __restrict__ relk_bf, unsigned short* __restrict__ relvT_bf){
  int i = blockIdx.x*256 + threadIdx.x;
  if (i < 272*64){
    int r = i >> 6, d = i & 63;
    relk_bf[i] = (r < 257) ? f2bf(rlk[r*64 + d]) : (unsigned short)0;
  }
  if (i < 64*288){
    int d = i / 288, r = i % 288;
    relvT_bf[i] = (r < 257) ? f2bf(rlv[(size_t)r*64 + d]) : (unsigned short)0;
  }
}

// ---------------- QKV projections: counted-vmcnt double-buffered pipeline ----------------
__global__ __launch_bounds__(256, 3) void k_qkv(
    const unsigned short* __restrict__ xbf, const unsigned short* __restrict__ wqkv,
    unsigned short* __restrict__ Qf, unsigned short* __restrict__ Kf,
    unsigned short* __restrict__ Vf)
{
  __shared__ __align__(16) unsigned short smem[2][8192];   // 2 x 16 KB: A blocks 0-7, B blocks 8-15
  const int nt = blockIdx.x;
  const int b  = blockIdx.y;
  const int st = blockIdx.z;
  const int w = threadIdx.x >> 6, lane = threadIdx.x & 63;
  const int wr = w >> 1, wc = w & 1;
  const int p = lane & 15, g = lane >> 4;
  const int s0 = st*128;
  const int n0 = nt*128;
  const f4 fz = {0.f,0.f,0.f,0.f};
  f4 acc[4][4];
#pragma unroll
  for (int m=0;m<4;++m)
#pragma unroll
    for (int n=0;n<4;++n) acc[m][n] = fz;

  const int j0 = w*2, j1 = w*2 + 1;
  const unsigned short* gA = xbf  + (size_t)((s0 + p)*4 + b)*1024 + g*8;
  const unsigned short* gB = wqkv + (size_t)(n0 + p)*1024 + g*8;

  {
    unsigned short* d0 = &smem[0][0];
    gload16(gA + (size_t)j0*65536, d0 + j0*512);
    gload16(gA + (size_t)j1*65536, d0 + j1*512);
    gload16(gB + (size_t)j0*16384, d0 + 4096 + j0*512);
    gload16(gB + (size_t)j1*16384, d0 + 4096 + j1*512);
  }

  for (int it=0; it<32; ++it){
    const int cur = it & 1;
    if (it < 31){
      const int kn = (it+1)*32;
      unsigned short* dn = &smem[cur^1][0];
      gload16(gA + (size_t)j0*65536 + kn, dn + j0*512);
      gload16(gA + (size_t)j1*65536 + kn, dn + j1*512);
      gload16(gB + (size_t)j0*16384 + kn, dn + 4096 + j0*512);
      gload16(gB + (size_t)j1*16384 + kn, dn + 4096 + j1*512);
      asm volatile("s_waitcnt vmcnt(4)" ::: "memory");
    } else {
      asm volatile("s_waitcnt vmcnt(0)" ::: "memory");
    }
    __builtin_amdgcn_sched_barrier(0);
    __builtin_amdgcn_s_barrier();
    __builtin_amdgcn_sched_barrier(0);
    {
      const unsigned short* Ab = &smem[cur][0];
      bfx8 af[4], bfr[4];
#pragma unroll
      for (int m=0;m<4;++m) af[m] = *(const bfx8*)(Ab + (wr*4+m)*512 + lane*8);
#pragma unroll
      for (int n=0;n<4;++n) bfr[n] = *(const bfx8*)(Ab + 4096 + (wc*4+n)*512 + lane*8);
#pragma unroll
      for (int m=0;m<4;++m)
#pragma unroll
        for (int n=0;n<4;++n)
          acc[m][n] = mfma32(af[m], bfr[n], acc[m][n]);
    }
    __builtin_amdgcn_sched_barrier(0);
    __builtin_amdgcn_s_barrier();
    __builtin_amdgcn_sched_barrier(0);
  }

  const int n64 = n0 + wc*64;
  const int sec = n64 >> 10;            // 0 Q, 1 K, 2 V
  const int h = (n64 & 1023) >> 6;
  float* es = (float*)&smem[0][0] + w*1280;

  if (sec < 2){
    const float scl = (sec == 0) ? 0.125f : 1.0f;
    unsigned short* dst = (sec == 0) ? Qf : Kf;
#pragma unroll
    for (int m=0;m<4;++m){
#pragma unroll
      for (int n=0;n<4;++n)
#pragma unroll
        for (int r=0;r<4;++r)
          es[(4*g + r)*80 + 16*n + p] = acc[m][n][r] * scl;
      __syncthreads();
      f4 v0 = *(const f4*)&es[p*80 + 8*g];
      f4 v1 = *(const f4*)&es[p*80 + 8*g + 4];
      f4 v2 = *(const f4*)&es[p*80 + 32 + 8*g];
      f4 v3 = *(const f4*)&es[p*80 + 32 + 8*g + 4];
      bfx8 lo, hi;
#pragma unroll
      for (int j=0;j<4;++j){
        lo[j]   = (short)f2bf(v0[j]);
        lo[j+4] = (short)f2bf(v1[j]);
        hi[j]   = (short)f2bf(v2[j]);
        hi[j+4] = (short)f2bf(v3[j]);
      }
      size_t fb = ((size_t)(b*16 + h)*64 + (st*8 + wr*4 + m))*1024 + (size_t)lane*16;
      *(bfx8*)(dst + fb) = lo;
      *(bfx8*)(dst + fb + 8) = hi;
      __syncthreads();
    }
  } else {
#pragma unroll
    for (int m=0;m<4;++m){
#pragma unroll
      for (int n=0;n<4;++n)
        *(f4*)&es[(16*n + p)*20 + 4*g] = acc[m][n];
      __syncthreads();
      f4 vv0 = *(const f4*)&es[(p)*20 + 4*g];
      f4 vv1 = *(const f4*)&es[(16 + p)*20 + 4*g];
      f4 vv2 = *(const f4*)&es[(32 + p)*20 + 4*g];
      f4 vv3 = *(const f4*)&es[(48 + p)*20 + 4*g];
      bfx8 lo, hi;
#pragma unroll
      for (int j=0;j<4;++j){
        lo[j]   = (short)f2bf(vv0[j]);
        lo[j+4] = (short)f2bf(vv1[j]);
        hi[j]   = (short)f2bf(vv2[j]);
        hi[j+4] = (short)f2bf(vv3[j]);
      }
      size_t fb = ((size_t)(b*16 + h)*64 + (st*8 + wr*4 + m))*1024 + (size_t)lane*16;
      *(bfx8*)(Vf + fb) = lo;
      *(bfx8*)(Vf + fb + 8) = hi;
      __syncthreads();
    }
  }
}

// ---------------- Qr2 producer, write-coalesced: all 16 heads per block ----------------
__global__ __launch_bounds__(256) void k_qr(
    const unsigned short* __restrict__ Qf, const unsigned short* __restrict__ relk,
    unsigned short* __restrict__ Qr2)
{
  __shared__ __align__(16) unsigned short sst[16][16][24];
  const int bx = blockIdx.x;
  const int b  = bx & 3;
  const int st = (bx >> 2) & 63;
  const int uh = bx >> 8;
  const int w = threadIdx.x >> 6, lane = threadIdx.x & 63;
  const int p = lane & 15, g = lane >> 4;
  const int s0 = st << 4;
  const f4 fz = {0.f,0.f,0.f,0.f};

  bfx8 a0[4], a1[4];
#pragma unroll
  for (int hh=0; hh<4; ++hh){
    size_t fb = (((size_t)(b*16 + w*4 + hh))*64 + st)*1024 + (size_t)lane*16;
    a0[hh] = *(const bfx8*)(Qf + fb);
    a1[hh] = *(const bfx8*)(Qf + fb + 8);
  }

  const int c0 = uh ? 9 : 0;
  const int c1 = uh ? 17 : 9;
  const int so = threadIdx.x >> 4, uo = threadIdx.x & 15;

  for (int c=c0; c<c1; ++c){
    const int r0 = c << 4;
    bfx8 b0 = *(const bfx8*)(relk + (size_t)(r0 + p)*64 + 8*g);
    bfx8 b1 = *(const bfx8*)(relk + (size_t)(r0 + p)*64 + 32 + 8*g);
#pragma unroll
    for (int hh=0; hh<4; ++hh){
      f4 acc = mfma32(a1[hh], b1, mfma32(a0[hh], b0, fz));
#pragma unroll
      for (int r=0; r<4; ++r)
        sst[4*g + r][p][w*4 + hh] = f2bf(acc[r]);
    }
    __syncthreads();
    bfx8 v0 = *(const bfx8*)&sst[so][uo][0];
    bfx8 v1 = *(const bfx8*)&sst[so][uo][8];
    size_t ga = (((size_t)b*1024 + s0 + so)*272 + r0 + uo)*16;
    *(bfx8*)(Qr2 + ga) = v0;
    *(bfx8*)(Qr2 + ga + 8) = v1;
    __syncthreads();
  }
}

// ---------------- softmax denominator -> ivf (fragment layout, coalesced) ----------------
__global__ __launch_bounds__(256, 3) void k_s(
    const unsigned short* __restrict__ Qf, const unsigned short* __restrict__ Kf,
    const unsigned short* __restrict__ Qr2, float* __restrict__ ivf)
{
  const int pbid = blockIdx.x;            // (st<<6)|(ttg<<2)|b
  const int b   = pbid & 3;
  const int ttg = (pbid >> 2) & 15;
  const int st  = pbid >> 6;
  const int w = threadIdx.x >> 6, lane = threadIdx.x & 63;
  const int tt = ttg*4 + w;
  const int p = lane & 15, g = lane >> 4;
  const int s0 = st << 4, t0 = tt << 4;
  const int s = s0 + p;
  const f4 fz = {0.f,0.f,0.f,0.f};

  bfx8 rv[4][2];
#pragma unroll
  for (int r=0; r<4; ++r){
    int t = t0 + 4*g + r;
    int u = s - t + 128; u = u < 0 ? 0 : (u > 256 ? 256 : u);
    const unsigned short* q = Qr2 + (((size_t)b*1024 + s)*272 + u)*16;
    rv[r][0] = *(const bfx8*)q;
    rv[r][1] = *(const bfx8*)(q + 8);
  }

  f4 ps = fz;
#pragma unroll
  for (int hg=0; hg<2; ++hg){
    f4 sc[8];
#pragma unroll
    for (int h8=0; h8<8; ++h8){
      size_t bh = (size_t)(b*16 + hg*8 + h8);
      size_t qb = (bh*64 + st)*1024 + (size_t)lane*16;
      size_t kb = (bh*64 + tt)*1024 + (size_t)lane*16;
      bfx8 q0 = *(const bfx8*)(Qf + qb);
      bfx8 q1 = *(const bfx8*)(Qf + qb + 8);
      bfx8 k0 = *(const bfx8*)(Kf + kb);
      bfx8 k1 = *(const bfx8*)(Kf + kb + 8);
      sc[h8] = mfma32(k1, q1, mfma32(k0, q0, fz));
    }
#pragma unroll
    for (int h8=0; h8<8; ++h8)
#pragma unroll
      for (int r=0; r<4; ++r)
        ps[r] += __expf(sc[h8][r] + bf2f((unsigned short)rv[r][hg][h8]));
  }

  f4 inv;
#pragma unroll
  for (int r=0; r<4; ++r) inv[r] = 1.0f / ps[r];
  *(f4*)(ivf + (((size_t)(b*64 + tt)*64 + st)*64 + lane)*4) = inv;
}

// ---------------- far attention: barrier-free, fragment loads, balanced strided far list ----------------
__global__ __launch_bounds__(256, 3) void k_far(
    const unsigned short* __restrict__ Qf, const unsigned short* __restrict__ Kf,
    const unsigned short* __restrict__ Vf, const unsigned short* __restrict__ Qr2,
    const float* __restrict__ ivf, float* __restrict__ tails,
    unsigned short* __restrict__ op)
{
  __shared__ __align__(16) float slab[4][16][68];
  const int pbid  = blockIdx.x;
  const int b     = pbid & 3;
  const int part  = (pbid >> 2) & 3;
  const int hhalf = (pbid >> 4) & 1;
  const int st    = pbid >> 5;
  const int s0 = st << 4;
  const int w = threadIdx.x >> 6, lane = threadIdx.x & 63;
  const int p = lane & 15, g = lane >> 4;
  const int s = s0 + p;
  const int h0 = hhalf*8 + w*2;
  const f4 fz = {0.f,0.f,0.f,0.f};

  bfx8 qf[2][2]; float qr0[2], qr1[2];
#pragma unroll
  for (int hh=0; hh<2; ++hh){
    size_t bh = (size_t)(b*16 + h0 + hh);
    size_t qb = (bh*64 + st)*1024 + (size_t)lane*16;
    qf[hh][0] = *(const bfx8*)(Qf + qb);
    qf[hh][1] = *(const bfx8*)(Qf + qb + 8);
    qr0[hh] = bf2f(Qr2[(((size_t)b*1024 + s)*272 + 0)*16 + (h0+hh)]);
    qr1[hh] = bf2f(Qr2[(((size_t)b*1024 + s)*272 + 256)*16 + (h0+hh)]);
  }

  f4 o[2][4];
#pragma unroll
  for (int hh=0; hh<2; ++hh)
#pragma unroll
    for (int df=0; df<4; ++df) o[hh][df] = fz;
  float tl0[2] = {0.f,0.f};
  float tl1[2] = {0.f,0.f};

  const int tlo = (st-8 < 0) ? 0 : st-8;
  const int thi = (st+8 > 63) ? 63 : st+8;
  const int nband = thi - tlo + 1;
  const int nfar = 64 - nband;

  bfx8 kc[2][2]; bfx4 vc[2][4]; f4 is;
  bfx8 kn[2][2]; bfx4 vn[2][4]; f4 isn;

  int idx = part;
  {
    const int ti = (idx < tlo) ? idx : idx + nband;
#pragma unroll
    for (int hh=0; hh<2; ++hh){
      size_t fb = (((size_t)(b*16 + h0 + hh))*64 + ti)*1024 + (size_t)lane*16;
      kc[hh][0] = *(const bfx8*)(Kf + fb);
      kc[hh][1] = *(const bfx8*)(Kf + fb + 8);
#pragma unroll
      for (int df=0; df<4; ++df)
        vc[hh][df] = *(const bfx4*)(Vf + fb + df*4);
    }
    is = *(const f4*)(ivf + (((size_t)(b*64 + ti)*64 + st)*64 + lane)*4);
  }

  while (idx < nfar){
    const int idn = idx + 4;
    if (idn < nfar){
      const int tn = (idn < tlo) ? idn : idn + nband;
#pragma unroll
      for (int hh=0; hh<2; ++hh){
        size_t fb = (((size_t)(b*16 + h0 + hh))*64 + tn)*1024 + (size_t)lane*16;
        kn[hh][0] = *(const bfx8*)(Kf + fb);
        kn[hh][1] = *(const bfx8*)(Kf + fb + 8);
#pragma unroll
        for (int df=0; df<4; ++df)
          vn[hh][df] = *(const bfx4*)(Vf + fb + df*4);
      }
      isn = *(const f4*)(ivf + (((size_t)(b*64 + tn)*64 + st)*64 + lane)*4);
    }

    const int ti = (idx < tlo) ? idx : idx + nband;
    const bool hiSide = (ti < st);
#pragma unroll
    for (int hh=0; hh<2; ++hh){
      f4 sc = mfma32(kc[hh][1], qf[hh][1], mfma32(kc[hh][0], qf[hh][0], fz));
      const float qa = hiSide ? qr1[hh] : qr0[hh];
      f4 at;
#pragma unroll
      for (int r=0; r<4; ++r) at[r] = __expf(sc[r] + qa) * is[r];
      float tsum = at[0] + at[1] + at[2] + at[3];
      if (hiSide) tl1[hh] += tsum; else tl0[hh] += tsum;
      bfx4 pk;
#pragma unroll
      for (int r=0; r<4; ++r) pk[r] = (short)f2bf(at[r]);
#pragma unroll
      for (int df=0; df<4; ++df)
        o[hh][df] = mfma16(vc[hh][df], pk, o[hh][df]);
    }

    if (idn < nfar){
#pragma unroll
      for (int hh=0; hh<2; ++hh){
        kc[hh][0] = kn[hh][0]; kc[hh][1] = kn[hh][1];
#pragma unroll
        for (int df=0; df<4; ++df) vc[hh][df] = vn[hh][df];
      }
      is = isn;
    }
    idx = idn;
  }

  // tail buckets for this part
#pragma unroll
  for (int hh=0; hh<2; ++hh){
    float v0 = tl0[hh];
    v0 += __shfl_xor(v0, 16, 64);
    v0 += __shfl_xor(v0, 32, 64);
    float v1 = tl1[hh];
    v1 += __shfl_xor(v1, 16, 64);
    v1 += __shfl_xor(v1, 32, 64);
    if (g == 0){
      size_t tix = ((size_t)(part*64 + b*16 + h0 + hh)*1024 + s)*2;
      tails[tix + 0] = v0;
      tails[tix + 1] = v1;
    }
  }

  // transpose epilogue -> bf16 partial output for this part
  unsigned short* dst = op + (size_t)part * 4194304;
#pragma unroll
  for (int hh=0; hh<2; ++hh){
    float (*tb)[68] = slab[w];
#pragma unroll
    for (int df=0; df<4; ++df)
      *(f4*)&tb[p][df*16 + 4*g] = o[hh][df];
    __syncthreads();
    const int srow = lane >> 2, quad = lane & 3;
    f4 r0 = *(const f4*)&tb[srow][quad*16 + 0];
    f4 r1 = *(const f4*)&tb[srow][quad*16 + 4];
    f4 r2 = *(const f4*)&tb[srow][quad*16 + 8];
    f4 r3 = *(const f4*)&tb[srow][quad*16 + 12];
    bfx8 pa, pb;
#pragma unroll
    for (int j=0; j<4; ++j){
      pa[j]   = (short)f2bf(r0[j]);
      pa[j+4] = (short)f2bf(r1[j]);
      pb[j]   = (short)f2bf(r2[j]);
      pb[j+4] = (short)f2bf(r3[j]);
    }
    size_t addr = ((size_t)b*1024 + s0 + srow)*1024 + (h0+hh)*64 + quad*16;
    *(bfx8*)(dst + addr) = pa;
    *(bfx8*)(dst + addr + 8) = pb;
    __syncthreads();
  }
}

// ---------------- near attention, head-split: (b, st, hhalf); 4 waves x 2 heads ----------------
// skew [128][264] = 67.6 KB -> 2 blocks/CU. Local head hl for LDS; global h0 for memory.
__global__ __launch_bounds__(256, 2) void k_near(
    const unsigned short* __restrict__ Qf, const unsigned short* __restrict__ Kf,
    const unsigned short* __restrict__ Vf, const unsigned short* __restrict__ Qr2,
    const float* __restrict__ ivf, const unsigned short* __restrict__ relvT,
    const float* __restrict__ relv, const float* __restrict__ tails,
    const unsigned short* __restrict__ op, unsigned short* __restrict__ out1)
{
  __shared__ __align__(16) unsigned short skew[128*264];   // 67,584 B
  const int pbid = blockIdx.x;
  const int xcd = pbid & 7;
  const int b = xcd >> 1;
  const int hhalf = (pbid >> 3) & 1;
  const int st = ((pbid >> 4) << 1) | (xcd & 1);
  const int s0 = st << 4;
  const int w = threadIdx.x >> 6;
  const int lane = threadIdx.x & 63;
  const int p = lane & 15, g = lane >> 4;
  const int s = s0 + p;
  const int hl0 = w * 2;                 // local head base (skew rows)
  const int h0 = hhalf*8 + hl0;          // global head base (memory)
  const f4 fz = {0.f,0.f,0.f,0.f};

  {
    unsigned* zp = (unsigned*)skew + w*4224;
    for (int i = lane; i < 4224; i += 64) zp[i] = 0u;
  }

  bfx8 qf[2][2];
#pragma unroll
  for (int hh=0; hh<2; ++hh){
    size_t qb = (((size_t)(b*16 + h0 + hh))*64 + st)*1024 + (size_t)lane*16;
    qf[hh][0] = *(const bfx8*)(Qf + qb);
    qf[hh][1] = *(const bfx8*)(Qf + qb + 8);
  }

  f4 o[2][4];
#pragma unroll
  for (int hh=0; hh<2; ++hh)
#pragma unroll
    for (int df=0; df<4; ++df) o[hh][df] = fz;

  float tl0[2] = {0.f,0.f};
  float tl1[2] = {0.f,0.f};

  const int tlo = (st-8 < 0) ? 0 : st-8;
  const int thi = (st+8 > 63) ? 63 : st+8;

  bfx8 kc[2][2]; bfx4 vc[2][4]; unsigned short qc[2][4]; f4 is;
  bfx8 kn[2][2]; bfx4 vn[2][4]; unsigned short qn[2][4]; f4 isn;

#pragma unroll
  for (int hh=0; hh<2; ++hh){
    size_t bh = (size_t)(b*16 + h0 + hh);
    size_t fb = (bh*64 + tlo)*1024 + (size_t)lane*16;
    kc[hh][0] = *(const bfx8*)(Kf + fb);
    kc[hh][1] = *(const bfx8*)(Kf + fb + 8);
#pragma unroll
    for (int df=0; df<4; ++df)
      vc[hh][df] = *(const bfx4*)(Vf + fb + df*4);
#pragma unroll
    for (int r=0; r<4; ++r){
      int t = (tlo<<4) + 4*g + r;
      int u = s - t + 128; u = u < 0 ? 0 : (u > 256 ? 256 : u);
      qc[hh][r] = Qr2[(((size_t)b*1024 + s)*272 + u)*16 + (h0+hh)];
    }
  }
  is = *(const f4*)(ivf + (((size_t)(b*64 + tlo)*64 + st)*64 + lane)*4);

  for (int ti = tlo; ti <= thi; ++ti){
    const int t0 = ti << 4;

    if (ti < thi){
      const int tn = ti + 1;
#pragma unroll
      for (int hh=0; hh<2; ++hh){
        size_t bh = (size_t)(b*16 + h0 + hh);
        size_t fb = (bh*64 + tn)*1024 + (size_t)lane*16;
        kn[hh][0] = *(const bfx8*)(Kf + fb);
        kn[hh][1] = *(const bfx8*)(Kf + fb + 8);
#pragma unroll
        for (int df=0; df<4; ++df)
          vn[hh][df] = *(const bfx4*)(Vf + fb + df*4);
#pragma unroll
        for (int r=0; r<4; ++r){
          int t = (tn<<4) + 4*g + r;
          int u = s - t + 128; u = u < 0 ? 0 : (u > 256 ? 256 : u);
          qn[hh][r] = Qr2[(((size_t)b*1024 + s)*272 + u)*16 + (h0+hh)];
        }
      }
      isn = *(const f4*)(ivf + (((size_t)(b*64 + tn)*64 + st)*64 + lane)*4);
    }

#pragma unroll
    for (int hh=0; hh<2; ++hh){
      f4 sc = mfma32(kc[hh][1], qf[hh][1], mfma32(kc[hh][0], qf[hh][0], fz));
      f4 at;
#pragma unroll
      for (int r=0; r<4; ++r) at[r] = __expf(sc[r] + bf2f(qc[hh][r])) * is[r];
      const int row = (hl0 + hh)*16 + p;
#pragma unroll
      for (int r=0; r<4; ++r){
        int t = t0 + 4*g + r;
        int u = s - t + 128;
        float a = at[r];
        if (u <= 0) tl0[hh] += a;
        else if (u >= 256) tl1[hh] += a;
        else skew[row*264 + u] = f2bf(a);
      }
      bfx4 pk;
#pragma unroll
      for (int r=0; r<4; ++r) pk[r] = (short)f2bf(at[r]);
#pragma unroll
      for (int df=0; df<4; ++df)
        o[hh][df] = mfma16(vc[hh][df], pk, o[hh][df]);
    }

    if (ti < thi){
#pragma unroll
      for (int hh=0; hh<2; ++hh){
#pragma unroll
        for (int kf=0; kf<2; ++kf) kc[hh][kf] = kn[hh][kf];
#pragma unroll
        for (int df=0; df<4; ++df) vc[hh][df] = vn[hh][df];
#pragma unroll
        for (int r=0; r<4; ++r) qc[hh][r] = qn[hh][r];
      }
      is = isn;
    }
  }

  __syncthreads();

  // ---- fused out2 = rel_v^T @ skew (own-wave rows only; local head rows) ----
  f4 acc2[2][4];
#pragma unroll
  for (int hh=0; hh<2; ++hh)
#pragma unroll
    for (int df=0; df<4; ++df) acc2[hh][df] = fz;
#pragma unroll
  for (int k0=0; k0<256; k0+=32){
    bfx8 bb0 = *(const bfx8*)&skew[(hl0*16 + p)*264 + k0 + 8*g];
    bfx8 bb1 = *(const bfx8*)&skew[((hl0+1)*16 + p)*264 + k0 + 8*g];
#pragma unroll
    for (int df=0; df<4; ++df){
      bfx8 a = *(const bfx8*)(relvT + (size_t)(df*16 + p)*288 + k0 + 8*g);
      acc2[0][df] = mfma32(a, bb0, acc2[0][df]);
      acc2[1][df] = mfma32(a, bb1, acc2[1][df]);
    }
  }

  f4 rv0[4], rv1[4];
#pragma unroll
  for (int df=0; df<4; ++df){
    rv0[df] = *(const f4*)(relv + df*16 + 4*g);
    rv1[df] = *(const f4*)(relv + 16384 + df*16 + 4*g);
  }
#pragma unroll
  for (int hh=0; hh<2; ++hh){
    float tv0 = tl0[hh];
    tv0 += __shfl_xor(tv0, 16, 64);
    tv0 += __shfl_xor(tv0, 32, 64);
    float tv1 = tl1[hh];
    tv1 += __shfl_xor(tv1, 16, 64);
    tv1 += __shfl_xor(tv1, 32, 64);
    size_t bh = (size_t)(b*16 + h0 + hh);
#pragma unroll
    for (int part=0; part<4; ++part){
      size_t tix = ((size_t)(part*64) + bh)*2048 + (size_t)s*2;
      tv0 += tails[tix + 0];
      tv1 += tails[tix + 1];
    }
#pragma unroll
    for (int df=0; df<4; ++df)
#pragma unroll
      for (int r=0; r<4; ++r)
        o[hh][df][r] += acc2[hh][df][r] + tv0*rv0[df][r] + tv1*rv1[df][r];
  }

  __syncthreads();

  float* slabBase = (float*)skew;
  float (*tb)[68] = (float(*)[68])(slabBase + w*(16*68));
#pragma unroll
  for (int hh=0; hh<2; ++hh){
#pragma unroll
    for (int df=0; df<4; ++df)
      *(f4*)&tb[p][df*16 + 4*g] = o[hh][df];
    __syncthreads();
    const int srow = lane >> 2, quad = lane & 3;
    f4 r0 = *(const f4*)&tb[srow][quad*16 + 0];
    f4 r1 = *(const f4*)&tb[srow][quad*16 + 4];
    f4 r2 = *(const f4*)&tb[srow][quad*16 + 8];
    f4 r3 = *(const f4*)&tb[srow][quad*16 + 12];
    size_t addr = ((size_t)b*1024 + s0 + srow)*1024 + (h0+hh)*64 + quad*16;
    bfx8 pa, pb;
#pragma unroll
    for (int j=0; j<4; ++j){
      float a0 = r0[j], a1 = r1[j], a2 = r2[j], a3 = r3[j];
#pragma unroll
      for (int part=0; part<4; ++part){
        const unsigned short* pp = op + (size_t)part*4194304 + addr;
        bfx8 q0 = *(const bfx8*)pp;
        bfx8 q1 = *(const bfx8*)(pp + 8);
        a0 += bf2f((unsigned short)q0[j]);
        a1 += bf2f((unsigned short)q0[j+4]);
        a2 += bf2f((unsigned short)q1[j]);
        a3 += bf2f((unsigned short)q1[j+4]);
      }
      pa[j]   = (short)f2bf(a0);
      pa[j+4] = (short)f2bf(a1);
      pb[j]   = (short)f2bf(a2);
      pb[j+4] = (short)f2bf(a3);
    }
    *(bfx8*)(out1 + addr) = pa;
    *(bfx8*)(out1 + addr + 8) = pb;
    __syncthreads();
  }
}

// ---------------- final projection: counted-vmcnt double-buffered pipeline ----------------
__global__ __launch_bounds__(256) void k_wo(
    const unsigned short* __restrict__ out1, const unsigned short* __restrict__ wo,
    const float* __restrict__ bo, float* __restrict__ dout)
{
  __shared__ __align__(16) unsigned short smem[2][6144];
  const int nt = blockIdx.x;
  const int mt = blockIdx.y;
  const int w = threadIdx.x >> 6, lane = threadIdx.x & 63;
  const int wr = w >> 1, wc = w & 1;
  const int p = lane & 15, g = lane >> 4;
  const int m0 = mt*64, n0 = nt*128;
  const f4 fz = {0.f,0.f,0.f,0.f};
  f4 acc[2][4];
#pragma unroll
  for (int m=0;m<2;++m)
#pragma unroll
    for (int n=0;n<4;++n) acc[m][n] = fz;

  const int j0 = w*2, j1 = w*2 + 1;
  const unsigned short* gA = out1 + (size_t)(m0 + p)*1024 + g*8;
  const unsigned short* gB = wo   + (size_t)(n0 + p)*1024 + g*8;

  {
    unsigned short* d0 = &smem[0][0];
    gload16(gA + (size_t)w*16384, d0 + w*512);
    gload16(gB + (size_t)j0*16384, d0 + 2048 + j0*512);
    gload16(gB + (size_t)j1*16384, d0 + 2048 + j1*512);
  }

  for (int it=0; it<32; ++it){
    const int cur = it & 1;
    if (it < 31){
      const int kn = (it+1)*32;
      unsigned short* dn = &smem[cur^1][0];
      gload16(gA + (size_t)w*16384 + kn, dn + w*512);
      gload16(gB + (size_t)j0*16384 + kn, dn + 2048 + j0*512);
      gload16(gB + (size_t)j1*16384 + kn, dn + 2048 + j1*512);
      asm volatile("s_waitcnt vmcnt(3)" ::: "memory");
    } else {
      asm volatile("s_waitcnt vmcnt(0)" ::: "memory");
    }
    __builtin_amdgcn_sched_barrier(0);
    __builtin_amdgcn_s_barrier();
    __builtin_amdgcn_sched_barrier(0);
    {
      const unsigned short* Ab = &smem[cur][0];
      bfx8 af[2], bfr[4];
#pragma unroll
      for (int m=0;m<2;++m) af[m] = *(const bfx8*)(Ab + (wr*2+m)*512 + lane*8);
#pragma unroll
      for (int n=0;n<4;++n) bfr[n] = *(const bfx8*)(Ab + 2048 + (wc*4+n)*512 + lane*8);
#pragma unroll
      for (int m=0;m<2;++m)
#pragma unroll
        for (int n=0;n<4;++n)
          acc[m][n] = mfma32(af[m], bfr[n], acc[m][n]);
    }
    __builtin_amdgcn_sched_barrier(0);
    __builtin_amdgcn_s_barrier();
    __builtin_amdgcn_sched_barrier(0);
  }

#pragma unroll
  for (int n=0;n<4;++n){
    const int col = n0 + wc*64 + n*16 + p;
    const float bias = bo[col];
#pragma unroll
    for (int m=0;m<2;++m)
#pragma unroll
      for (int r=0;r<4;++r){
        int row = m0 + wr*32 + m*16 + 4*g + r;
        int bb = row >> 10, s = row & 1023;
        dout[((size_t)s*4 + bb)*1024 + col] = acc[m][n][r] + bias;
      }
  }
}

extern "C" void kernel_launch(void* const* d_in, const int* in_sizes, int n_in,
                              void* d_out, int out_size, void* d_ws, size_t ws_size,
                              hipStream_t stream){
  const float* x   = (const float*)d_in[0];
  const float* wq  = (const float*)d_in[1];
  const float* wk  = (const float*)d_in[2];
  const float* wv  = (const float*)d_in[3];
  const float* wo  = (const float*)d_in[4];
  const float* bo  = (const float*)d_in[5];
  const float* rlk = (const float*)d_in[6];
  const float* rlv = (const float*)d_in[7];
  char* ws = (char*)d_ws;

  unsigned short* x_bf    = (unsigned short*)(ws + 0);
  unsigned short* wq_bf   = (unsigned short*)(ws + 8388608);   // [wq|wk|wv|wo] contiguous
  unsigned short* relk_bf = (unsigned short*)(ws + 16777216);
  unsigned short* relvT_bf= (unsigned short*)(ws + 16812032);
  unsigned short* Qf      = (unsigned short*)(ws + 16848896);   // fragment layout
  unsigned short* Kf      = (unsigned short*)(ws + 25237504);   // fragment layout
  unsigned short* Vf      = (unsigned short*)(ws + 33626112);   // fragment layout
  unsigned short* Qr2     = (unsigned short*)(ws + 42014720);   // 35.65 MB -> 77666304
  float*          tails   = (float*)        (ws + 77666304);   // 2 MB -> 79763456
  unsigned short* op      = (unsigned short*)(ws + 79763456);   // 32 MB (4 parts) -> 113317888
  unsigned short* out1    = (unsigned short*)(ws + 113317888);  // 8 MB -> 121706496
  float*          ivf     = (float*)        (ws + 121706496);  // 16 MB -> 138483712
  unsigned short* wo_bf   = (unsigned short*)(ws + 14680064);

  k_cast<<<4096, 256, 0, stream>>>(x, x_bf, 1048576);
  k_castw<<<dim3(1024,4), 256, 0, stream>>>(wq, wk, wv, wo, wq_bf);
  k_relprep<<<72, 256, 0, stream>>>(rlk, rlv, relk_bf, relvT_bf);

  k_qkv<<<dim3(24,4,8), 256, 0, stream>>>(x_bf, wq_bf, Qf, Kf, Vf);
  k_qr<<<512, 256, 0, stream>>>(Qf, relk_bf, Qr2);

  k_s  <<<4096, 256, 0, stream>>>(Qf, Kf, Qr2, ivf);
  k_far<<<2048, 256, 0, stream>>>(Qf, Kf, Vf, Qr2, ivf, tails, op);
  k_near<<<512, 256, 0, stream>>>(Qf, Kf, Vf, Qr2, ivf, relvT_bf, rlv, tails, op, out1);
  k_wo<<<dim3(8,64), 256, 0, stream>>>(out1, wo_bf, bo, (float*)d_out);
}